// Round 2
// baseline (4245.907 us; speedup 1.0000x reference)
//
#include <hip/hip_runtime.h>
#include <cstdint>
#include <cstddef>

// ---------------------------------------------------------------------------
// ConvStackedTemporalGCN — fp32, timestep-batched
// N=10000 nodes, F=128 feats, P=4 steps, E=160000 edges, C=512, HID=256
//
// Rewrites:
//  * gcn(h,W,b) = A(hW)+b = (A h)W + b  (A = normalized adjacency, linear)
//    -> A.Xp shared by W1/Wz/Wr/Wh; 4 aggregations@512ch per step, not 8.
//  * CSR by dst built per launch -> gather aggregation (no float atomics).
//  * P timesteps batched into one [PB*N, .] problem (same graph, independent
//    until the probs-weighted accumulation). PB picked from ws_size.
// ---------------------------------------------------------------------------

__global__ void deg_init_k(float* deg, int N) {
  int i = blockIdx.x * blockDim.x + threadIdx.x;
  if (i < N) deg[i] = 1.0f;  // self-loop weight
}

__global__ void deg_accum_k(const int* __restrict__ ei, const float* __restrict__ ea,
                            float* deg, int E) {
  int e = blockIdx.x * blockDim.x + threadIdx.x;
  if (e < E) atomicAdd(&deg[ei[E + e]], ea[e]);  // dst row
}

__global__ void dinv_k(const float* __restrict__ deg, float* dinv, float* dinv2, int N) {
  int i = blockIdx.x * blockDim.x + threadIdx.x;
  if (i < N) {
    float d = deg[i];
    float r = d > 0.0f ? rsqrtf(d) : 0.0f;
    dinv[i] = r;
    dinv2[i] = r * r;  // self-loop norm
  }
}

__global__ void norm_count_k(const int* __restrict__ ei, const float* __restrict__ ea,
                             const float* __restrict__ dinv, float* __restrict__ normw,
                             int* counts, int E) {
  int e = blockIdx.x * blockDim.x + threadIdx.x;
  if (e < E) {
    int s = ei[e], d = ei[E + e];
    normw[e] = dinv[s] * ea[e] * dinv[d];
    atomicAdd(&counts[d], 1);
  }
}

// single-block exclusive scan over counts -> row_ptr
__global__ void scan_k(const int* __restrict__ counts, int* row_ptr, int n) {
  __shared__ int smem[1024];
  __shared__ int carry_s;
  int tid = threadIdx.x;
  if (tid == 0) carry_s = 0;
  __syncthreads();
  for (int base = 0; base < n; base += 1024) {
    int i = base + tid;
    int v = (i < n) ? counts[i] : 0;
    smem[tid] = v;
    __syncthreads();
    for (int off = 1; off < 1024; off <<= 1) {
      int t = (tid >= off) ? smem[tid - off] : 0;
      __syncthreads();
      smem[tid] += t;
      __syncthreads();
    }
    int carry = carry_s;
    if (i < n) row_ptr[i] = carry + smem[tid] - v;  // exclusive
    __syncthreads();
    if (tid == 1023) carry_s = carry + smem[1023];
    __syncthreads();
  }
  if (tid == 0) row_ptr[n] = carry_s;
}

__global__ void fill_k(const int* __restrict__ ei, const float* __restrict__ normw,
                       const int* __restrict__ row_ptr, int* cursor,
                       int* __restrict__ csr_src, float* __restrict__ csr_w, int E) {
  int e = blockIdx.x * blockDim.x + threadIdx.x;
  if (e < E) {
    int d = ei[E + e];
    int pos = atomicAdd(&cursor[d], 1);
    int idx = row_ptr[d] + pos;
    csr_src[idx] = ei[e];
    csr_w[idx] = normw[e];
  }
}

__global__ void softmax4_k(const float* __restrict__ attn, float* probs) {
  float a0 = attn[0], a1 = attn[1], a2 = attn[2], a3 = attn[3];
  float m = fmaxf(fmaxf(a0, a1), fmaxf(a2, a3));
  float e0 = expf(a0 - m), e1 = expf(a1 - m), e2 = expf(a2 - m), e3 = expf(a3 - m);
  float s = e0 + e1 + e2 + e3;
  probs[0] = e0 / s; probs[1] = e1 / s; probs[2] = e2 / s; probs[3] = e3 / s;
}

// deinterleave x[N,F,P=4] -> 4 contiguous [N*F] slices in one float4 pass
__global__ void extract_all_k(const float* __restrict__ x, float* __restrict__ xp, int NF) {
  int i = blockIdx.x * blockDim.x + threadIdx.x;
  if (i < NF) {
    float4 v = ((const float4*)x)[i];
    xp[i] = v.x;
    xp[NF + i] = v.y;
    xp[2 * NF + i] = v.z;
    xp[3 * NF + i] = v.w;
  }
}

// batched aggregation, Cdim=512: one wave per (batched) row, lane owns 8 ch
__global__ __launch_bounds__(256) void aggregate512_k(
    const float* __restrict__ in, float* __restrict__ out,
    const int* __restrict__ row_ptr, const int* __restrict__ csr_src,
    const float* __restrict__ csr_w, const float* __restrict__ dinv2, int N, int NB) {
  int gw = (blockIdx.x * 256 + threadIdx.x) >> 6;
  int lane = threadIdx.x & 63;
  if (gw >= NB) return;
  int node = gw % N;
  int off = gw - node;  // p*N
  float w0 = dinv2[node];
  const float4* sr = (const float4*)(in + (size_t)gw * 512) + lane * 2;
  float4 s0 = sr[0], s1 = sr[1];
  float4 acc0 = make_float4(w0 * s0.x, w0 * s0.y, w0 * s0.z, w0 * s0.w);
  float4 acc1 = make_float4(w0 * s1.x, w0 * s1.y, w0 * s1.z, w0 * s1.w);
  int s = row_ptr[node], e = row_ptr[node + 1];
  for (int idx = s; idx < e; ++idx) {
    int srcn = csr_src[idx] + off;
    float w = csr_w[idx];
    const float4* r = (const float4*)(in + (size_t)srcn * 512) + lane * 2;
    float4 r0 = r[0], r1 = r[1];
    acc0.x += w * r0.x; acc0.y += w * r0.y; acc0.z += w * r0.z; acc0.w += w * r0.w;
    acc1.x += w * r1.x; acc1.y += w * r1.y; acc1.z += w * r1.z; acc1.w += w * r1.w;
  }
  float4* orow = (float4*)(out + (size_t)gw * 512) + lane * 2;
  orow[0] = acc0;
  orow[1] = acc1;
}

// batched aggregation, Cdim=128: lane owns 2 ch (float2)
__global__ __launch_bounds__(256) void aggregate128_k(
    const float* __restrict__ in, float* __restrict__ out,
    const int* __restrict__ row_ptr, const int* __restrict__ csr_src,
    const float* __restrict__ csr_w, const float* __restrict__ dinv2, int N, int NB) {
  int gw = (blockIdx.x * 256 + threadIdx.x) >> 6;
  int lane = threadIdx.x & 63;
  if (gw >= NB) return;
  int node = gw % N;
  int off = gw - node;
  float w0 = dinv2[node];
  const float2* sr = (const float2*)(in + (size_t)gw * 128) + lane;
  float2 sv = *sr;
  float2 acc = make_float2(w0 * sv.x, w0 * sv.y);
  int s = row_ptr[node], e = row_ptr[node + 1];
  for (int idx = s; idx < e; ++idx) {
    int srcn = csr_src[idx] + off;
    float w = csr_w[idx];
    float2 r = *((const float2*)(in + (size_t)srcn * 128) + lane);
    acc.x += w * r.x;
    acc.y += w * r.y;
  }
  *((float2*)(out + (size_t)gw * 128) + lane) = acc;
}

// C[N,Co] = A[N,K] @ W[K,Co] (+bias | +accumulate) (+relu). K%32==0, Co%64==0.
// 128x64 tile, BK=32, 256 threads, 8x4 per thread. flags: bit0 accum, bit1 relu
__global__ __launch_bounds__(256) void gemm_f32_k(
    const float* __restrict__ A, const float* __restrict__ W,
    const float* __restrict__ bias, float* __restrict__ C,
    int N, int K, int Co, int flags) {
  __shared__ float As[32][128];  // [k][m] transposed -> b128 fragment reads
  __shared__ float Bs[32][64];
  int bm = blockIdx.x * 128;
  int bn = blockIdx.y * 64;
  int tid = threadIdx.x;
  int tx = tid & 15, ty = tid >> 4;  // 16x16 threads, each 8 rows x 4 cols
  float acc[8][4] = {};
  int am = tid & 127;  // A row in tile
  int ah = tid >> 7;   // k half (16 floats each)
  int arow = bm + am;
  const float* Abase = A + (size_t)arow * K + ah * 16;
  int bkr = tid >> 3, bnq = tid & 7;
  const float* Bbase = W + (size_t)bkr * Co + bn + bnq * 8;
  for (int k0 = 0; k0 < K; k0 += 32) {
    float4 a0, a1, a2, a3;
    if (arow < N) {
      const float4* Ap = (const float4*)(Abase + k0);
      a0 = Ap[0]; a1 = Ap[1]; a2 = Ap[2]; a3 = Ap[3];
    } else {
      a0 = make_float4(0.f, 0.f, 0.f, 0.f); a1 = a0; a2 = a0; a3 = a0;
    }
    const float4* Bp = (const float4*)(Bbase + (size_t)k0 * Co);
    float4 b0 = Bp[0], b1 = Bp[1];
    __syncthreads();
    int kk = ah * 16;
    As[kk + 0][am] = a0.x;  As[kk + 1][am] = a0.y;  As[kk + 2][am] = a0.z;  As[kk + 3][am] = a0.w;
    As[kk + 4][am] = a1.x;  As[kk + 5][am] = a1.y;  As[kk + 6][am] = a1.z;  As[kk + 7][am] = a1.w;
    As[kk + 8][am] = a2.x;  As[kk + 9][am] = a2.y;  As[kk + 10][am] = a2.z; As[kk + 11][am] = a2.w;
    As[kk + 12][am] = a3.x; As[kk + 13][am] = a3.y; As[kk + 14][am] = a3.z; As[kk + 15][am] = a3.w;
    *(float4*)&Bs[bkr][bnq * 8] = b0;
    *(float4*)&Bs[bkr][bnq * 8 + 4] = b1;
    __syncthreads();
#pragma unroll 8
    for (int k = 0; k < 32; ++k) {
      float4 af0 = *(const float4*)&As[k][ty * 8];
      float4 af1 = *(const float4*)&As[k][ty * 8 + 4];
      float4 bf = *(const float4*)&Bs[k][tx * 4];
      float av[8] = {af0.x, af0.y, af0.z, af0.w, af1.x, af1.y, af1.z, af1.w};
      float bv[4] = {bf.x, bf.y, bf.z, bf.w};
#pragma unroll
      for (int i2 = 0; i2 < 8; ++i2)
#pragma unroll
        for (int j2 = 0; j2 < 4; ++j2) acc[i2][j2] += av[i2] * bv[j2];
    }
  }
  bool accum = (flags & 1) != 0;
  bool relu = (flags & 2) != 0;
#pragma unroll
  for (int i2 = 0; i2 < 8; ++i2) {
    int row = bm + ty * 8 + i2;
    if (row >= N) continue;
    int col = bn + tx * 4;
    float* Cp = C + (size_t)row * Co + col;
    float4 v = make_float4(acc[i2][0], acc[i2][1], acc[i2][2], acc[i2][3]);
    if (accum) {
      float4 o = *(const float4*)Cp;
      v.x += o.x; v.y += o.y; v.z += o.z; v.w += o.w;
    } else if (bias) {
      float4 bb = *(const float4*)(bias + col);
      v.x += bb.x; v.y += bb.y; v.z += bb.z; v.w += bb.w;
    }
    if (relu) {
      v.x = fmaxf(v.x, 0.f); v.y = fmaxf(v.y, 0.f);
      v.z = fmaxf(v.z, 0.f); v.w = fmaxf(v.w, 0.f);
    }
    *(float4*)Cp = v;
  }
}

__global__ void sigmoid_k(const float* __restrict__ in, float* __restrict__ out, int n) {
  int i = blockIdx.x * blockDim.x + threadIdx.x;
  if (i < n) out[i] = 1.0f / (1.0f + expf(-in[i]));
}

// rp := H * sigmoid(rp)
__global__ void hr_k(float* rp, const float* __restrict__ H, int n) {
  int i = blockIdx.x * blockDim.x + threadIdx.x;
  if (i < n) {
    float r = 1.0f / (1.0f + expf(-rp[i]));
    rp[i] = H[i] * r;
  }
}

// hacc[j] += sum_pr probs[p0+pr] * (Z*H + (1-Z)*tanh(Ht))[pr*NC + j]
__global__ void accum_batched_k(float* __restrict__ hacc, const float* __restrict__ Z,
                                const float* __restrict__ H, const float* __restrict__ Ht,
                                const float* __restrict__ probs, int p0, int PB, int NC) {
  int j = blockIdx.x * blockDim.x + threadIdx.x;
  if (j >= NC) return;
  float s = 0.0f;
  for (int pr = 0; pr < PB; ++pr) {
    size_t idx = (size_t)pr * NC + j;
    float z = Z[idx];
    s += probs[p0 + pr] * (z * H[idx] + (1.0f - z) * tanhf(Ht[idx]));
  }
  hacc[j] += s;
}

__global__ void relu_copy_k(const float* __restrict__ in, float* __restrict__ out, int n) {
  int i = blockIdx.x * blockDim.x + threadIdx.x;
  if (i < n) out[i] = fmaxf(in[i], 0.0f);
}

// out[i] = dot(A[i,:K], w) + b[0]; one wave per row
__global__ __launch_bounds__(256) void matvec_k(const float* __restrict__ A,
                                                const float* __restrict__ w,
                                                const float* __restrict__ b,
                                                float* __restrict__ out, int N, int K) {
  int gw = (blockIdx.x * 256 + threadIdx.x) >> 6;
  int lane = threadIdx.x & 63;
  if (gw >= N) return;
  float s = 0.0f;
  for (int k = lane; k < K; k += 64) s += A[(size_t)gw * K + k] * w[k];
#pragma unroll
  for (int off = 32; off > 0; off >>= 1) s += __shfl_down(s, off);
  if (lane == 0) out[gw] = s + b[0];
}

extern "C" void kernel_launch(void* const* d_in, const int* in_sizes, int n_in,
                              void* d_out, int out_size, void* d_ws, size_t ws_size,
                              hipStream_t stream) {
  const int N = 10000, F = 128, P = 4, E = 160000;
  const int C = 512, HID = 256;
  const int NF = N * F, NC = N * C;

  const float* x     = (const float*)d_in[0];
  const int*   ei    = (const int*)d_in[1];
  const float* ea    = (const float*)d_in[2];
  const float* W1    = (const float*)d_in[3];
  const float* b1    = (const float*)d_in[4];
  const float* W2    = (const float*)d_in[5];
  const float* b2    = (const float*)d_in[6];
  const float* W3    = (const float*)d_in[7];
  const float* b3    = (const float*)d_in[8];
  const float* W4    = (const float*)d_in[9];
  const float* b4    = (const float*)d_in[10];
  const float* W5    = (const float*)d_in[11];
  const float* b5    = (const float*)d_in[12];
  const float* Wz    = (const float*)d_in[13];
  const float* bz    = (const float*)d_in[14];
  const float* Lz_w  = (const float*)d_in[15];
  const float* Lz_b  = (const float*)d_in[16];
  const float* Wr    = (const float*)d_in[17];
  const float* br    = (const float*)d_in[18];
  const float* Lr_w  = (const float*)d_in[19];
  const float* Lr_b  = (const float*)d_in[20];
  const float* Wh    = (const float*)d_in[21];
  const float* bh    = (const float*)d_in[22];
  const float* Lh_w  = (const float*)d_in[23];
  const float* Lh_b  = (const float*)d_in[24];
  const float* attn  = (const float*)d_in[25];
  const float* lin1w = (const float*)d_in[26];
  const float* lin1b = (const float*)d_in[27];
  const float* lin2w = (const float*)d_in[28];
  const float* lin2b = (const float*)d_in[29];
  (void)in_sizes; (void)n_in;

  // ---- pick timestep batch size from ws_size ----
  auto need_bytes = [&](int PB) -> size_t {
    size_t fixed = 0;
    fixed += ((size_t)N * 4 + 255 & ~(size_t)255) * 5;        // deg,dinv,dinv2,counts + slack
    fixed += ((size_t)(N + 1) * 4 + 255) & ~(size_t)255;      // rowp
    fixed += (((size_t)E * 4 + 255) & ~(size_t)255) * 3;      // normw,csrs,csrw
    fixed += 256;                                             // probs
    fixed += (((size_t)P * NF * 4 + 255) & ~(size_t)255);     // XPall4
    size_t per = 0;
    per += (((size_t)PB * NF * 4 + 255) & ~(size_t)255);      // AXP
    per += (((size_t)PB * NC * 4 + 255) & ~(size_t)255) * 5;  // B0..B4
    return fixed + per + 4096;
  };
  int PB = 1;
  if (ws_size >= need_bytes(4)) PB = 4;
  else if (ws_size >= need_bytes(2)) PB = 2;
  const int NB = PB * N;

  // ---- workspace carve-out ----
  char* wsp = (char*)d_ws;
  auto alloc = [&](size_t bytes) -> char* {
    char* ret = wsp;
    wsp += (bytes + 255) & ~(size_t)255;
    return ret;
  };
  float* deg    = (float*)alloc((size_t)N * 4);
  float* dinv   = (float*)alloc((size_t)N * 4);
  float* dinv2  = (float*)alloc((size_t)N * 4);
  int*   counts = (int*)alloc((size_t)N * 4);
  int*   rowp   = (int*)alloc((size_t)(N + 1) * 4);
  float* normw  = (float*)alloc((size_t)E * 4);
  int*   csrs   = (int*)alloc((size_t)E * 4);
  float* csrw   = (float*)alloc((size_t)E * 4);
  float* probs  = (float*)alloc(256);
  float* XPall4 = (float*)alloc((size_t)P * NF * 4);
  float* AXP    = (float*)alloc((size_t)PB * NF * 4);
  float* B0     = (float*)alloc((size_t)PB * NC * 4);
  float* B1     = (float*)alloc((size_t)PB * NC * 4);
  float* B2     = (float*)alloc((size_t)PB * NC * 4);  // H
  float* B3     = (float*)alloc((size_t)PB * NC * 4);  // Z
  float* B4     = (float*)alloc((size_t)PB * NC * 4);  // Ht pre-activation

  float* Hacc = (float*)d_out + 10000;  // out_hidden lives in d_out

  const int NBC = NB * C;
  const int ewBlocks = (NBC + 255) / 256;

  // ---- init + graph preprocessing ----
  hipMemsetAsync(d_out, 0, (size_t)out_size * sizeof(float), stream);
  hipMemsetAsync(counts, 0, (size_t)N * 4, stream);
  deg_init_k<<<(N + 255) / 256, 256, 0, stream>>>(deg, N);
  deg_accum_k<<<(E + 255) / 256, 256, 0, stream>>>(ei, ea, deg, E);
  dinv_k<<<(N + 255) / 256, 256, 0, stream>>>(deg, dinv, dinv2, N);
  norm_count_k<<<(E + 255) / 256, 256, 0, stream>>>(ei, ea, dinv, normw, counts, E);
  scan_k<<<1, 1024, 0, stream>>>(counts, rowp, N);
  hipMemsetAsync(counts, 0, (size_t)N * 4, stream);
  fill_k<<<(E + 255) / 256, 256, 0, stream>>>(ei, normw, rowp, counts, csrs, csrw, E);
  softmax4_k<<<1, 1, 0, stream>>>(attn, probs);
  extract_all_k<<<(NF + 255) / 256, 256, 0, stream>>>(x, XPall4, NF);

  auto gemm = [&](const float* A, const float* Wp, const float* bp, float* Cp,
                  int Nrows, int K, int Co, int flags) {
    dim3 g((Nrows + 127) / 128, Co / 64);
    gemm_f32_k<<<g, 256, 0, stream>>>(A, Wp, bp, Cp, Nrows, K, Co, flags);
  };
  auto agg512 = [&](const float* in, float* out) {
    aggregate512_k<<<(NB * 64) / 256, 256, 0, stream>>>(in, out, rowp, csrs, csrw, dinv2, N, NB);
  };

  for (int p0 = 0; p0 < P; p0 += PB) {
    const float* XPb = XPall4 + (size_t)p0 * NF;
    aggregate128_k<<<(NB * 64) / 256, 256, 0, stream>>>(XPb, AXP, rowp, csrs, csrw, dinv2, N, NB);

    // stacked GCN: h_{i+1} = (A h_i) W_{i+1} + b_{i+1}
    gemm(AXP, W1, b1, B0, NB, F, C, 0);                   // h1
    agg512(B0, B1); gemm(B1, W2, b2, B0, NB, C, C, 0);    // h2
    agg512(B0, B1); gemm(B1, W3, b3, B0, NB, C, C, 0);    // h3
    agg512(B0, B1); gemm(B1, W4, b4, B0, NB, C, C, 0);    // h4
    agg512(B0, B1); gemm(B1, W5, b5, B2, NB, C, C, 0);    // H

    // Z gate
    gemm(AXP, Wz, bz, B0, NB, F, C, 0);                        // Gz
    gemm(B0, Lz_w, Lz_b, B1, NB, C, C, 0);                     // Gz@Lz_top + b
    gemm(B2, Lz_w + (size_t)C * C, nullptr, B1, NB, C, C, 1);  // += H@Lz_bot
    sigmoid_k<<<ewBlocks, 256, 0, stream>>>(B1, B3, NBC);      // Z

    // R gate -> H*R
    gemm(AXP, Wr, br, B0, NB, F, C, 0);
    gemm(B0, Lr_w, Lr_b, B1, NB, C, C, 0);
    gemm(B2, Lr_w + (size_t)C * C, nullptr, B1, NB, C, C, 1);
    hr_k<<<ewBlocks, 256, 0, stream>>>(B1, B2, NBC);           // B1 = H*sigmoid(Rpre)

    // candidate pre-activation
    gemm(AXP, Wh, bh, B0, NB, F, C, 0);
    gemm(B0, Lh_w, Lh_b, B4, NB, C, C, 0);
    gemm(B1, Lh_w + (size_t)C * C, nullptr, B4, NB, C, C, 1);

    accum_batched_k<<<(NC + 255) / 256, 256, 0, stream>>>(Hacc, B3, B2, B4, probs, p0, PB, NC);
  }

  // final MLP: relu -> lin1+relu -> lin2 (matvec)
  relu_copy_k<<<(NC + 255) / 256, 256, 0, stream>>>(Hacc, B0, NC);
  gemm(B0, lin1w, lin1b, B1, N, C, HID, 2);
  matvec_k<<<(N * 64) / 256, 256, 0, stream>>>(B1, lin2w, lin2b, (float*)d_out, N, HID);
}

// Round 3
// 3154.998 us; speedup vs baseline: 1.3458x; 1.3458x over previous
//
#include <hip/hip_runtime.h>
#include <cstdint>
#include <cstddef>

// ---------------------------------------------------------------------------
// ConvStackedTemporalGCN — split-bf16 MFMA GEMM + P-interleaved aggregation
// N=10000, F=128, P=4, E=160000, C=512, HID=256
//
//  * gcn(h,W,b) = (A h) W + b  (A = normalized adjacency) — A.Xp shared.
//  * Batch rows as r = node*PB + p  -> each edge gathers PB contiguous rows.
//  * All GEMMs: fp32 ~= hi+lo bf16 planes; C = AhBh + AhBl + AlBh via
//    mfma_f32_16x16x32_bf16 (3-product split, ~1e-5 rel error).
//  * Weights transposed+split to [Co][K] bf16 planes once per launch.
// ---------------------------------------------------------------------------

typedef short bf16x8 __attribute__((ext_vector_type(8)));
typedef float f32x4 __attribute__((ext_vector_type(4)));

__device__ __forceinline__ uint16_t f2bf(float f) {
  uint32_t u = __float_as_uint(f);
  u += 0x7FFFu + ((u >> 16) & 1u);
  return (uint16_t)(u >> 16);
}
__device__ __forceinline__ float bf2f(uint16_t h) {
  return __uint_as_float((uint32_t)h << 16);
}
__device__ __forceinline__ void gl16(const void* g, void* l) {
  __builtin_amdgcn_global_load_lds((const __attribute__((address_space(1))) uint32_t*)g,
                                   (__attribute__((address_space(3))) uint32_t*)l, 16, 0, 0);
}

// ---------------- graph preprocessing ----------------
__global__ void deg_init_k(float* deg, int N) {
  int i = blockIdx.x * blockDim.x + threadIdx.x;
  if (i < N) deg[i] = 1.0f;
}
__global__ void deg_accum_k(const int* __restrict__ ei, const float* __restrict__ ea,
                            float* deg, int E) {
  int e = blockIdx.x * blockDim.x + threadIdx.x;
  if (e < E) atomicAdd(&deg[ei[E + e]], ea[e]);
}
__global__ void dinv_k(const float* __restrict__ deg, float* dinv, float* dinv2, int N) {
  int i = blockIdx.x * blockDim.x + threadIdx.x;
  if (i < N) {
    float d = deg[i];
    float r = d > 0.0f ? rsqrtf(d) : 0.0f;
    dinv[i] = r;
    dinv2[i] = r * r;
  }
}
__global__ void norm_count_k(const int* __restrict__ ei, const float* __restrict__ ea,
                             const float* __restrict__ dinv, float* __restrict__ normw,
                             int* counts, int E) {
  int e = blockIdx.x * blockDim.x + threadIdx.x;
  if (e < E) {
    int s = ei[e], d = ei[E + e];
    normw[e] = dinv[s] * ea[e] * dinv[d];
    atomicAdd(&counts[d], 1);
  }
}
__global__ void scan_k(const int* __restrict__ counts, int* row_ptr, int n) {
  __shared__ int smem[1024];
  __shared__ int carry_s;
  int tid = threadIdx.x;
  if (tid == 0) carry_s = 0;
  __syncthreads();
  for (int base = 0; base < n; base += 1024) {
    int i = base + tid;
    int v = (i < n) ? counts[i] : 0;
    smem[tid] = v;
    __syncthreads();
    for (int off = 1; off < 1024; off <<= 1) {
      int t = (tid >= off) ? smem[tid - off] : 0;
      __syncthreads();
      smem[tid] += t;
      __syncthreads();
    }
    int carry = carry_s;
    if (i < n) row_ptr[i] = carry + smem[tid] - v;
    __syncthreads();
    if (tid == 1023) carry_s = carry + smem[1023];
    __syncthreads();
  }
  if (tid == 0) row_ptr[n] = carry_s;
}
__global__ void fill_k(const int* __restrict__ ei, const float* __restrict__ normw,
                       const int* __restrict__ row_ptr, int* cursor,
                       int* __restrict__ csr_src, float* __restrict__ csr_w, int E) {
  int e = blockIdx.x * blockDim.x + threadIdx.x;
  if (e < E) {
    int d = ei[E + e];
    int pos = atomicAdd(&cursor[d], 1);
    int idx = row_ptr[d] + pos;
    csr_src[idx] = ei[e];
    csr_w[idx] = normw[e];
  }
}
__global__ void softmax4_k(const float* __restrict__ attn, float* probs) {
  float a0 = attn[0], a1 = attn[1], a2 = attn[2], a3 = attn[3];
  float m = fmaxf(fmaxf(a0, a1), fmaxf(a2, a3));
  float e0 = expf(a0 - m), e1 = expf(a1 - m), e2 = expf(a2 - m), e3 = expf(a3 - m);
  float s = e0 + e1 + e2 + e3;
  probs[0] = e0 / s; probs[1] = e1 / s; probs[2] = e2 / s; probs[3] = e3 / s;
}

// ---------------- weight transpose + split:  W[K][Co] -> Wt[Co][K] bf16 hi/lo
__global__ void wconv_k(const float* __restrict__ W, uint16_t* __restrict__ Th,
                        uint16_t* __restrict__ Tl, int K, int Co) {
  __shared__ float t[32][33];
  int bco = blockIdx.x * 32, bk = blockIdx.y * 32;
  int tx = threadIdx.x & 31, ty = threadIdx.x >> 5;
  for (int r = ty; r < 32; r += 8) t[r][tx] = W[(size_t)(bk + r) * Co + bco + tx];
  __syncthreads();
  for (int r = ty; r < 32; r += 8) {
    float v = t[tx][r];
    uint16_t h = f2bf(v);
    size_t o = (size_t)(bco + r) * K + bk + tx;
    Th[o] = h;
    Tl[o] = f2bf(v - bf2f(h));
  }
}

// ---------------- aggregation, C=512: fp32 in, bf16 hi/lo planes out --------
// wave per node; reads PB contiguous rows per edge (rows r = node*PB + p)
template <int PB>
__global__ __launch_bounds__(256) void agg512_k(
    const float* __restrict__ in, uint16_t* __restrict__ outh, uint16_t* __restrict__ outl,
    const int* __restrict__ rowp, const int* __restrict__ csrs,
    const float* __restrict__ csrw, const float* __restrict__ dinv2, int N) {
  int node = (blockIdx.x * 256 + threadIdx.x) >> 6;
  int l = threadIdx.x & 63;
  if (node >= N) return;
  float acc[PB][8];
  float w0 = dinv2[node];
  const float* sp = in + (size_t)node * PB * 512 + l * 8;
#pragma unroll
  for (int p = 0; p < PB; ++p) {
    float4 v0 = *(const float4*)(sp + (size_t)p * 512);
    float4 v1 = *(const float4*)(sp + (size_t)p * 512 + 4);
    acc[p][0] = w0 * v0.x; acc[p][1] = w0 * v0.y; acc[p][2] = w0 * v0.z; acc[p][3] = w0 * v0.w;
    acc[p][4] = w0 * v1.x; acc[p][5] = w0 * v1.y; acc[p][6] = w0 * v1.z; acc[p][7] = w0 * v1.w;
  }
  int s = rowp[node], e = rowp[node + 1];
#pragma unroll 2
  for (int idx = s; idx < e; ++idx) {
    int src = csrs[idx];
    float w = csrw[idx];
    const float* rp = in + (size_t)src * PB * 512 + l * 8;
#pragma unroll
    for (int p = 0; p < PB; ++p) {
      float4 v0 = *(const float4*)(rp + (size_t)p * 512);
      float4 v1 = *(const float4*)(rp + (size_t)p * 512 + 4);
      acc[p][0] += w * v0.x; acc[p][1] += w * v0.y; acc[p][2] += w * v0.z; acc[p][3] += w * v0.w;
      acc[p][4] += w * v1.x; acc[p][5] += w * v1.y; acc[p][6] += w * v1.z; acc[p][7] += w * v1.w;
    }
  }
#pragma unroll
  for (int p = 0; p < PB; ++p) {
    size_t ro = ((size_t)node * PB + p) * 512 + l * 8;
    uint16_t h8[8], l8[8];
#pragma unroll
    for (int j = 0; j < 8; ++j) {
      uint16_t h = f2bf(acc[p][j]);
      h8[j] = h;
      l8[j] = f2bf(acc[p][j] - bf2f(h));
    }
    *(bf16x8*)(outh + ro) = *(bf16x8*)h8;
    *(bf16x8*)(outl + ro) = *(bf16x8*)l8;
  }
}

// ---------------- first-hop aggregation straight from x [N][F=128][P=4] -----
template <int PB>
__global__ __launch_bounds__(256) void agg128_k(
    const float* __restrict__ x, uint16_t* __restrict__ outh, uint16_t* __restrict__ outl,
    const int* __restrict__ rowp, const int* __restrict__ csrs,
    const float* __restrict__ csrw, const float* __restrict__ dinv2, int N, int p0) {
  int node = (blockIdx.x * 256 + threadIdx.x) >> 6;
  int l = threadIdx.x & 63;
  if (node >= N) return;
  float acc[8];
  float w0 = dinv2[node];
  const float* sp = x + (size_t)node * 512 + l * 8;
  {
    float4 v0 = *(const float4*)sp;
    float4 v1 = *(const float4*)(sp + 4);
    acc[0] = w0 * v0.x; acc[1] = w0 * v0.y; acc[2] = w0 * v0.z; acc[3] = w0 * v0.w;
    acc[4] = w0 * v1.x; acc[5] = w0 * v1.y; acc[6] = w0 * v1.z; acc[7] = w0 * v1.w;
  }
  int s = rowp[node], e = rowp[node + 1];
#pragma unroll 2
  for (int idx = s; idx < e; ++idx) {
    int src = csrs[idx];
    float w = csrw[idx];
    const float* rp = x + (size_t)src * 512 + l * 8;
    float4 v0 = *(const float4*)rp;
    float4 v1 = *(const float4*)(rp + 4);
    acc[0] += w * v0.x; acc[1] += w * v0.y; acc[2] += w * v0.z; acc[3] += w * v0.w;
    acc[4] += w * v1.x; acc[5] += w * v1.y; acc[6] += w * v1.z; acc[7] += w * v1.w;
  }
  // slot j: flat = l*8+j ; f = l*2 + (j>>2) ; p = j&3   (x is [F][P] per node)
#pragma unroll
  for (int pr = 0; pr < PB; ++pr) {
    int pa = p0 + pr;
    float v0 = acc[pa], v1 = acc[4 + pa];
    uint16_t h0 = f2bf(v0), h1 = f2bf(v1);
    uint16_t lo0 = f2bf(v0 - bf2f(h0)), lo1 = f2bf(v1 - bf2f(h1));
    size_t o = ((size_t)node * PB + pr) * 128 + l * 2;
    *(uint32_t*)(outh + o) = (uint32_t)h0 | ((uint32_t)h1 << 16);
    *(uint32_t*)(outl + o) = (uint32_t)lo0 | ((uint32_t)lo1 << 16);
  }
}

// ---------------- split-bf16 GEMM: C = A@W (+bias | +ACCsrc) (+act) ---------
// A planes [Nrows][K] (lda=K), W planes transposed [Co][Kfull] (ldb=Kfull).
// 128x128 tile, BK=32, 256 thr (4 waves, each 64x64). 3-product split.
// flags: 1=ACC (add ACh/ACl planes), 2=sigmoid, 4=HR (out = AUX*sigmoid(acc)),
//        8=relu. Outputs written where pointers non-null.
__global__ __launch_bounds__(256) void gemm_sp_k(
    const uint16_t* __restrict__ Ah, const uint16_t* __restrict__ Al, int lda,
    const uint16_t* __restrict__ Bh, const uint16_t* __restrict__ Bl, int ldb, int koff,
    const float* __restrict__ bias,
    uint16_t* __restrict__ Chi, uint16_t* __restrict__ Clo, float* __restrict__ Cf,
    const uint16_t* __restrict__ ACh, const uint16_t* __restrict__ ACl,
    const uint16_t* __restrict__ AXh, const uint16_t* __restrict__ AXl,
    int Nrows, int K, int Co, int flags) {
  __shared__ char lds[32768];  // Ah|Al|Bh|Bl tiles, each 4 chunk-planes of 2KB
  const int tid = threadIdx.x;
  const int bm = blockIdx.x * 128, bn = blockIdx.y * 128;
  const int l = tid & 63, w = tid >> 6, wr = w >> 1, wc = w & 1;

  f32x4 acc[4][4];
#pragma unroll
  for (int i = 0; i < 4; ++i)
#pragma unroll
    for (int j = 0; j < 4; ++j) acc[i][j] = (f32x4){0.f, 0.f, 0.f, 0.f};

  const int r127 = tid & 127, ch = tid >> 7;  // staging row & chunk-half
  const uint16_t* Ahp = Ah + (size_t)(bm + r127) * lda + ch * 8;
  const uint16_t* Alp = Al + (size_t)(bm + r127) * lda + ch * 8;
  const uint16_t* Bhp = Bh + (size_t)(bn + r127) * ldb + koff + ch * 8;
  const uint16_t* Blp = Bl + (size_t)(bn + r127) * ldb + koff + ch * 8;
  char* l0 = lds + (uint32_t)(tid & 192) * 16;  // wave-uniform LDS base

  for (int k0 = 0; k0 < K; k0 += 32) {
    __syncthreads();
    gl16(Ahp + k0, l0 + 0);
    gl16(Ahp + k0 + 16, l0 + 4096);
    gl16(Alp + k0, l0 + 8192);
    gl16(Alp + k0 + 16, l0 + 12288);
    gl16(Bhp + k0, l0 + 16384);
    gl16(Bhp + k0 + 16, l0 + 20480);
    gl16(Blp + k0, l0 + 24576);
    gl16(Blp + k0 + 16, l0 + 28672);
    __syncthreads();
    const uint32_t kc = (uint32_t)(l >> 4) * 2048;
    const uint32_t ar = kc + (uint32_t)(wr * 64 + (l & 15)) * 16;
    const uint32_t br = kc + (uint32_t)(wc * 64 + (l & 15)) * 16;
    bf16x8 ah[4], al[4], bh[4], bl[4];
#pragma unroll
    for (int i = 0; i < 4; ++i) {
      ah[i] = *(const bf16x8*)(lds + ar + i * 256);
      al[i] = *(const bf16x8*)(lds + 8192 + ar + i * 256);
      bh[i] = *(const bf16x8*)(lds + 16384 + br + i * 256);
      bl[i] = *(const bf16x8*)(lds + 24576 + br + i * 256);
    }
#pragma unroll
    for (int mi = 0; mi < 4; ++mi)
#pragma unroll
      for (int ni = 0; ni < 4; ++ni) {
        acc[mi][ni] = __builtin_amdgcn_mfma_f32_16x16x32_bf16(ah[mi], bh[ni], acc[mi][ni], 0, 0, 0);
        acc[mi][ni] = __builtin_amdgcn_mfma_f32_16x16x32_bf16(ah[mi], bl[ni], acc[mi][ni], 0, 0, 0);
        acc[mi][ni] = __builtin_amdgcn_mfma_f32_16x16x32_bf16(al[mi], bh[ni], acc[mi][ni], 0, 0, 0);
      }
  }

  const bool facc = flags & 1, fsig = flags & 2, fhr = flags & 4, frelu = flags & 8;
#pragma unroll
  for (int mi = 0; mi < 4; ++mi) {
#pragma unroll
    for (int q = 0; q < 4; ++q) {
      int row = bm + wr * 64 + mi * 16 + (l >> 4) * 4 + q;
      if (row >= Nrows) continue;
#pragma unroll
      for (int ni = 0; ni < 4; ++ni) {
        int col = bn + wc * 64 + ni * 16 + (l & 15);
        float v = acc[mi][ni][q];
        size_t off = (size_t)row * Co + col;
        if (facc) v += bf2f(ACh[off]) + bf2f(ACl[off]);
        else if (bias) v += bias[col];
        if (fsig) v = 1.0f / (1.0f + expf(-v));
        if (fhr) {
          float rr = 1.0f / (1.0f + expf(-v));
          v = (bf2f(AXh[off]) + bf2f(AXl[off])) * rr;
        }
        if (frelu) v = fmaxf(v, 0.f);
        if (Chi) {
          uint16_t h = f2bf(v);
          Chi[off] = h;
          Clo[off] = f2bf(v - bf2f(h));
        }
        if (Cf) Cf[off] = v;
      }
    }
  }
}

// ---------------- weighted GRU combine: Hacc[node] += sum_p probs*(...) -----
template <int PB>
__global__ __launch_bounds__(256) void accum_k(
    const uint16_t* __restrict__ Zh, const uint16_t* __restrict__ Zl,
    const uint16_t* __restrict__ Hh, const uint16_t* __restrict__ Hl,
    const uint16_t* __restrict__ Th, const uint16_t* __restrict__ Tl,
    const float* __restrict__ probs, float* __restrict__ hacc, int N, int p0) {
  int node = (blockIdx.x * 256 + threadIdx.x) >> 6;
  int l = threadIdx.x & 63;
  if (node >= N) return;
  float sum[8] = {};
#pragma unroll
  for (int pr = 0; pr < PB; ++pr) {
    float pw = probs[p0 + pr];
    size_t ro = ((size_t)node * PB + pr) * 512 + l * 8;
    bf16x8 zh = *(const bf16x8*)(Zh + ro), zl = *(const bf16x8*)(Zl + ro);
    bf16x8 hh = *(const bf16x8*)(Hh + ro), hl = *(const bf16x8*)(Hl + ro);
    bf16x8 th = *(const bf16x8*)(Th + ro), tl = *(const bf16x8*)(Tl + ro);
#pragma unroll
    for (int j = 0; j < 8; ++j) {
      float z = bf2f((uint16_t)zh[j]) + bf2f((uint16_t)zl[j]);
      float h = bf2f((uint16_t)hh[j]) + bf2f((uint16_t)hl[j]);
      float t = tanhf(bf2f((uint16_t)th[j]) + bf2f((uint16_t)tl[j]));
      sum[j] += pw * (z * h + (1.0f - z) * t);
    }
  }
  float* o = hacc + (size_t)node * 512 + l * 8;
#pragma unroll
  for (int j = 0; j < 8; ++j) o[j] += sum[j];
}

// relu(Hacc) -> bf16 planes (lin1 input)
__global__ void reluconv_k(const float* __restrict__ in, uint16_t* __restrict__ oh,
                           uint16_t* __restrict__ ol, int n4) {
  int i = blockIdx.x * blockDim.x + threadIdx.x;
  if (i >= n4) return;
  float4 v = ((const float4*)in)[i];
  float a[4] = {fmaxf(v.x, 0.f), fmaxf(v.y, 0.f), fmaxf(v.z, 0.f), fmaxf(v.w, 0.f)};
  uint16_t h4[4], l4[4];
#pragma unroll
  for (int j = 0; j < 4; ++j) {
    h4[j] = f2bf(a[j]);
    l4[j] = f2bf(a[j] - bf2f(h4[j]));
  }
  ((uint2*)oh)[i] = *(uint2*)h4;
  ((uint2*)ol)[i] = *(uint2*)l4;
}

// out[i] = dot(A[i,:K], w) + b[0]
__global__ __launch_bounds__(256) void matvec_k(const float* __restrict__ A,
                                                const float* __restrict__ w,
                                                const float* __restrict__ b,
                                                float* __restrict__ out, int N, int K) {
  int gw = (blockIdx.x * 256 + threadIdx.x) >> 6;
  int lane = threadIdx.x & 63;
  if (gw >= N) return;
  float s = 0.0f;
  for (int k = lane; k < K; k += 64) s += A[(size_t)gw * K + k] * w[k];
#pragma unroll
  for (int off = 32; off > 0; off >>= 1) s += __shfl_down(s, off);
  if (lane == 0) out[gw] = s + b[0];
}

extern "C" void kernel_launch(void* const* d_in, const int* in_sizes, int n_in,
                              void* d_out, int out_size, void* d_ws, size_t ws_size,
                              hipStream_t stream) {
  const int N = 10000, F = 128, P = 4, E = 160000;
  const int C = 512, HID = 256;
  const int NC = N * C;
  (void)F; (void)in_sizes; (void)n_in;

  const float* x     = (const float*)d_in[0];
  const int*   ei    = (const int*)d_in[1];
  const float* ea    = (const float*)d_in[2];
  const float* W1    = (const float*)d_in[3];
  const float* b1    = (const float*)d_in[4];
  const float* W2    = (const float*)d_in[5];
  const float* b2    = (const float*)d_in[6];
  const float* W3    = (const float*)d_in[7];
  const float* b3    = (const float*)d_in[8];
  const float* W4    = (const float*)d_in[9];
  const float* b4    = (const float*)d_in[10];
  const float* W5    = (const float*)d_in[11];
  const float* b5    = (const float*)d_in[12];
  const float* Wz    = (const float*)d_in[13];
  const float* bz    = (const float*)d_in[14];
  const float* Lz_w  = (const float*)d_in[15];
  const float* Lz_b  = (const float*)d_in[16];
  const float* Wr    = (const float*)d_in[17];
  const float* br    = (const float*)d_in[18];
  const float* Lr_w  = (const float*)d_in[19];
  const float* Lr_b  = (const float*)d_in[20];
  const float* Wh    = (const float*)d_in[21];
  const float* bh    = (const float*)d_in[22];
  const float* Lh_w  = (const float*)d_in[23];
  const float* Lh_b  = (const float*)d_in[24];
  const float* attn  = (const float*)d_in[25];
  const float* lin1w = (const float*)d_in[26];
  const float* lin1b = (const float*)d_in[27];
  const float* lin2w = (const float*)d_in[28];
  const float* lin2b = (const float*)d_in[29];

  // ---- pick PB from ws_size ----
  auto need = [&](int PBv) -> size_t {
    size_t NBp = ((size_t)PBv * N + 127) / 128 * 128;
    return ((size_t)16 << 20) + NBp * 128 * 4 + NBp * 512 * 4 * 5;
  };
  int PB = 1;
  if (ws_size >= need(4)) PB = 4;
  else if (ws_size >= need(2)) PB = 2;
  const int NB = PB * N;
  const size_t NBp = ((size_t)NB + 127) / 128 * 128;

  // ---- workspace carve-out ----
  char* wsp = (char*)d_ws;
  auto alloc = [&](size_t bytes) -> char* {
    char* ret = wsp;
    wsp += (bytes + 255) & ~(size_t)255;
    return ret;
  };
  float* deg    = (float*)alloc((size_t)N * 4);
  float* dinv   = (float*)alloc((size_t)N * 4);
  float* dinv2  = (float*)alloc((size_t)N * 4);
  int*   counts = (int*)alloc((size_t)N * 4);
  int*   rowp   = (int*)alloc((size_t)(N + 1) * 4);
  float* normw  = (float*)alloc((size_t)E * 4);
  int*   csrs   = (int*)alloc((size_t)E * 4);
  float* csrw   = (float*)alloc((size_t)E * 4);
  float* probs  = (float*)alloc(256);

  // weight planes (transposed [Co][K])
  auto wplanes = [&](int K, int Co, uint16_t** h, uint16_t** lo) {
    *h = (uint16_t*)alloc((size_t)K * Co * 2);
    *lo = (uint16_t*)alloc((size_t)K * Co * 2);
  };
  uint16_t *W1h, *W1l, *Wzh, *Wzl, *Wrh, *Wrl, *Whh, *Whl;
  uint16_t *W2h, *W2l, *W3h, *W3l, *W4h, *W4l, *W5h, *W5l;
  uint16_t *Lzh, *Lzl, *Lrh, *Lrl, *Lhh, *Lhl, *l1h, *l1l;
  wplanes(128, 512, &W1h, &W1l);
  wplanes(128, 512, &Wzh, &Wzl);
  wplanes(128, 512, &Wrh, &Wrl);
  wplanes(128, 512, &Whh, &Whl);
  wplanes(512, 512, &W2h, &W2l);
  wplanes(512, 512, &W3h, &W3l);
  wplanes(512, 512, &W4h, &W4l);
  wplanes(512, 512, &W5h, &W5l);
  wplanes(1024, 512, &Lzh, &Lzl);
  wplanes(1024, 512, &Lrh, &Lrl);
  wplanes(1024, 512, &Lhh, &Lhl);
  wplanes(512, 256, &l1h, &l1l);

  // activation planes
  uint16_t* AXh = (uint16_t*)alloc(NBp * 128 * 2);
  uint16_t* AXl = (uint16_t*)alloc(NBp * 128 * 2);
  uint16_t* T1h = (uint16_t*)alloc(NBp * 512 * 2);
  uint16_t* T1l = (uint16_t*)alloc(NBp * 512 * 2);
  uint16_t* Uh  = (uint16_t*)alloc(NBp * 512 * 2);
  uint16_t* Ul  = (uint16_t*)alloc(NBp * 512 * 2);
  float*    Uf  = (float*)Uh;  // union: conv-phase fp32 view of (Uh|Ul)
  uint16_t* Hh  = (uint16_t*)alloc(NBp * 512 * 2);
  uint16_t* Hl  = (uint16_t*)alloc(NBp * 512 * 2);
  uint16_t* Zh  = (uint16_t*)alloc(NBp * 512 * 2);
  uint16_t* Zl  = (uint16_t*)alloc(NBp * 512 * 2);
  uint16_t* Th  = (uint16_t*)alloc(NBp * 512 * 2);
  uint16_t* Tl  = (uint16_t*)alloc(NBp * 512 * 2);

  float* Hacc = (float*)d_out + 10000;

  // ---- preprocessing ----
  hipMemsetAsync(d_out, 0, (size_t)out_size * sizeof(float), stream);
  hipMemsetAsync(counts, 0, (size_t)N * 4, stream);
  deg_init_k<<<(N + 255) / 256, 256, 0, stream>>>(deg, N);
  deg_accum_k<<<(E + 255) / 256, 256, 0, stream>>>(ei, ea, deg, E);
  dinv_k<<<(N + 255) / 256, 256, 0, stream>>>(deg, dinv, dinv2, N);
  norm_count_k<<<(E + 255) / 256, 256, 0, stream>>>(ei, ea, dinv, normw, counts, E);
  scan_k<<<1, 1024, 0, stream>>>(counts, rowp, N);
  hipMemsetAsync(counts, 0, (size_t)N * 4, stream);
  fill_k<<<(E + 255) / 256, 256, 0, stream>>>(ei, normw, rowp, counts, csrs, csrw, E);
  softmax4_k<<<1, 1, 0, stream>>>(attn, probs);

  auto wconv = [&](const float* W, uint16_t* h, uint16_t* lo, int K, int Co) {
    dim3 g(Co / 32, K / 32);
    wconv_k<<<g, 256, 0, stream>>>(W, h, lo, K, Co);
  };
  wconv(W1, W1h, W1l, 128, 512);
  wconv(Wz, Wzh, Wzl, 128, 512);
  wconv(Wr, Wrh, Wrl, 128, 512);
  wconv(Wh, Whh, Whl, 128, 512);
  wconv(W2, W2h, W2l, 512, 512);
  wconv(W3, W3h, W3l, 512, 512);
  wconv(W4, W4h, W4l, 512, 512);
  wconv(W5, W5h, W5l, 512, 512);
  wconv(Lz_w, Lzh, Lzl, 1024, 512);
  wconv(Lr_w, Lrh, Lrl, 1024, 512);
  wconv(Lh_w, Lhh, Lhl, 1024, 512);
  wconv(lin1w, l1h, l1l, 512, 256);

  auto gemm = [&](const uint16_t* Ah, const uint16_t* Al, int lda,
                  const uint16_t* Bh, const uint16_t* Bl, int ldb, int koff,
                  const float* bias, uint16_t* Chi, uint16_t* Clo, float* Cf,
                  const uint16_t* ACh, const uint16_t* ACl,
                  const uint16_t* AXh_, const uint16_t* AXl_,
                  int Nrows, int K, int Co, int flags) {
    dim3 g((Nrows + 127) / 128, Co / 128);
    gemm_sp_k<<<g, 256, 0, stream>>>(Ah, Al, lda, Bh, Bl, ldb, koff, bias,
                                     Chi, Clo, Cf, ACh, ACl, AXh_, AXl_,
                                     Nrows, K, Co, flags);
  };

  const int aggBlocks = (N * 64 + 255) / 256;
  auto run_steps = [&](int p0, auto aggK, auto agg5) {
    aggK();  // AXP planes

    // conv stack: h_{i+1} = (A h_i) W + b ; fp32 inter-buffer Uf
    gemm(AXh, AXl, 128, W1h, W1l, 128, 0, b1, nullptr, nullptr, Uf,
         nullptr, nullptr, nullptr, nullptr, NB, 128, C, 0);
    agg5();
    gemm(T1h, T1l, 512, W2h, W2l, 512, 0, b2, nullptr, nullptr, Uf,
         nullptr, nullptr, nullptr, nullptr, NB, 512, C, 0);
    agg5();
    gemm(T1h, T1l, 512, W3h, W3l, 512, 0, b3, nullptr, nullptr, Uf,
         nullptr, nullptr, nullptr, nullptr, NB, 512, C, 0);
    agg5();
    gemm(T1h, T1l, 512, W4h, W4l, 512, 0, b4, nullptr, nullptr, Uf,
         nullptr, nullptr, nullptr, nullptr, NB, 512, C, 0);
    agg5();
    gemm(T1h, T1l, 512, W5h, W5l, 512, 0, b5, Hh, Hl, nullptr,
         nullptr, nullptr, nullptr, nullptr, NB, 512, C, 0);  // H planes

    // Z gate
    gemm(AXh, AXl, 128, Wzh, Wzl, 128, 0, bz, Uh, Ul, nullptr,
         nullptr, nullptr, nullptr, nullptr, NB, 128, C, 0);          // Gz
    gemm(Uh, Ul, 512, Lzh, Lzl, 1024, 0, Lz_b, T1h, T1l, nullptr,
         nullptr, nullptr, nullptr, nullptr, NB, 512, C, 0);          // top
    gemm(Hh, Hl, 512, Lzh, Lzl, 1024, 512, nullptr, Zh, Zl, nullptr,
         T1h, T1l, nullptr, nullptr, NB, 512, C, 1 | 2);              // +bot, sigmoid

    // R gate -> HR
    gemm(AXh, AXl, 128, Wrh, Wrl, 128, 0, br, Uh, Ul, nullptr,
         nullptr, nullptr, nullptr, nullptr, NB, 128, C, 0);          // Gr
    gemm(Uh, Ul, 512, Lrh, Lrl, 1024, 0, Lr_b, T1h, T1l, nullptr,
         nullptr, nullptr, nullptr, nullptr, NB, 512, C, 0);          // top
    gemm(Hh, Hl, 512, Lrh, Lrl, 1024, 512, nullptr, Uh, Ul, nullptr,
         T1h, T1l, Hh, Hl, NB, 512, C, 1 | 4);                        // HR = H*sig

    // candidate pre-activation
    gemm(AXh, AXl, 128, Whh, Whl, 128, 0, bh, T1h, T1l, nullptr,
         nullptr, nullptr, nullptr, nullptr, NB, 128, C, 0);          // Gh
    gemm(T1h, T1l, 512, Lhh, Lhl, 1024, 0, Lh_b, Th, Tl, nullptr,
         nullptr, nullptr, nullptr, nullptr, NB, 512, C, 0);          // top
    gemm(Uh, Ul, 512, Lhh, Lhl, 1024, 512, nullptr, Th, Tl, nullptr,
         Th, Tl, nullptr, nullptr, NB, 512, C, 1);                    // +bot

    accum_k<4><<<aggBlocks, 256, 0, stream>>>(Zh, Zl, Hh, Hl, Th, Tl, probs, Hacc, N, p0);
  };

  for (int p0 = 0; p0 < P; p0 += PB) {
    if (PB == 4) {
      run_steps(p0,
        [&] { agg128_k<4><<<aggBlocks, 256, 0, stream>>>(x, AXh, AXl, rowp, csrs, csrw, dinv2, N, p0); },
        [&] { agg512_k<4><<<aggBlocks, 256, 0, stream>>>(Uf, T1h, T1l, rowp, csrs, csrw, dinv2, N); });
    } else if (PB == 2) {
      // PB=2 variant: reuse run_steps body with PB-2 agg/accum
      agg128_k<2><<<aggBlocks, 256, 0, stream>>>(x, AXh, AXl, rowp, csrs, csrw, dinv2, N, p0);
      gemm(AXh, AXl, 128, W1h, W1l, 128, 0, b1, nullptr, nullptr, Uf, nullptr, nullptr, nullptr, nullptr, NB, 128, C, 0);
      agg512_k<2><<<aggBlocks, 256, 0, stream>>>(Uf, T1h, T1l, rowp, csrs, csrw, dinv2, N);
      gemm(T1h, T1l, 512, W2h, W2l, 512, 0, b2, nullptr, nullptr, Uf, nullptr, nullptr, nullptr, nullptr, NB, 512, C, 0);
      agg512_k<2><<<aggBlocks, 256, 0, stream>>>(Uf, T1h, T1l, rowp, csrs, csrw, dinv2, N);
      gemm(T1h, T1l, 512, W3h, W3l, 512, 0, b3, nullptr, nullptr, Uf, nullptr, nullptr, nullptr, nullptr, NB, 512, C, 0);
      agg512_k<2><<<aggBlocks, 256, 0, stream>>>(Uf, T1h, T1l, rowp, csrs, csrw, dinv2, N);
      gemm(T1h, T1l, 512, W4h, W4l, 512, 0, b4, nullptr, nullptr, Uf, nullptr, nullptr, nullptr, nullptr, NB, 512, C, 0);
      agg512_k<2><<<aggBlocks, 256, 0, stream>>>(Uf, T1h, T1l, rowp, csrs, csrw, dinv2, N);
      gemm(T1h, T1l, 512, W5h, W5l, 512, 0, b5, Hh, Hl, nullptr, nullptr, nullptr, nullptr, nullptr, NB, 512, C, 0);
      gemm(AXh, AXl, 128, Wzh, Wzl, 128, 0, bz, Uh, Ul, nullptr, nullptr, nullptr, nullptr, nullptr, NB, 128, C, 0);
      gemm(Uh, Ul, 512, Lzh, Lzl, 1024, 0, Lz_b, T1h, T1l, nullptr, nullptr, nullptr, nullptr, nullptr, NB, 512, C, 0);
      gemm(Hh, Hl, 512, Lzh, Lzl, 1024, 512, nullptr, Zh, Zl, nullptr, T1h, T1l, nullptr, nullptr, NB, 512, C, 3);
      gemm(AXh, AXl, 128, Wrh, Wrl, 128, 0, br, Uh, Ul, nullptr, nullptr, nullptr, nullptr, nullptr, NB, 128, C, 0);
      gemm(Uh, Ul, 512, Lrh, Lrl, 1024, 0, Lr_b, T1h, T1l, nullptr, nullptr, nullptr, nullptr, nullptr, NB, 512, C, 0);
      gemm(Hh, Hl, 512, Lrh, Lrl, 1024, 512, nullptr, Uh, Ul, nullptr, T1h, T1l, Hh, Hl, NB, 512, C, 5);
      gemm(AXh, AXl, 128, Whh, Whl, 128, 0, bh, T1h, T1l, nullptr, nullptr, nullptr, nullptr, nullptr, NB, 128, C, 0);
      gemm(T1h, T1l, 512, Lhh, Lhl, 1024, 0, Lh_b, Th, Tl, nullptr, nullptr, nullptr, nullptr, nullptr, NB, 512, C, 0);
      gemm(Uh, Ul, 512, Lhh, Lhl, 1024, 512, nullptr, Th, Tl, nullptr, Th, Tl, nullptr, nullptr, NB, 512, C, 1);
      accum_k<2><<<aggBlocks, 256, 0, stream>>>(Zh, Zl, Hh, Hl, Th, Tl, probs, Hacc, N, p0);
    } else {
      agg128_k<1><<<aggBlocks, 256, 0, stream>>>(x, AXh, AXl, rowp, csrs, csrw, dinv2, N, p0);
      gemm(AXh, AXl, 128, W1h, W1l, 128, 0, b1, nullptr, nullptr, Uf, nullptr, nullptr, nullptr, nullptr, NB, 128, C, 0);
      agg512_k<1><<<aggBlocks, 256, 0, stream>>>(Uf, T1h, T1l, rowp, csrs, csrw, dinv2, N);
      gemm(T1h, T1l, 512, W2h, W2l, 512, 0, b2, nullptr, nullptr, Uf, nullptr, nullptr, nullptr, nullptr, NB, 512, C, 0);
      agg512_k<1><<<aggBlocks, 256, 0, stream>>>(Uf, T1h, T1l, rowp, csrs, csrw, dinv2, N);
      gemm(T1h, T1l, 512, W3h, W3l, 512, 0, b3, nullptr, nullptr, Uf, nullptr, nullptr, nullptr, nullptr, NB, 512, C, 0);
      agg512_k<1><<<aggBlocks, 256, 0, stream>>>(Uf, T1h, T1l, rowp, csrs, csrw, dinv2, N);
      gemm(T1h, T1l, 512, W4h, W4l, 512, 0, b4, nullptr, nullptr, Uf, nullptr, nullptr, nullptr, nullptr, NB, 512, C, 0);
      agg512_k<1><<<aggBlocks, 256, 0, stream>>>(Uf, T1h, T1l, rowp, csrs, csrw, dinv2, N);
      gemm(T1h, T1l, 512, W5h, W5l, 512, 0, b5, Hh, Hl, nullptr, nullptr, nullptr, nullptr, nullptr, NB, 512, C, 0);
      gemm(AXh, AXl, 128, Wzh, Wzl, 128, 0, bz, Uh, Ul, nullptr, nullptr, nullptr, nullptr, nullptr, NB, 128, C, 0);
      gemm(Uh, Ul, 512, Lzh, Lzl, 1024, 0, Lz_b, T1h, T1l, nullptr, nullptr, nullptr, nullptr, nullptr, NB, 512, C, 0);
      gemm(Hh, Hl, 512, Lzh, Lzl, 1024, 512, nullptr, Zh, Zl, nullptr, T1h, T1l, nullptr, nullptr, NB, 512, C, 3);
      gemm(AXh, AXl, 128, Wrh, Wrl, 128, 0, br, Uh, Ul, nullptr, nullptr, nullptr, nullptr, nullptr, NB, 128, C, 0);
      gemm(Uh, Ul, 512, Lrh, Lrl, 1024, 0, Lr_b, T1h, T1l, nullptr, nullptr, nullptr, nullptr, nullptr, NB, 512, C, 0);
      gemm(Hh, Hl, 512, Lrh, Lrl, 1024, 512, nullptr, Uh, Ul, nullptr, T1h, T1l, Hh, Hl, NB, 512, C, 5);
      gemm(AXh, AXl, 128, Whh, Whl, 128, 0, bh, T1h, T1l, nullptr, nullptr, nullptr, nullptr, nullptr, NB, 128, C, 0);
      gemm(T1h, T1l, 512, Lhh, Lhl, 1024, 0, Lh_b, Th, Tl, nullptr, nullptr, nullptr, nullptr, nullptr, NB, 512, C, 0);
      gemm(Uh, Ul, 512, Lhh, Lhl, 1024, 512, nullptr, Th, Tl, nullptr, Th, Tl, nullptr, nullptr, NB, 512, C, 1);
      accum_k<1><<<aggBlocks, 256, 0, stream>>>(Zh, Zl, Hh, Hl, Th, Tl, probs, Hacc, N, p0);
    }
  }

  // final MLP: relu(Hacc) -> lin1(+relu) -> lin2 matvec
  reluconv_k<<<(NC / 4 + 255) / 256, 256, 0, stream>>>(Hacc, T1h, T1l, NC / 4);
  gemm(T1h, T1l, 512, l1h, l1l, 512, 0, lin1b, nullptr, nullptr, Uf,
       nullptr, nullptr, nullptr, nullptr, N, 512, HID, 8);
  matvec_k<<<(N * 64 + 255) / 256, 256, 0, stream>>>(Uf, lin2w, lin2b, (float*)d_out, N, HID);
}

// Round 4
// 2917.378 us; speedup vs baseline: 1.4554x; 1.0814x over previous
//
#include <hip/hip_runtime.h>
#include <cstdint>
#include <cstddef>

// ---------------------------------------------------------------------------
// ConvStackedTemporalGCN — split-bf16 MFMA GEMM, gate-weight folding,
// P-interleaved aggregation. N=10000, F=128, P=4, E=160000, C=512, HID=256
//
//  * gcn(h,W,b) = (A h) W + b  (A = normalized adjacency) — A.Xp shared.
//  * Gate fold: [gcn(X,Wg,bg) | H] @ L + Lb
//        = (AX)@(Wg@L_top) + (bg@L_top + Lb) + H@L_bot
//    -> per gate ONE K=128 GEMM + ONE K=512 GEMM (was 1xK128 + 2xK512).
//  * Rows batched r = node*PB + p -> each edge gathers PB contiguous rows.
//  * GEMMs: fp32 ~= hi+lo bf16 planes; C = AhBh + AhBl + AlBh via
//    mfma_f32_16x16x32_bf16 (3-product split).
// ---------------------------------------------------------------------------

typedef short bf16x8 __attribute__((ext_vector_type(8)));
typedef float f32x4 __attribute__((ext_vector_type(4)));

__device__ __forceinline__ uint16_t f2bf(float f) {
  uint32_t u = __float_as_uint(f);
  u += 0x7FFFu + ((u >> 16) & 1u);
  return (uint16_t)(u >> 16);
}
__device__ __forceinline__ float bf2f(uint16_t h) {
  return __uint_as_float((uint32_t)h << 16);
}
__device__ __forceinline__ void gl16(const void* g, void* l) {
  __builtin_amdgcn_global_load_lds((const __attribute__((address_space(1))) uint32_t*)g,
                                   (__attribute__((address_space(3))) uint32_t*)l, 16, 0, 0);
}

// ---------------- graph preprocessing ----------------
__global__ void deg_init_k(float* deg, int N) {
  int i = blockIdx.x * blockDim.x + threadIdx.x;
  if (i < N) deg[i] = 1.0f;
}
__global__ void deg_accum_k(const int* __restrict__ ei, const float* __restrict__ ea,
                            float* deg, int E) {
  int e = blockIdx.x * blockDim.x + threadIdx.x;
  if (e < E) atomicAdd(&deg[ei[E + e]], ea[e]);
}
__global__ void dinv_k(const float* __restrict__ deg, float* dinv, float* dinv2, int N) {
  int i = blockIdx.x * blockDim.x + threadIdx.x;
  if (i < N) {
    float d = deg[i];
    float r = d > 0.0f ? rsqrtf(d) : 0.0f;
    dinv[i] = r;
    dinv2[i] = r * r;
  }
}
__global__ void count_k(const int* __restrict__ ei, int* counts, int E) {
  int e = blockIdx.x * blockDim.x + threadIdx.x;
  if (e < E) atomicAdd(&counts[ei[E + e]], 1);
}
// single-block shfl-based exclusive scan: counts -> row_ptr
__global__ void scan_k(const int* __restrict__ counts, int* row_ptr, int n) {
  __shared__ int wtot[16];
  __shared__ int carry_s;
  int tid = threadIdx.x, lane = tid & 63, w = tid >> 6;
  if (tid == 0) carry_s = 0;
  __syncthreads();
  for (int base = 0; base < n; base += 1024) {
    int i = base + tid;
    int v = (i < n) ? counts[i] : 0;
    int s = v;
#pragma unroll
    for (int off = 1; off < 64; off <<= 1) {
      int t = __shfl_up(s, off);
      if (lane >= off) s += t;
    }
    if (lane == 63) wtot[w] = s;
    __syncthreads();
    if (w == 0) {
      int t16 = (lane < 16) ? wtot[lane] : 0;
#pragma unroll
      for (int off = 1; off < 16; off <<= 1) {
        int t = __shfl_up(t16, off);
        if (lane >= off) t16 += t;
      }
      if (lane < 16) wtot[lane] = t16;
    }
    __syncthreads();
    int carry = carry_s;
    int woff = (w > 0) ? wtot[w - 1] : 0;
    int incl = carry + woff + s;
    if (i < n) row_ptr[i] = incl - v;
    __syncthreads();
    if (tid == 1023) carry_s = incl;
    __syncthreads();
  }
  if (threadIdx.x == 0) row_ptr[n] = carry_s;
}
// CSR fill, packed {src, norm-weight}; norm computed inline
__global__ void fill_k(const int* __restrict__ ei, const float* __restrict__ ea,
                       const float* __restrict__ dinv, const int* __restrict__ row_ptr,
                       int* cursor, int2* __restrict__ csrE, int E) {
  int e = blockIdx.x * blockDim.x + threadIdx.x;
  if (e < E) {
    int s = ei[e], d = ei[E + e];
    float w = dinv[s] * ea[e] * dinv[d];
    int pos = atomicAdd(&cursor[d], 1);
    csrE[row_ptr[d] + pos] = make_int2(s, __float_as_int(w));
  }
}
__global__ void softmax4_k(const float* __restrict__ attn, float* probs) {
  float a0 = attn[0], a1 = attn[1], a2 = attn[2], a3 = attn[3];
  float m = fmaxf(fmaxf(a0, a1), fmaxf(a2, a3));
  float e0 = expf(a0 - m), e1 = expf(a1 - m), e2 = expf(a2 - m), e3 = expf(a3 - m);
  float s = e0 + e1 + e2 + e3;
  probs[0] = e0 / s; probs[1] = e1 / s; probs[2] = e2 / s; probs[3] = e3 / s;
}

// ---------------- weight transpose + split:  W[K][Co] -> planes [Co][K] ----
__global__ void wconv_k(const float* __restrict__ W, uint16_t* __restrict__ Th,
                        uint16_t* __restrict__ Tl, int K, int Co) {
  __shared__ float t[32][33];
  int bco = blockIdx.x * 32, bk = blockIdx.y * 32;
  int tx = threadIdx.x & 31, ty = threadIdx.x >> 5;
  for (int r = ty; r < 32; r += 8) t[r][tx] = W[(size_t)(bk + r) * Co + bco + tx];
  __syncthreads();
  for (int r = ty; r < 32; r += 8) {
    float v = t[tx][r];
    uint16_t h = f2bf(v);
    size_t o = (size_t)(bco + r) * K + bk + tx;
    Th[o] = h;
    Tl[o] = f2bf(v - bf2f(h));
  }
}

// ---------------- gate-weight fold: O[f,c] = sum_k Wg[f,k] * Ltop[k,c] -----
// Wg [128,512], Ltop [512,512] (row-major, top half of L). Planes out [c][f].
__global__ void wfold_k(const float* __restrict__ Wg, const float* __restrict__ Ltop,
                        uint16_t* __restrict__ Oh, uint16_t* __restrict__ Ol) {
  __shared__ float a[32][33], b[32][33];
  int c0 = blockIdx.x * 32, f0 = blockIdx.y * 32;
  int tx = threadIdx.x & 31, ty = threadIdx.x >> 5;  // 32 x 8
  float acc[4] = {0.f, 0.f, 0.f, 0.f};
  for (int k0 = 0; k0 < 512; k0 += 32) {
    for (int r = ty; r < 32; r += 8) a[r][tx] = Wg[(size_t)(f0 + r) * 512 + k0 + tx];
    for (int r = ty; r < 32; r += 8) b[r][tx] = Ltop[(size_t)(k0 + r) * 512 + c0 + tx];
    __syncthreads();
    for (int kk = 0; kk < 32; ++kk) {
      float bv = b[kk][tx];
#pragma unroll
      for (int q = 0; q < 4; ++q) acc[q] += a[ty * 4 + q][kk] * bv;
    }
    __syncthreads();
  }
#pragma unroll
  for (int q = 0; q < 4; ++q) {
    int f = f0 + ty * 4 + q, c = c0 + tx;
    float v = acc[q];
    uint16_t h = f2bf(v);
    Oh[(size_t)c * 128 + f] = h;
    Ol[(size_t)c * 128 + f] = f2bf(v - bf2f(h));
  }
}
// folded biases: out[g*512+c] = Lb_g[c] + sum_k bg[k] * Lg_top[k,c]
__global__ void gbias_k(const float* bz, const float* Lz, const float* Lzb,
                        const float* br, const float* Lr, const float* Lrb,
                        const float* bh, const float* Lh, const float* Lhb,
                        float* __restrict__ out) {
  int c = blockIdx.x * 256 + threadIdx.x;
  if (c >= 1536) return;
  int g = c >> 9, cc = c & 511;
  const float* bsrc = g == 0 ? bz : (g == 1 ? br : bh);
  const float* L    = g == 0 ? Lz : (g == 1 ? Lr : Lh);
  const float* lb   = g == 0 ? Lzb : (g == 1 ? Lrb : Lhb);
  float s = lb[cc];
  for (int k = 0; k < 512; ++k) s += bsrc[k] * L[(size_t)k * 512 + cc];
  out[c] = s;
}

// ---------------- aggregation, C=512: fp32 in, bf16 hi/lo planes out -------
template <int PB>
__global__ __launch_bounds__(256) void agg512_k(
    const float* __restrict__ in, uint16_t* __restrict__ outh, uint16_t* __restrict__ outl,
    const int* __restrict__ rowp, const int2* __restrict__ csrE,
    const float* __restrict__ dinv2, int N) {
  int node = (blockIdx.x * 256 + threadIdx.x) >> 6;
  int l = threadIdx.x & 63;
  if (node >= N) return;
  float acc[PB][8];
  float w0 = dinv2[node];
  const float* sp = in + (size_t)node * PB * 512 + l * 8;
#pragma unroll
  for (int p = 0; p < PB; ++p) {
    float4 v0 = *(const float4*)(sp + (size_t)p * 512);
    float4 v1 = *(const float4*)(sp + (size_t)p * 512 + 4);
    acc[p][0] = w0 * v0.x; acc[p][1] = w0 * v0.y; acc[p][2] = w0 * v0.z; acc[p][3] = w0 * v0.w;
    acc[p][4] = w0 * v1.x; acc[p][5] = w0 * v1.y; acc[p][6] = w0 * v1.z; acc[p][7] = w0 * v1.w;
  }
  int s = rowp[node], e = rowp[node + 1];
#pragma unroll 2
  for (int idx = s; idx < e; ++idx) {
    int2 pk = csrE[idx];
    int src = pk.x;
    float w = __int_as_float(pk.y);
    const float* rp = in + (size_t)src * PB * 512 + l * 8;
#pragma unroll
    for (int p = 0; p < PB; ++p) {
      float4 v0 = *(const float4*)(rp + (size_t)p * 512);
      float4 v1 = *(const float4*)(rp + (size_t)p * 512 + 4);
      acc[p][0] += w * v0.x; acc[p][1] += w * v0.y; acc[p][2] += w * v0.z; acc[p][3] += w * v0.w;
      acc[p][4] += w * v1.x; acc[p][5] += w * v1.y; acc[p][6] += w * v1.z; acc[p][7] += w * v1.w;
    }
  }
#pragma unroll
  for (int p = 0; p < PB; ++p) {
    size_t ro = ((size_t)node * PB + p) * 512 + l * 8;
    uint16_t h8[8], l8[8];
#pragma unroll
    for (int j = 0; j < 8; ++j) {
      uint16_t h = f2bf(acc[p][j]);
      h8[j] = h;
      l8[j] = f2bf(acc[p][j] - bf2f(h));
    }
    *(bf16x8*)(outh + ro) = *(bf16x8*)h8;
    *(bf16x8*)(outl + ro) = *(bf16x8*)l8;
  }
}

// ---------------- first-hop aggregation straight from x [N][F=128][P=4] ----
template <int PB>
__global__ __launch_bounds__(256) void agg128_k(
    const float* __restrict__ x, uint16_t* __restrict__ outh, uint16_t* __restrict__ outl,
    const int* __restrict__ rowp, const int2* __restrict__ csrE,
    const float* __restrict__ dinv2, int N, int p0) {
  int node = (blockIdx.x * 256 + threadIdx.x) >> 6;
  int l = threadIdx.x & 63;
  if (node >= N) return;
  float acc[8];
  float w0 = dinv2[node];
  const float* sp = x + (size_t)node * 512 + l * 8;
  {
    float4 v0 = *(const float4*)sp;
    float4 v1 = *(const float4*)(sp + 4);
    acc[0] = w0 * v0.x; acc[1] = w0 * v0.y; acc[2] = w0 * v0.z; acc[3] = w0 * v0.w;
    acc[4] = w0 * v1.x; acc[5] = w0 * v1.y; acc[6] = w0 * v1.z; acc[7] = w0 * v1.w;
  }
  int s = rowp[node], e = rowp[node + 1];
#pragma unroll 2
  for (int idx = s; idx < e; ++idx) {
    int2 pk = csrE[idx];
    int src = pk.x;
    float w = __int_as_float(pk.y);
    const float* rp = x + (size_t)src * 512 + l * 8;
    float4 v0 = *(const float4*)rp;
    float4 v1 = *(const float4*)(rp + 4);
    acc[0] += w * v0.x; acc[1] += w * v0.y; acc[2] += w * v0.z; acc[3] += w * v0.w;
    acc[4] += w * v1.x; acc[5] += w * v1.y; acc[6] += w * v1.z; acc[7] += w * v1.w;
  }
  // slot j: f = l*2 + (j>>2) ; p = j&3   (x is [F][P] per node)
#pragma unroll
  for (int pr = 0; pr < PB; ++pr) {
    int pa = p0 + pr;
    float v0 = acc[pa], v1 = acc[4 + pa];
    uint16_t h0 = f2bf(v0), h1 = f2bf(v1);
    uint16_t lo0 = f2bf(v0 - bf2f(h0)), lo1 = f2bf(v1 - bf2f(h1));
    size_t o = ((size_t)node * PB + pr) * 128 + l * 2;
    *(uint32_t*)(outh + o) = (uint32_t)h0 | ((uint32_t)h1 << 16);
    *(uint32_t*)(outl + o) = (uint32_t)lo0 | ((uint32_t)lo1 << 16);
  }
}

// ---------------- split-bf16 GEMM: C = A@W (+bias | +ACCsrc) (+act) --------
// A planes [Nrows][K] (lda=K), W planes transposed [Co][Kfull] (ldb).
// 128x128 tile, BK=32, 256 thr (4 waves, each 64x64). 3-product split.
// flags: 1=ACC, 2=sigmoid, 4=HR (out = AUX*sigmoid(acc)), 8=relu.
__global__ __launch_bounds__(256) void gemm_sp_k(
    const uint16_t* __restrict__ Ah, const uint16_t* __restrict__ Al, int lda,
    const uint16_t* __restrict__ Bh, const uint16_t* __restrict__ Bl, int ldb, int koff,
    const float* __restrict__ bias,
    uint16_t* __restrict__ Chi, uint16_t* __restrict__ Clo, float* __restrict__ Cf,
    const uint16_t* __restrict__ ACh, const uint16_t* __restrict__ ACl,
    const uint16_t* __restrict__ AXh, const uint16_t* __restrict__ AXl,
    int Nrows, int K, int Co, int flags) {
  __shared__ char lds[32768];
  const int tid = threadIdx.x;
  const int bm = blockIdx.x * 128, bn = blockIdx.y * 128;
  const int l = tid & 63, w = tid >> 6, wr = w >> 1, wc = w & 1;

  f32x4 acc[4][4];
#pragma unroll
  for (int i = 0; i < 4; ++i)
#pragma unroll
    for (int j = 0; j < 4; ++j) acc[i][j] = (f32x4){0.f, 0.f, 0.f, 0.f};

  const int r127 = tid & 127, ch = tid >> 7;
  const uint16_t* Ahp = Ah + (size_t)(bm + r127) * lda + ch * 8;
  const uint16_t* Alp = Al + (size_t)(bm + r127) * lda + ch * 8;
  const uint16_t* Bhp = Bh + (size_t)(bn + r127) * ldb + koff + ch * 8;
  const uint16_t* Blp = Bl + (size_t)(bn + r127) * ldb + koff + ch * 8;
  char* l0 = lds + (uint32_t)(tid & 192) * 16;

  for (int k0 = 0; k0 < K; k0 += 32) {
    __syncthreads();
    gl16(Ahp + k0, l0 + 0);
    gl16(Ahp + k0 + 16, l0 + 4096);
    gl16(Alp + k0, l0 + 8192);
    gl16(Alp + k0 + 16, l0 + 12288);
    gl16(Bhp + k0, l0 + 16384);
    gl16(Bhp + k0 + 16, l0 + 20480);
    gl16(Blp + k0, l0 + 24576);
    gl16(Blp + k0 + 16, l0 + 28672);
    __syncthreads();
    const uint32_t kc = (uint32_t)(l >> 4) * 2048;
    const uint32_t ar = kc + (uint32_t)(wr * 64 + (l & 15)) * 16;
    const uint32_t br = kc + (uint32_t)(wc * 64 + (l & 15)) * 16;
    bf16x8 ah[4], al[4], bh[4], bl[4];
#pragma unroll
    for (int i = 0; i < 4; ++i) {
      ah[i] = *(const bf16x8*)(lds + ar + i * 256);
      al[i] = *(const bf16x8*)(lds + 8192 + ar + i * 256);
      bh[i] = *(const bf16x8*)(lds + 16384 + br + i * 256);
      bl[i] = *(const bf16x8*)(lds + 24576 + br + i * 256);
    }
#pragma unroll
    for (int mi = 0; mi < 4; ++mi)
#pragma unroll
      for (int ni = 0; ni < 4; ++ni) {
        acc[mi][ni] = __builtin_amdgcn_mfma_f32_16x16x32_bf16(ah[mi], bh[ni], acc[mi][ni], 0, 0, 0);
        acc[mi][ni] = __builtin_amdgcn_mfma_f32_16x16x32_bf16(ah[mi], bl[ni], acc[mi][ni], 0, 0, 0);
        acc[mi][ni] = __builtin_amdgcn_mfma_f32_16x16x32_bf16(al[mi], bh[ni], acc[mi][ni], 0, 0, 0);
      }
  }

  const bool facc = flags & 1, fsig = flags & 2, fhr = flags & 4, frelu = flags & 8;
#pragma unroll
  for (int mi = 0; mi < 4; ++mi) {
#pragma unroll
    for (int q = 0; q < 4; ++q) {
      int row = bm + wr * 64 + mi * 16 + (l >> 4) * 4 + q;
      if (row >= Nrows) continue;
#pragma unroll
      for (int ni = 0; ni < 4; ++ni) {
        int col = bn + wc * 64 + ni * 16 + (l & 15);
        float v = acc[mi][ni][q];
        size_t off = (size_t)row * Co + col;
        if (facc) v += bf2f(ACh[off]) + bf2f(ACl[off]);
        else if (bias) v += bias[col];
        if (fsig) v = 1.0f / (1.0f + expf(-v));
        if (fhr) {
          float rr = 1.0f / (1.0f + expf(-v));
          v = (bf2f(AXh[off]) + bf2f(AXl[off])) * rr;
        }
        if (frelu) v = fmaxf(v, 0.f);
        if (Chi) {
          uint16_t h = f2bf(v);
          Chi[off] = h;
          Clo[off] = f2bf(v - bf2f(h));
        }
        if (Cf) Cf[off] = v;
      }
    }
  }
}

// ---------------- GRU combine, fused (PB=4): Hacc = sum_p probs*(...) ------
// also emits relu(Hacc) bf16 planes for lin1
__global__ __launch_bounds__(256) void accum_fused_k(
    const uint16_t* __restrict__ Zh, const uint16_t* __restrict__ Zl,
    const uint16_t* __restrict__ Hh, const uint16_t* __restrict__ Hl,
    const uint16_t* __restrict__ Th, const uint16_t* __restrict__ Tl,
    const float* __restrict__ probs, float* __restrict__ hacc,
    uint16_t* __restrict__ Rh, uint16_t* __restrict__ Rl, int N) {
  int node = (blockIdx.x * 256 + threadIdx.x) >> 6;
  int l = threadIdx.x & 63;
  if (node >= N) return;
  float sum[8] = {};
#pragma unroll
  for (int pr = 0; pr < 4; ++pr) {
    float pw = probs[pr];
    size_t ro = ((size_t)node * 4 + pr) * 512 + l * 8;
    bf16x8 zh = *(const bf16x8*)(Zh + ro), zl = *(const bf16x8*)(Zl + ro);
    bf16x8 hh = *(const bf16x8*)(Hh + ro), hl = *(const bf16x8*)(Hl + ro);
    bf16x8 th = *(const bf16x8*)(Th + ro), tl = *(const bf16x8*)(Tl + ro);
#pragma unroll
    for (int j = 0; j < 8; ++j) {
      float z = bf2f((uint16_t)zh[j]) + bf2f((uint16_t)zl[j]);
      float h = bf2f((uint16_t)hh[j]) + bf2f((uint16_t)hl[j]);
      float t = tanhf(bf2f((uint16_t)th[j]) + bf2f((uint16_t)tl[j]));
      sum[j] += pw * (z * h + (1.0f - z) * t);
    }
  }
  float* o = hacc + (size_t)node * 512 + l * 8;
  uint16_t h8[8], l8[8];
#pragma unroll
  for (int j = 0; j < 8; ++j) {
    o[j] = sum[j];
    float rv = fmaxf(sum[j], 0.f);
    uint16_t h = f2bf(rv);
    h8[j] = h;
    l8[j] = f2bf(rv - bf2f(h));
  }
  size_t po = (size_t)node * 512 + l * 8;
  *(bf16x8*)(Rh + po) = *(bf16x8*)h8;
  *(bf16x8*)(Rl + po) = *(bf16x8*)l8;
}

// fallback (PB<4): Hacc += sum
template <int PB>
__global__ __launch_bounds__(256) void accum_k(
    const uint16_t* __restrict__ Zh, const uint16_t* __restrict__ Zl,
    const uint16_t* __restrict__ Hh, const uint16_t* __restrict__ Hl,
    const uint16_t* __restrict__ Th, const uint16_t* __restrict__ Tl,
    const float* __restrict__ probs, float* __restrict__ hacc, int N, int p0) {
  int node = (blockIdx.x * 256 + threadIdx.x) >> 6;
  int l = threadIdx.x & 63;
  if (node >= N) return;
  float sum[8] = {};
#pragma unroll
  for (int pr = 0; pr < PB; ++pr) {
    float pw = probs[p0 + pr];
    size_t ro = ((size_t)node * PB + pr) * 512 + l * 8;
    bf16x8 zh = *(const bf16x8*)(Zh + ro), zl = *(const bf16x8*)(Zl + ro);
    bf16x8 hh = *(const bf16x8*)(Hh + ro), hl = *(const bf16x8*)(Hl + ro);
    bf16x8 th = *(const bf16x8*)(Th + ro), tl = *(const bf16x8*)(Tl + ro);
#pragma unroll
    for (int j = 0; j < 8; ++j) {
      float z = bf2f((uint16_t)zh[j]) + bf2f((uint16_t)zl[j]);
      float h = bf2f((uint16_t)hh[j]) + bf2f((uint16_t)hl[j]);
      float t = tanhf(bf2f((uint16_t)th[j]) + bf2f((uint16_t)tl[j]));
      sum[j] += pw * (z * h + (1.0f - z) * t);
    }
  }
  float* o = hacc + (size_t)node * 512 + l * 8;
#pragma unroll
  for (int j = 0; j < 8; ++j) o[j] += sum[j];
}

// relu(Hacc) -> bf16 planes (fallback path)
__global__ void reluconv_k(const float* __restrict__ in, uint16_t* __restrict__ oh,
                           uint16_t* __restrict__ ol, int n4) {
  int i = blockIdx.x * blockDim.x + threadIdx.x;
  if (i >= n4) return;
  float4 v = ((const float4*)in)[i];
  float a[4] = {fmaxf(v.x, 0.f), fmaxf(v.y, 0.f), fmaxf(v.z, 0.f), fmaxf(v.w, 0.f)};
  uint16_t h4[4], l4[4];
#pragma unroll
  for (int j = 0; j < 4; ++j) {
    h4[j] = f2bf(a[j]);
    l4[j] = f2bf(a[j] - bf2f(h4[j]));
  }
  ((uint2*)oh)[i] = *(uint2*)h4;
  ((uint2*)ol)[i] = *(uint2*)l4;
}

// out[i] = dot(A[i,:K], w) + b[0]
__global__ __launch_bounds__(256) void matvec_k(const float* __restrict__ A,
                                                const float* __restrict__ w,
                                                const float* __restrict__ b,
                                                float* __restrict__ out, int N, int K) {
  int gw = (blockIdx.x * 256 + threadIdx.x) >> 6;
  int lane = threadIdx.x & 63;
  if (gw >= N) return;
  float s = 0.0f;
  for (int k = lane; k < K; k += 64) s += A[(size_t)gw * K + k] * w[k];
#pragma unroll
  for (int off = 32; off > 0; off >>= 1) s += __shfl_down(s, off);
  if (lane == 0) out[gw] = s + b[0];
}

extern "C" void kernel_launch(void* const* d_in, const int* in_sizes, int n_in,
                              void* d_out, int out_size, void* d_ws, size_t ws_size,
                              hipStream_t stream) {
  const int N = 10000, F = 128, P = 4, E = 160000;
  const int C = 512, HID = 256;
  const int NC = N * C;
  (void)F; (void)in_sizes; (void)n_in;

  const float* x     = (const float*)d_in[0];
  const int*   ei    = (const int*)d_in[1];
  const float* ea    = (const float*)d_in[2];
  const float* W1    = (const float*)d_in[3];
  const float* b1    = (const float*)d_in[4];
  const float* W2    = (const float*)d_in[5];
  const float* b2    = (const float*)d_in[6];
  const float* W3    = (const float*)d_in[7];
  const float* b3    = (const float*)d_in[8];
  const float* W4    = (const float*)d_in[9];
  const float* b4    = (const float*)d_in[10];
  const float* W5    = (const float*)d_in[11];
  const float* b5    = (const float*)d_in[12];
  const float* Wz    = (const float*)d_in[13];
  const float* bz    = (const float*)d_in[14];
  const float* Lz_w  = (const float*)d_in[15];
  const float* Lz_b  = (const float*)d_in[16];
  const float* Wr    = (const float*)d_in[17];
  const float* br    = (const float*)d_in[18];
  const float* Lr_w  = (const float*)d_in[19];
  const float* Lr_b  = (const float*)d_in[20];
  const float* Wh    = (const float*)d_in[21];
  const float* bh    = (const float*)d_in[22];
  const float* Lh_w  = (const float*)d_in[23];
  const float* Lh_b  = (const float*)d_in[24];
  const float* attn  = (const float*)d_in[25];
  const float* lin1w = (const float*)d_in[26];
  const float* lin1b = (const float*)d_in[27];
  const float* lin2w = (const float*)d_in[28];
  const float* lin2b = (const float*)d_in[29];

  // ---- pick PB from ws_size (same bound as R3 so PB choice is stable) ----
  auto need = [&](int PBv) -> size_t {
    size_t NBp = ((size_t)PBv * N + 127) / 128 * 128;
    return ((size_t)16 << 20) + NBp * 128 * 4 + NBp * 512 * 4 * 5;
  };
  int PB = 1;
  if (ws_size >= need(4)) PB = 4;
  else if (ws_size >= need(2)) PB = 2;
  const int NB = PB * N;

  // ---- workspace carve-out ----
  char* wsp = (char*)d_ws;
  auto alloc = [&](size_t bytes) -> char* {
    char* ret = wsp;
    wsp += (bytes + 255) & ~(size_t)255;
    return ret;
  };
  float* deg    = (float*)alloc((size_t)N * 4);
  float* dinv   = (float*)alloc((size_t)N * 4);
  float* dinv2  = (float*)alloc((size_t)N * 4);
  int*   counts = (int*)alloc((size_t)N * 4);
  int*   rowp   = (int*)alloc((size_t)(N + 1) * 4);
  int2*  csrE   = (int2*)alloc((size_t)E * 8);
  float* probs  = (float*)alloc(256);

  auto wplanes = [&](int K, int Co, uint16_t** h, uint16_t** lo) {
    *h = (uint16_t*)alloc((size_t)K * Co * 2);
    *lo = (uint16_t*)alloc((size_t)K * Co * 2);
  };
  uint16_t *W1h, *W1l, *W2h, *W2l, *W3h, *W3l, *W4h, *W4l, *W5h, *W5l;
  uint16_t *LzBh, *LzBl, *LrBh, *LrBl, *LhBh, *LhBl, *l1h, *l1l;
  uint16_t *GzH, *GzL, *GrH, *GrL, *GhH, *GhL;
  wplanes(128, 512, &W1h, &W1l);
  wplanes(512, 512, &W2h, &W2l);
  wplanes(512, 512, &W3h, &W3l);
  wplanes(512, 512, &W4h, &W4l);
  wplanes(512, 512, &W5h, &W5l);
  wplanes(512, 512, &LzBh, &LzBl);   // L*_bot planes [512][512]
  wplanes(512, 512, &LrBh, &LrBl);
  wplanes(512, 512, &LhBh, &LhBl);
  wplanes(512, 256, &l1h, &l1l);
  wplanes(128, 512, &GzH, &GzL);     // folded gate weights [512][128]
  wplanes(128, 512, &GrH, &GrL);
  wplanes(128, 512, &GhH, &GhL);
  float* gbias = (float*)alloc(1536 * 4);  // z | r | h folded biases

  const size_t NBp = ((size_t)NB + 127) / 128 * 128;
  uint16_t* AXh = (uint16_t*)alloc(NBp * 128 * 2);
  uint16_t* AXl = (uint16_t*)alloc(NBp * 128 * 2);
  uint16_t* T1h = (uint16_t*)alloc(NBp * 512 * 2);
  uint16_t* T1l = (uint16_t*)alloc(NBp * 512 * 2);
  uint16_t* Uh  = (uint16_t*)alloc(NBp * 512 * 2);
  uint16_t* Ul  = (uint16_t*)alloc(NBp * 512 * 2);
  float*    Uf  = (float*)Uh;  // fp32 view spanning Uh+Ul (contiguous)
  uint16_t* Hh  = (uint16_t*)alloc(NBp * 512 * 2);
  uint16_t* Hl  = (uint16_t*)alloc(NBp * 512 * 2);
  uint16_t* Zh  = (uint16_t*)alloc(NBp * 512 * 2);
  uint16_t* Zl  = (uint16_t*)alloc(NBp * 512 * 2);
  uint16_t* Th  = (uint16_t*)alloc(NBp * 512 * 2);
  uint16_t* Tl  = (uint16_t*)alloc(NBp * 512 * 2);

  float* Hacc = (float*)d_out + 10000;

  // ---- preprocessing ----
  if (PB != 4) hipMemsetAsync(d_out, 0, (size_t)out_size * sizeof(float), stream);
  hipMemsetAsync(counts, 0, (size_t)N * 4, stream);
  deg_init_k<<<(N + 255) / 256, 256, 0, stream>>>(deg, N);
  deg_accum_k<<<(E + 255) / 256, 256, 0, stream>>>(ei, ea, deg, E);
  dinv_k<<<(N + 255) / 256, 256, 0, stream>>>(deg, dinv, dinv2, N);
  count_k<<<(E + 255) / 256, 256, 0, stream>>>(ei, counts, E);
  scan_k<<<1, 1024, 0, stream>>>(counts, rowp, N);
  hipMemsetAsync(counts, 0, (size_t)N * 4, stream);
  fill_k<<<(E + 255) / 256, 256, 0, stream>>>(ei, ea, dinv, rowp, counts, csrE, E);
  softmax4_k<<<1, 1, 0, stream>>>(attn, probs);

  auto wconv = [&](const float* W, uint16_t* h, uint16_t* lo, int K, int Co) {
    dim3 g(Co / 32, K / 32);
    wconv_k<<<g, 256, 0, stream>>>(W, h, lo, K, Co);
  };
  wconv(W1, W1h, W1l, 128, 512);
  wconv(W2, W2h, W2l, 512, 512);
  wconv(W3, W3h, W3l, 512, 512);
  wconv(W4, W4h, W4l, 512, 512);
  wconv(W5, W5h, W5l, 512, 512);
  wconv(Lz_w + (size_t)512 * 512, LzBh, LzBl, 512, 512);  // bottom halves
  wconv(Lr_w + (size_t)512 * 512, LrBh, LrBl, 512, 512);
  wconv(Lh_w + (size_t)512 * 512, LhBh, LhBl, 512, 512);
  wconv(lin1w, l1h, l1l, 512, 256);
  {
    dim3 g(16, 4);
    wfold_k<<<g, 256, 0, stream>>>(Wz, Lz_w, GzH, GzL);
    wfold_k<<<g, 256, 0, stream>>>(Wr, Lr_w, GrH, GrL);
    wfold_k<<<g, 256, 0, stream>>>(Wh, Lh_w, GhH, GhL);
  }
  gbias_k<<<6, 256, 0, stream>>>(bz, Lz_w, Lz_b, br, Lr_w, Lr_b, bh, Lh_w, Lh_b, gbias);

  auto gemm = [&](const uint16_t* Ah, const uint16_t* Al, int lda,
                  const uint16_t* Bh, const uint16_t* Bl, int ldb,
                  const float* bias, uint16_t* Chi, uint16_t* Clo, float* Cf,
                  const uint16_t* ACh, const uint16_t* ACl,
                  const uint16_t* AXh_, const uint16_t* AXl_,
                  int Nrows, int K, int Co, int flags) {
    dim3 g((Nrows + 127) / 128, Co / 128);
    gemm_sp_k<<<g, 256, 0, stream>>>(Ah, Al, lda, Bh, Bl, ldb, 0, bias,
                                     Chi, Clo, Cf, ACh, ACl, AXh_, AXl_,
                                     Nrows, K, Co, flags);
  };

  const int aggBlocks = (N * 64 + 255) / 256;
  auto agg5 = [&](const float* in) {
    if (PB == 4)      agg512_k<4><<<aggBlocks, 256, 0, stream>>>(in, T1h, T1l, rowp, csrE, dinv2, N);
    else if (PB == 2) agg512_k<2><<<aggBlocks, 256, 0, stream>>>(in, T1h, T1l, rowp, csrE, dinv2, N);
    else              agg512_k<1><<<aggBlocks, 256, 0, stream>>>(in, T1h, T1l, rowp, csrE, dinv2, N);
  };

  for (int p0 = 0; p0 < P; p0 += PB) {
    if (PB == 4)      agg128_k<4><<<aggBlocks, 256, 0, stream>>>(x, AXh, AXl, rowp, csrE, dinv2, N, p0);
    else if (PB == 2) agg128_k<2><<<aggBlocks, 256, 0, stream>>>(x, AXh, AXl, rowp, csrE, dinv2, N, p0);
    else              agg128_k<1><<<aggBlocks, 256, 0, stream>>>(x, AXh, AXl, rowp, csrE, dinv2, N, p0);

    // conv stack: h_{i+1} = (A h_i) W + b
    gemm(AXh, AXl, 128, W1h, W1l, 128, b1, nullptr, nullptr, Uf,
         nullptr, nullptr, nullptr, nullptr, NB, 128, C, 0);
    agg5(Uf);
    gemm(T1h, T1l, 512, W2h, W2l, 512, b2, nullptr, nullptr, Uf,
         nullptr, nullptr, nullptr, nullptr, NB, 512, C, 0);
    agg5(Uf);
    gemm(T1h, T1l, 512, W3h, W3l, 512, b3, nullptr, nullptr, Uf,
         nullptr, nullptr, nullptr, nullptr, NB, 512, C, 0);
    agg5(Uf);
    gemm(T1h, T1l, 512, W4h, W4l, 512, b4, nullptr, nullptr, Uf,
         nullptr, nullptr, nullptr, nullptr, NB, 512, C, 0);
    agg5(Uf);
    gemm(T1h, T1l, 512, W5h, W5l, 512, b5, Hh, Hl, nullptr,
         nullptr, nullptr, nullptr, nullptr, NB, 512, C, 0);  // H planes

    // gates (folded tops, K=128)
    gemm(AXh, AXl, 128, GzH, GzL, 128, gbias, T1h, T1l, nullptr,
         nullptr, nullptr, nullptr, nullptr, NB, 128, C, 0);          // Z top
    gemm(Hh, Hl, 512, LzBh, LzBl, 512, nullptr, Zh, Zl, nullptr,
         T1h, T1l, nullptr, nullptr, NB, 512, C, 1 | 2);              // Z = sig(top+bot)
    gemm(AXh, AXl, 128, GrH, GrL, 128, gbias + 512, T1h, T1l, nullptr,
         nullptr, nullptr, nullptr, nullptr, NB, 128, C, 0);          // R top
    gemm(Hh, Hl, 512, LrBh, LrBl, 512, nullptr, Uh, Ul, nullptr,
         T1h, T1l, Hh, Hl, NB, 512, C, 1 | 4);                        // HR = H*sig
    gemm(AXh, AXl, 128, GhH, GhL, 128, gbias + 1024, T1h, T1l, nullptr,
         nullptr, nullptr, nullptr, nullptr, NB, 128, C, 0);          // Ht top
    gemm(Uh, Ul, 512, LhBh, LhBl, 512, nullptr, Th, Tl, nullptr,
         T1h, T1l, nullptr, nullptr, NB, 512, C, 1);                  // Ht pre

    if (PB == 4)
      accum_fused_k<<<aggBlocks, 256, 0, stream>>>(Zh, Zl, Hh, Hl, Th, Tl, probs,
                                                   Hacc, T1h, T1l, N);
    else if (PB == 2)
      accum_k<2><<<aggBlocks, 256, 0, stream>>>(Zh, Zl, Hh, Hl, Th, Tl, probs, Hacc, N, p0);
    else
      accum_k<1><<<aggBlocks, 256, 0, stream>>>(Zh, Zl, Hh, Hl, Th, Tl, probs, Hacc, N, p0);
  }

  if (PB != 4)
    reluconv_k<<<(NC / 4 + 255) / 256, 256, 0, stream>>>(Hacc, T1h, T1l, NC / 4);

  // final MLP: relu(Hacc) -> lin1(+relu) -> lin2 matvec
  gemm(T1h, T1l, 512, l1h, l1l, 512, lin1b, nullptr, nullptr, Uf,
       nullptr, nullptr, nullptr, nullptr, N, 512, HID, 8);
  matvec_k<<<(N * 64 + 255) / 256, 256, 0, stream>>>(Uf, lin2w, lin2b, (float*)d_out, N, HID);
}

// Round 5
// 2624.500 us; speedup vs baseline: 1.6178x; 1.1116x over previous
//
#include <hip/hip_runtime.h>
#include <cstdint>
#include <cstddef>

// ---------------------------------------------------------------------------
// ConvStackedTemporalGCN — split-bf16 MFMA GEMM, gate folding, batched GEMMs
// N=10000, F=128, P=4, E=160000, C=512, HID=256
//  * gcn(h,W,b) = (A h) W + b ; A.Xp shared across W1/gates.
//  * Gate fold: top = (AX)@(Wg@L_top) + folded bias ; bot = H@L_bot.
//  * Segmented GEMM: one dispatch covers several 512-col output segments
//    with independent epilogues (batch 3 gate tops; batch Zbot+Rbot).
//  * Rows r = node*PB + p (P-interleaved) -> edge gathers PB contiguous rows.
//  * fp32 ~= hi+lo bf16 planes; C = AhBh + AhBl + AlBh (3-product split).
// ---------------------------------------------------------------------------

typedef short bf16x8 __attribute__((ext_vector_type(8)));
typedef float f32x4 __attribute__((ext_vector_type(4)));

__device__ __forceinline__ uint16_t f2bf(float f) {
  uint32_t u = __float_as_uint(f);
  u += 0x7FFFu + ((u >> 16) & 1u);
  return (uint16_t)(u >> 16);
}
__device__ __forceinline__ float bf2f(uint16_t h) {
  return __uint_as_float((uint32_t)h << 16);
}
__device__ __forceinline__ void gl16(const void* g, void* l) {
  __builtin_amdgcn_global_load_lds((const __attribute__((address_space(1))) uint32_t*)g,
                                   (__attribute__((address_space(3))) uint32_t*)l, 16, 0, 0);
}

// ---------------- graph preprocessing (fused) ----------------
__global__ void init_k(float* deg, int* counts, int N) {
  int i = blockIdx.x * blockDim.x + threadIdx.x;
  if (i < N) { deg[i] = 1.0f; counts[i] = 0; }
}
__global__ void edge_k(const int* __restrict__ ei, const float* __restrict__ ea,
                       float* deg, int* counts, int E) {
  int e = blockIdx.x * blockDim.x + threadIdx.x;
  if (e < E) {
    int d = ei[E + e];
    atomicAdd(&deg[d], ea[e]);
    atomicAdd(&counts[d], 1);
  }
}
__global__ void dinv_k(const float* __restrict__ deg, float* dinv, float* dinv2, int N) {
  int i = blockIdx.x * blockDim.x + threadIdx.x;
  if (i < N) {
    float d = deg[i];
    float r = d > 0.0f ? rsqrtf(d) : 0.0f;
    dinv[i] = r;
    dinv2[i] = r * r;
  }
}
// shfl exclusive scan (counts -> row_ptr), re-zeroes counts, + softmax(attn)
__global__ void scan_sm_k(int* __restrict__ counts, int* row_ptr, int n,
                          const float* __restrict__ attn, float* probs) {
  __shared__ int wtot[16];
  __shared__ int carry_s;
  int tid = threadIdx.x, lane = tid & 63, w = tid >> 6;
  if (tid == 0) carry_s = 0;
  __syncthreads();
  for (int base = 0; base < n; base += 1024) {
    int i = base + tid;
    int v = 0;
    if (i < n) { v = counts[i]; counts[i] = 0; }
    int s = v;
#pragma unroll
    for (int off = 1; off < 64; off <<= 1) {
      int t = __shfl_up(s, off);
      if (lane >= off) s += t;
    }
    if (lane == 63) wtot[w] = s;
    __syncthreads();
    if (w == 0) {
      int t16 = (lane < 16) ? wtot[lane] : 0;
#pragma unroll
      for (int off = 1; off < 16; off <<= 1) {
        int t = __shfl_up(t16, off);
        if (lane >= off) t16 += t;
      }
      if (lane < 16) wtot[lane] = t16;
    }
    __syncthreads();
    int carry = carry_s;
    int woff = (w > 0) ? wtot[w - 1] : 0;
    int incl = carry + woff + s;
    if (i < n) row_ptr[i] = incl - v;
    __syncthreads();
    if (tid == 1023) carry_s = incl;
    __syncthreads();
  }
  if (tid == 0) {
    row_ptr[n] = carry_s;
    float a0 = attn[0], a1 = attn[1], a2 = attn[2], a3 = attn[3];
    float m = fmaxf(fmaxf(a0, a1), fmaxf(a2, a3));
    float e0 = expf(a0 - m), e1 = expf(a1 - m), e2 = expf(a2 - m), e3 = expf(a3 - m);
    float s4 = e0 + e1 + e2 + e3;
    probs[0] = e0 / s4; probs[1] = e1 / s4; probs[2] = e2 / s4; probs[3] = e3 / s4;
  }
}
__global__ void fill_k(const int* __restrict__ ei, const float* __restrict__ ea,
                       const float* __restrict__ dinv, const int* __restrict__ row_ptr,
                       int* cursor, int2* __restrict__ csrE, int E) {
  int e = blockIdx.x * blockDim.x + threadIdx.x;
  if (e < E) {
    int s = ei[e], d = ei[E + e];
    float w = dinv[s] * ea[e] * dinv[d];
    int pos = atomicAdd(&cursor[d], 1);
    csrE[row_ptr[d] + pos] = make_int2(s, __float_as_int(w));
  }
}

// ---------------- all weight transposes+splits in one launch ----------------
struct WCdesc {
  const float* src[9];
  uint16_t* dh[9];
  uint16_t* dl[9];
  int K[9];
  int Co[9];
};
__global__ void wconv_all_k(WCdesc d) {
  int z = blockIdx.z;
  int K, Co;
  const float* W;
  uint16_t *Th, *Tl;
  switch (z) {  // constant-index selects (avoid scratch)
    case 0: W = d.src[0]; Th = d.dh[0]; Tl = d.dl[0]; K = d.K[0]; Co = d.Co[0]; break;
    case 1: W = d.src[1]; Th = d.dh[1]; Tl = d.dl[1]; K = d.K[1]; Co = d.Co[1]; break;
    case 2: W = d.src[2]; Th = d.dh[2]; Tl = d.dl[2]; K = d.K[2]; Co = d.Co[2]; break;
    case 3: W = d.src[3]; Th = d.dh[3]; Tl = d.dl[3]; K = d.K[3]; Co = d.Co[3]; break;
    case 4: W = d.src[4]; Th = d.dh[4]; Tl = d.dl[4]; K = d.K[4]; Co = d.Co[4]; break;
    case 5: W = d.src[5]; Th = d.dh[5]; Tl = d.dl[5]; K = d.K[5]; Co = d.Co[5]; break;
    case 6: W = d.src[6]; Th = d.dh[6]; Tl = d.dl[6]; K = d.K[6]; Co = d.Co[6]; break;
    case 7: W = d.src[7]; Th = d.dh[7]; Tl = d.dl[7]; K = d.K[7]; Co = d.Co[7]; break;
    default: W = d.src[8]; Th = d.dh[8]; Tl = d.dl[8]; K = d.K[8]; Co = d.Co[8]; break;
  }
  int bco = blockIdx.x * 32, bk = blockIdx.y * 32;
  if (bco >= Co || bk >= K) return;
  __shared__ float t[32][33];
  int tx = threadIdx.x & 31, ty = threadIdx.x >> 5;
  for (int r = ty; r < 32; r += 8) t[r][tx] = W[(size_t)(bk + r) * Co + bco + tx];
  __syncthreads();
  for (int r = ty; r < 32; r += 8) {
    float v = t[tx][r];
    uint16_t h = f2bf(v);
    size_t o = (size_t)(bco + r) * K + bk + tx;
    Th[o] = h;
    Tl[o] = f2bf(v - bf2f(h));
  }
}

// ---------------- 3 gate-weight folds in one launch ------------------------
// O_g[f,c] = sum_k Wg[f,k]*Ltop_g[k,c]; planes out [1536][128] (seg g at g*512)
struct WFdesc { const float* Wg[3]; const float* Lt[3]; };
__global__ void wfold3_k(WFdesc d, uint16_t* __restrict__ Oh, uint16_t* __restrict__ Ol) {
  int z = blockIdx.z;
  const float *Wg, *Lt;
  switch (z) {
    case 0: Wg = d.Wg[0]; Lt = d.Lt[0]; break;
    case 1: Wg = d.Wg[1]; Lt = d.Lt[1]; break;
    default: Wg = d.Wg[2]; Lt = d.Lt[2]; break;
  }
  __shared__ float a[32][33], b[32][33];
  int c0 = blockIdx.x * 32, f0 = blockIdx.y * 32;
  int tx = threadIdx.x & 31, ty = threadIdx.x >> 5;
  float acc[4] = {0.f, 0.f, 0.f, 0.f};
  for (int k0 = 0; k0 < 512; k0 += 32) {
    for (int r = ty; r < 32; r += 8) a[r][tx] = Wg[(size_t)(f0 + r) * 512 + k0 + tx];
    for (int r = ty; r < 32; r += 8) b[r][tx] = Lt[(size_t)(k0 + r) * 512 + c0 + tx];
    __syncthreads();
    for (int kk = 0; kk < 32; ++kk) {
      float bv = b[kk][tx];
#pragma unroll
      for (int q = 0; q < 4; ++q) acc[q] += a[ty * 4 + q][kk] * bv;
    }
    __syncthreads();
  }
  size_t base = (size_t)z * 512 * 128;
#pragma unroll
  for (int q = 0; q < 4; ++q) {
    int f = f0 + ty * 4 + q, c = c0 + tx;
    float v = acc[q];
    uint16_t h = f2bf(v);
    Oh[base + (size_t)c * 128 + f] = h;
    Ol[base + (size_t)c * 128 + f] = f2bf(v - bf2f(h));
  }
}
// folded biases: out[g*512+c] = Lb_g[c] + sum_k bg[k] * Lg_top[k,c]
__global__ void gbias_k(const float* bz, const float* Lz, const float* Lzb,
                        const float* br, const float* Lr, const float* Lrb,
                        const float* bh, const float* Lh, const float* Lhb,
                        float* __restrict__ out) {
  int c = blockIdx.x * 256 + threadIdx.x;
  if (c >= 1536) return;
  int g = c >> 9, cc = c & 511;
  const float* bsrc = g == 0 ? bz : (g == 1 ? br : bh);
  const float* L    = g == 0 ? Lz : (g == 1 ? Lr : Lh);
  const float* lb   = g == 0 ? Lzb : (g == 1 ? Lrb : Lhb);
  float s = lb[cc];
  for (int k = 0; k < 512; ++k) s += bsrc[k] * L[(size_t)k * 512 + cc];
  out[c] = s;
}

// ---------------- aggregation, C=512: SP waves per node --------------------
template <int PB, int SP>
__global__ __launch_bounds__(256) void agg512_k(
    const float* __restrict__ in, uint16_t* __restrict__ outh, uint16_t* __restrict__ outl,
    const int* __restrict__ rowp, const int2* __restrict__ csrE,
    const float* __restrict__ dinv2, int N) {
  const int RP = PB / SP;  // rows handled per wave
  int gw = (blockIdx.x * 256 + threadIdx.x) >> 6;
  int l = threadIdx.x & 63;
  if (gw >= N * SP) return;
  int node = gw / SP;
  int rb = (gw - node * SP) * RP;
  float acc[RP][8];
  float w0 = dinv2[node];
  const float* sp = in + ((size_t)node * PB + rb) * 512 + l * 8;
#pragma unroll
  for (int p = 0; p < RP; ++p) {
    float4 v0 = *(const float4*)(sp + (size_t)p * 512);
    float4 v1 = *(const float4*)(sp + (size_t)p * 512 + 4);
    acc[p][0] = w0 * v0.x; acc[p][1] = w0 * v0.y; acc[p][2] = w0 * v0.z; acc[p][3] = w0 * v0.w;
    acc[p][4] = w0 * v1.x; acc[p][5] = w0 * v1.y; acc[p][6] = w0 * v1.z; acc[p][7] = w0 * v1.w;
  }
  int s = rowp[node], e = rowp[node + 1];
#pragma unroll 2
  for (int idx = s; idx < e; ++idx) {
    int2 pk = csrE[idx];
    int src = pk.x;
    float w = __int_as_float(pk.y);
    const float* rp = in + ((size_t)src * PB + rb) * 512 + l * 8;
#pragma unroll
    for (int p = 0; p < RP; ++p) {
      float4 v0 = *(const float4*)(rp + (size_t)p * 512);
      float4 v1 = *(const float4*)(rp + (size_t)p * 512 + 4);
      acc[p][0] += w * v0.x; acc[p][1] += w * v0.y; acc[p][2] += w * v0.z; acc[p][3] += w * v0.w;
      acc[p][4] += w * v1.x; acc[p][5] += w * v1.y; acc[p][6] += w * v1.z; acc[p][7] += w * v1.w;
    }
  }
#pragma unroll
  for (int p = 0; p < RP; ++p) {
    size_t ro = ((size_t)node * PB + rb + p) * 512 + l * 8;
    uint16_t h8[8], l8[8];
#pragma unroll
    for (int j = 0; j < 8; ++j) {
      uint16_t h = f2bf(acc[p][j]);
      h8[j] = h;
      l8[j] = f2bf(acc[p][j] - bf2f(h));
    }
    *(bf16x8*)(outh + ro) = *(bf16x8*)h8;
    *(bf16x8*)(outl + ro) = *(bf16x8*)l8;
  }
}

// ---------------- first-hop aggregation from x [N][F=128][P=4] -------------
template <int PB>
__global__ __launch_bounds__(256) void agg128_k(
    const float* __restrict__ x, uint16_t* __restrict__ outh, uint16_t* __restrict__ outl,
    const int* __restrict__ rowp, const int2* __restrict__ csrE,
    const float* __restrict__ dinv2, int N, int p0) {
  int node = (blockIdx.x * 256 + threadIdx.x) >> 6;
  int l = threadIdx.x & 63;
  if (node >= N) return;
  float acc[8];
  float w0 = dinv2[node];
  const float* sp = x + (size_t)node * 512 + l * 8;
  {
    float4 v0 = *(const float4*)sp;
    float4 v1 = *(const float4*)(sp + 4);
    acc[0] = w0 * v0.x; acc[1] = w0 * v0.y; acc[2] = w0 * v0.z; acc[3] = w0 * v0.w;
    acc[4] = w0 * v1.x; acc[5] = w0 * v1.y; acc[6] = w0 * v1.z; acc[7] = w0 * v1.w;
  }
  int s = rowp[node], e = rowp[node + 1];
#pragma unroll 2
  for (int idx = s; idx < e; ++idx) {
    int2 pk = csrE[idx];
    int src = pk.x;
    float w = __int_as_float(pk.y);
    const float* rp = x + (size_t)src * 512 + l * 8;
    float4 v0 = *(const float4*)rp;
    float4 v1 = *(const float4*)(rp + 4);
    acc[0] += w * v0.x; acc[1] += w * v0.y; acc[2] += w * v0.z; acc[3] += w * v0.w;
    acc[4] += w * v1.x; acc[5] += w * v1.y; acc[6] += w * v1.z; acc[7] += w * v1.w;
  }
  // slot j: f = l*2 + (j>>2) ; p = j&3
#pragma unroll
  for (int pr = 0; pr < PB; ++pr) {
    int pa = p0 + pr;
    float v0 = acc[pa], v1 = acc[4 + pa];
    uint16_t h0 = f2bf(v0), h1 = f2bf(v1);
    uint16_t lo0 = f2bf(v0 - bf2f(h0)), lo1 = f2bf(v1 - bf2f(h1));
    size_t o = ((size_t)node * PB + pr) * 128 + l * 2;
    *(uint32_t*)(outh + o) = (uint32_t)h0 | ((uint32_t)h1 << 16);
    *(uint32_t*)(outl + o) = (uint32_t)lo0 | ((uint32_t)lo1 << 16);
  }
}

// ---------------- segmented split-bf16 GEMM --------------------------------
// A planes [Nrows][lda], B planes [Co][ldb]. 128x128 tile, BK=32, 4 waves.
// Output cols partitioned in 512-wide segments, each with its own epilogue.
// flags: 1=ACC(in-place ok) 2=sigmoid 4=HR(out=AUX*sigmoid) 8=relu
struct Seg4 {
  const uint16_t* ACh[4]; const uint16_t* ACl[4];
  const uint16_t* AXh[4]; const uint16_t* AXl[4];
  uint16_t* Ch[4]; uint16_t* Cl[4];
  float* Cf[4];
  const float* bias[4];
  int flags[4];
  int ldc[4];
};
struct SegOne {
  const uint16_t *ACh, *ACl, *AXh, *AXl;
  uint16_t *Ch, *Cl;
  float* Cf;
  const float* bias;
  int flags, ldc;
};
__device__ __forceinline__ SegOne pickseg(const Seg4& s, int i) {
  SegOne o;
  switch (i) {  // constant indices only (avoid scratch)
    case 0: o = {s.ACh[0], s.ACl[0], s.AXh[0], s.AXl[0], s.Ch[0], s.Cl[0], s.Cf[0], s.bias[0], s.flags[0], s.ldc[0]}; break;
    case 1: o = {s.ACh[1], s.ACl[1], s.AXh[1], s.AXl[1], s.Ch[1], s.Cl[1], s.Cf[1], s.bias[1], s.flags[1], s.ldc[1]}; break;
    case 2: o = {s.ACh[2], s.ACl[2], s.AXh[2], s.AXl[2], s.Ch[2], s.Cl[2], s.Cf[2], s.bias[2], s.flags[2], s.ldc[2]}; break;
    default: o = {s.ACh[3], s.ACl[3], s.AXh[3], s.AXl[3], s.Ch[3], s.Cl[3], s.Cf[3], s.bias[3], s.flags[3], s.ldc[3]}; break;
  }
  return o;
}
__global__ __launch_bounds__(256) void gemm_sp_k(
    const uint16_t* __restrict__ Ah, const uint16_t* __restrict__ Al, int lda,
    const uint16_t* __restrict__ Bh, const uint16_t* __restrict__ Bl, int ldb,
    Seg4 sg, int Nrows, int K, int Co) {
  __shared__ char lds[32768];
  const int tid = threadIdx.x;
  const int bm = blockIdx.x * 128, bn = blockIdx.y * 128;
  const int l = tid & 63, w = tid >> 6, wr = w >> 1, wc = w & 1;

  f32x4 acc[4][4];
#pragma unroll
  for (int i = 0; i < 4; ++i)
#pragma unroll
    for (int j = 0; j < 4; ++j) acc[i][j] = (f32x4){0.f, 0.f, 0.f, 0.f};

  const int r127 = tid & 127, ch = tid >> 7;
  const uint16_t* Ahp = Ah + (size_t)(bm + r127) * lda + ch * 8;
  const uint16_t* Alp = Al + (size_t)(bm + r127) * lda + ch * 8;
  const uint16_t* Bhp = Bh + (size_t)(bn + r127) * ldb + ch * 8;
  const uint16_t* Blp = Bl + (size_t)(bn + r127) * ldb + ch * 8;
  char* l0 = lds + (uint32_t)(tid & 192) * 16;

  for (int k0 = 0; k0 < K; k0 += 32) {
    __syncthreads();
    gl16(Ahp + k0, l0 + 0);
    gl16(Ahp + k0 + 16, l0 + 4096);
    gl16(Alp + k0, l0 + 8192);
    gl16(Alp + k0 + 16, l0 + 12288);
    gl16(Bhp + k0, l0 + 16384);
    gl16(Bhp + k0 + 16, l0 + 20480);
    gl16(Blp + k0, l0 + 24576);
    gl16(Blp + k0 + 16, l0 + 28672);
    __syncthreads();
    const uint32_t kc = (uint32_t)(l >> 4) * 2048;
    const uint32_t ar = kc + (uint32_t)(wr * 64 + (l & 15)) * 16;
    const uint32_t br = kc + (uint32_t)(wc * 64 + (l & 15)) * 16;
    bf16x8 ah[4], al[4], bh[4], bl[4];
#pragma unroll
    for (int i = 0; i < 4; ++i) {
      ah[i] = *(const bf16x8*)(lds + ar + i * 256);
      al[i] = *(const bf16x8*)(lds + 8192 + ar + i * 256);
      bh[i] = *(const bf16x8*)(lds + 16384 + br + i * 256);
      bl[i] = *(const bf16x8*)(lds + 24576 + br + i * 256);
    }
#pragma unroll
    for (int mi = 0; mi < 4; ++mi)
#pragma unroll
      for (int ni = 0; ni < 4; ++ni) {
        acc[mi][ni] = __builtin_amdgcn_mfma_f32_16x16x32_bf16(ah[mi], bh[ni], acc[mi][ni], 0, 0, 0);
        acc[mi][ni] = __builtin_amdgcn_mfma_f32_16x16x32_bf16(ah[mi], bl[ni], acc[mi][ni], 0, 0, 0);
        acc[mi][ni] = __builtin_amdgcn_mfma_f32_16x16x32_bf16(al[mi], bh[ni], acc[mi][ni], 0, 0, 0);
      }
  }

  const SegOne sgo = pickseg(sg, bn >> 9);
  const bool facc = sgo.flags & 1, fsig = sgo.flags & 2, fhr = sgo.flags & 4, frelu = sgo.flags & 8;
#pragma unroll
  for (int mi = 0; mi < 4; ++mi) {
#pragma unroll
    for (int q = 0; q < 4; ++q) {
      int row = bm + wr * 64 + mi * 16 + (l >> 4) * 4 + q;
      if (row >= Nrows) continue;
#pragma unroll
      for (int ni = 0; ni < 4; ++ni) {
        int col = bn + wc * 64 + ni * 16 + (l & 15);
        float v = acc[mi][ni][q];
        size_t off = (size_t)row * sgo.ldc + (col & 511);
        if (facc) v += bf2f(sgo.ACh[off]) + bf2f(sgo.ACl[off]);
        else if (sgo.bias) v += sgo.bias[col & 511];
        if (fsig) v = 1.0f / (1.0f + expf(-v));
        if (fhr) {
          float rr = 1.0f / (1.0f + expf(-v));
          v = (bf2f(sgo.AXh[off]) + bf2f(sgo.AXl[off])) * rr;
        }
        if (frelu) v = fmaxf(v, 0.f);
        if (sgo.Ch) {
          uint16_t h = f2bf(v);
          sgo.Ch[off] = h;
          sgo.Cl[off] = f2bf(v - bf2f(h));
        }
        if (sgo.Cf) sgo.Cf[off] = v;
      }
    }
  }
}

// ---------------- GRU combine (PB=4): Hacc = sum_p probs*(...) + relu planes
__global__ __launch_bounds__(256) void accum_fused_k(
    const uint16_t* __restrict__ Zh, const uint16_t* __restrict__ Zl,
    const uint16_t* __restrict__ Hh, const uint16_t* __restrict__ Hl,
    const uint16_t* __restrict__ Th, const uint16_t* __restrict__ Tl,
    const float* __restrict__ probs, float* __restrict__ hacc,
    uint16_t* __restrict__ Rh, uint16_t* __restrict__ Rl, int N) {
  int node = (blockIdx.x * 256 + threadIdx.x) >> 6;
  int l = threadIdx.x & 63;
  if (node >= N) return;
  float sum[8] = {};
#pragma unroll
  for (int pr = 0; pr < 4; ++pr) {
    float pw = probs[pr];
    size_t ro = ((size_t)node * 4 + pr) * 512 + l * 8;
    bf16x8 zh = *(const bf16x8*)(Zh + ro), zl = *(const bf16x8*)(Zl + ro);
    bf16x8 hh = *(const bf16x8*)(Hh + ro), hl = *(const bf16x8*)(Hl + ro);
    bf16x8 th = *(const bf16x8*)(Th + ro), tl = *(const bf16x8*)(Tl + ro);
#pragma unroll
    for (int j = 0; j < 8; ++j) {
      float z = bf2f((uint16_t)zh[j]) + bf2f((uint16_t)zl[j]);
      float h = bf2f((uint16_t)hh[j]) + bf2f((uint16_t)hl[j]);
      float t = tanhf(bf2f((uint16_t)th[j]) + bf2f((uint16_t)tl[j]));
      sum[j] += pw * (z * h + (1.0f - z) * t);
    }
  }
  float* o = hacc + (size_t)node * 512 + l * 8;
  uint16_t h8[8], l8[8];
#pragma unroll
  for (int j = 0; j < 8; ++j) {
    o[j] = sum[j];
    float rv = fmaxf(sum[j], 0.f);
    uint16_t h = f2bf(rv);
    h8[j] = h;
    l8[j] = f2bf(rv - bf2f(h));
  }
  size_t po = (size_t)node * 512 + l * 8;
  *(bf16x8*)(Rh + po) = *(bf16x8*)h8;
  *(bf16x8*)(Rl + po) = *(bf16x8*)l8;
}

// fallback (PB<4): Hacc += sum
template <int PB>
__global__ __launch_bounds__(256) void accum_k(
    const uint16_t* __restrict__ Zh, const uint16_t* __restrict__ Zl,
    const uint16_t* __restrict__ Hh, const uint16_t* __restrict__ Hl,
    const uint16_t* __restrict__ Th, const uint16_t* __restrict__ Tl,
    const float* __restrict__ probs, float* __restrict__ hacc, int N, int p0) {
  int node = (blockIdx.x * 256 + threadIdx.x) >> 6;
  int l = threadIdx.x & 63;
  if (node >= N) return;
  float sum[8] = {};
#pragma unroll
  for (int pr = 0; pr < PB; ++pr) {
    float pw = probs[p0 + pr];
    size_t ro = ((size_t)node * PB + pr) * 512 + l * 8;
    bf16x8 zh = *(const bf16x8*)(Zh + ro), zl = *(const bf16x8*)(Zl + ro);
    bf16x8 hh = *(const bf16x8*)(Hh + ro), hl = *(const bf16x8*)(Hl + ro);
    bf16x8 th = *(const bf16x8*)(Th + ro), tl = *(const bf16x8*)(Tl + ro);
#pragma unroll
    for (int j = 0; j < 8; ++j) {
      float z = bf2f((uint16_t)zh[j]) + bf2f((uint16_t)zl[j]);
      float h = bf2f((uint16_t)hh[j]) + bf2f((uint16_t)hl[j]);
      float t = tanhf(bf2f((uint16_t)th[j]) + bf2f((uint16_t)tl[j]));
      sum[j] += pw * (z * h + (1.0f - z) * t);
    }
  }
  float* o = hacc + (size_t)node * 512 + l * 8;
#pragma unroll
  for (int j = 0; j < 8; ++j) o[j] += sum[j];
}

__global__ void reluconv_k(const float* __restrict__ in, uint16_t* __restrict__ oh,
                           uint16_t* __restrict__ ol, int n4) {
  int i = blockIdx.x * blockDim.x + threadIdx.x;
  if (i >= n4) return;
  float4 v = ((const float4*)in)[i];
  float a[4] = {fmaxf(v.x, 0.f), fmaxf(v.y, 0.f), fmaxf(v.z, 0.f), fmaxf(v.w, 0.f)};
  uint16_t h4[4], l4[4];
#pragma unroll
  for (int j = 0; j < 4; ++j) {
    h4[j] = f2bf(a[j]);
    l4[j] = f2bf(a[j] - bf2f(h4[j]));
  }
  ((uint2*)oh)[i] = *(uint2*)h4;
  ((uint2*)ol)[i] = *(uint2*)l4;
}

__global__ __launch_bounds__(256) void matvec_k(const float* __restrict__ A,
                                                const float* __restrict__ w,
                                                const float* __restrict__ b,
                                                float* __restrict__ out, int N, int K) {
  int gw = (blockIdx.x * 256 + threadIdx.x) >> 6;
  int lane = threadIdx.x & 63;
  if (gw >= N) return;
  float s = 0.0f;
  for (int k = lane; k < K; k += 64) s += A[(size_t)gw * K + k] * w[k];
#pragma unroll
  for (int off = 32; off > 0; off >>= 1) s += __shfl_down(s, off);
  if (lane == 0) out[gw] = s + b[0];
}

extern "C" void kernel_launch(void* const* d_in, const int* in_sizes, int n_in,
                              void* d_out, int out_size, void* d_ws, size_t ws_size,
                              hipStream_t stream) {
  const int N = 10000, F = 128, P = 4, E = 160000;
  const int C = 512, HID = 256;
  const int NC = N * C;
  (void)F; (void)in_sizes; (void)n_in;

  const float* x     = (const float*)d_in[0];
  const int*   ei    = (const int*)d_in[1];
  const float* ea    = (const float*)d_in[2];
  const float* W1    = (const float*)d_in[3];
  const float* b1    = (const float*)d_in[4];
  const float* W2    = (const float*)d_in[5];
  const float* b2    = (const float*)d_in[6];
  const float* W3    = (const float*)d_in[7];
  const float* b3    = (const float*)d_in[8];
  const float* W4    = (const float*)d_in[9];
  const float* b4    = (const float*)d_in[10];
  const float* W5    = (const float*)d_in[11];
  const float* b5    = (const float*)d_in[12];
  const float* Wz    = (const float*)d_in[13];
  const float* bz    = (const float*)d_in[14];
  const float* Lz_w  = (const float*)d_in[15];
  const float* Lz_b  = (const float*)d_in[16];
  const float* Wr    = (const float*)d_in[17];
  const float* br    = (const float*)d_in[18];
  const float* Lr_w  = (const float*)d_in[19];
  const float* Lr_b  = (const float*)d_in[20];
  const float* Wh    = (const float*)d_in[21];
  const float* bh    = (const float*)d_in[22];
  const float* Lh_w  = (const float*)d_in[23];
  const float* Lh_b  = (const float*)d_in[24];
  const float* attn  = (const float*)d_in[25];
  const float* lin1w = (const float*)d_in[26];
  const float* lin1b = (const float*)d_in[27];
  const float* lin2w = (const float*)d_in[28];
  const float* lin2b = (const float*)d_in[29];

  // ---- pick PB from ws_size (same bound as before -> stable choice) ----
  auto need = [&](int PBv) -> size_t {
    size_t NBpv = ((size_t)PBv * N + 127) / 128 * 128;
    return ((size_t)16 << 20) + NBpv * 128 * 4 + NBpv * 512 * 4 * 5;
  };
  int PB = 1;
  if (ws_size >= need(4)) PB = 4;
  else if (ws_size >= need(2)) PB = 2;
  const int NB = PB * N;
  const size_t NBp = ((size_t)NB + 127) / 128 * 128;

  // ---- workspace carve-out ----
  char* wsp = (char*)d_ws;
  auto alloc = [&](size_t bytes) -> char* {
    char* ret = wsp;
    wsp += (bytes + 255) & ~(size_t)255;
    return ret;
  };
  float* deg    = (float*)alloc((size_t)N * 4);
  float* dinv   = (float*)alloc((size_t)N * 4);
  float* dinv2  = (float*)alloc((size_t)N * 4);
  int*   counts = (int*)alloc((size_t)N * 4);
  int*   rowp   = (int*)alloc((size_t)(N + 1) * 4);
  int2*  csrE   = (int2*)alloc((size_t)E * 8);
  float* probs  = (float*)alloc(256);

  auto wplanes = [&](size_t n, uint16_t** h, uint16_t** lo) {
    *h = (uint16_t*)alloc(n * 2);
    *lo = (uint16_t*)alloc(n * 2);
  };
  uint16_t *W1h, *W1l, *W2h, *W2l, *W3h, *W3l, *W4h, *W4l, *W5h, *W5l;
  uint16_t *LZRh, *LZRl, *LhBh, *LhBl, *l1h, *l1l, *G3H, *G3L;
  wplanes((size_t)128 * 512, &W1h, &W1l);
  wplanes((size_t)512 * 512, &W2h, &W2l);
  wplanes((size_t)512 * 512, &W3h, &W3l);
  wplanes((size_t)512 * 512, &W4h, &W4l);
  wplanes((size_t)512 * 512, &W5h, &W5l);
  wplanes((size_t)1024 * 512, &LZRh, &LZRl);  // [LzB | LrB] as [1024][512]
  wplanes((size_t)512 * 512, &LhBh, &LhBl);
  wplanes((size_t)512 * 256, &l1h, &l1l);
  wplanes((size_t)1536 * 128, &G3H, &G3L);    // folded tops [1536][128]
  float* gbias = (float*)alloc(1536 * 4);

  uint16_t* AXh = (uint16_t*)alloc(NBp * 128 * 2);
  uint16_t* AXl = (uint16_t*)alloc(NBp * 128 * 2);
  uint16_t* T1h = (uint16_t*)alloc(NBp * 512 * 2);
  uint16_t* T1l = (uint16_t*)alloc(NBp * 512 * 2);
  uint16_t* Uh  = (uint16_t*)alloc(NBp * 512 * 2);
  uint16_t* Ul  = (uint16_t*)alloc(NBp * 512 * 2);
  float*    Uf  = (float*)Uh;  // fp32 view spanning Uh+Ul (contiguous)
  uint16_t* Hh  = (uint16_t*)alloc(NBp * 512 * 2);
  uint16_t* Hl  = (uint16_t*)alloc(NBp * 512 * 2);
  uint16_t* Zh  = (uint16_t*)alloc(NBp * 512 * 2);
  uint16_t* Zl  = (uint16_t*)alloc(NBp * 512 * 2);
  uint16_t* Th  = (uint16_t*)alloc(NBp * 512 * 2);
  uint16_t* Tl  = (uint16_t*)alloc(NBp * 512 * 2);

  float* Hacc = (float*)d_out + 10000;

  // ---- preprocessing (fused) ----
  if (PB != 4) hipMemsetAsync(d_out, 0, (size_t)out_size * sizeof(float), stream);
  init_k<<<(N + 255) / 256, 256, 0, stream>>>(deg, counts, N);
  edge_k<<<(E + 255) / 256, 256, 0, stream>>>(ei, ea, deg, counts, E);
  dinv_k<<<(N + 255) / 256, 256, 0, stream>>>(deg, dinv, dinv2, N);
  scan_sm_k<<<1, 1024, 0, stream>>>(counts, rowp, N, attn, probs);
  fill_k<<<(E + 255) / 256, 256, 0, stream>>>(ei, ea, dinv, rowp, counts, csrE, E);

  {
    WCdesc d;
    const float* srcs[9] = {W1, W2, W3, W4, W5,
                            Lz_w + (size_t)512 * 512, Lr_w + (size_t)512 * 512,
                            Lh_w + (size_t)512 * 512, lin1w};
    uint16_t* dhs[9] = {W1h, W2h, W3h, W4h, W5h, LZRh, LZRh + (size_t)512 * 512, LhBh, l1h};
    uint16_t* dls[9] = {W1l, W2l, W3l, W4l, W5l, LZRl, LZRl + (size_t)512 * 512, LhBl, l1l};
    int Ks[9] = {128, 512, 512, 512, 512, 512, 512, 512, 512};
    int Cos[9] = {512, 512, 512, 512, 512, 512, 512, 512, 256};
    for (int i = 0; i < 9; ++i) {
      d.src[i] = srcs[i]; d.dh[i] = dhs[i]; d.dl[i] = dls[i];
      d.K[i] = Ks[i]; d.Co[i] = Cos[i];
    }
    wconv_all_k<<<dim3(16, 16, 9), 256, 0, stream>>>(d);
  }
  {
    WFdesc d;
    d.Wg[0] = Wz; d.Wg[1] = Wr; d.Wg[2] = Wh;
    d.Lt[0] = Lz_w; d.Lt[1] = Lr_w; d.Lt[2] = Lh_w;
    wfold3_k<<<dim3(16, 4, 3), 256, 0, stream>>>(d, G3H, G3L);
  }
  gbias_k<<<6, 256, 0, stream>>>(bz, Lz_w, Lz_b, br, Lr_w, Lr_b, bh, Lh_w, Lh_b, gbias);

  auto setseg = [](Seg4& s, int i, const uint16_t* ach, const uint16_t* acl,
                   const uint16_t* axh, const uint16_t* axl,
                   uint16_t* chp, uint16_t* clp, float* cf,
                   const float* bias, int flags, int ldc) {
    s.ACh[i] = ach; s.ACl[i] = acl; s.AXh[i] = axh; s.AXl[i] = axl;
    s.Ch[i] = chp; s.Cl[i] = clp; s.Cf[i] = cf; s.bias[i] = bias;
    s.flags[i] = flags; s.ldc[i] = ldc;
  };
  auto gemm = [&](const uint16_t* Ah, const uint16_t* Al, int lda,
                  const uint16_t* Bh, const uint16_t* Bl, int ldb,
                  const Seg4& sg, int Nrows, int K, int Co) {
    dim3 g((Nrows + 127) / 128, Co / 128);
    gemm_sp_k<<<g, 256, 0, stream>>>(Ah, Al, lda, Bh, Bl, ldb, sg, Nrows, K, Co);
  };

  const int aggBlocks = (N * 64 + 255) / 256;
  auto agg5 = [&]() {
    if (PB == 4)
      agg512_k<4, 2><<<(N * 2 * 64 + 255) / 256, 256, 0, stream>>>(Uf, T1h, T1l, rowp, csrE, dinv2, N);
    else if (PB == 2)
      agg512_k<2, 2><<<(N * 2 * 64 + 255) / 256, 256, 0, stream>>>(Uf, T1h, T1l, rowp, csrE, dinv2, N);
    else
      agg512_k<1, 1><<<aggBlocks, 256, 0, stream>>>(Uf, T1h, T1l, rowp, csrE, dinv2, N);
  };

  for (int p0 = 0; p0 < P; p0 += PB) {
    if (PB == 4)      agg128_k<4><<<aggBlocks, 256, 0, stream>>>(x, AXh, AXl, rowp, csrE, dinv2, N, p0);
    else if (PB == 2) agg128_k<2><<<aggBlocks, 256, 0, stream>>>(x, AXh, AXl, rowp, csrE, dinv2, N, p0);
    else              agg128_k<1><<<aggBlocks, 256, 0, stream>>>(x, AXh, AXl, rowp, csrE, dinv2, N, p0);

    // conv stack: h_{i+1} = (A h_i) W + b
    { Seg4 s{}; setseg(s, 0, nullptr, nullptr, nullptr, nullptr, nullptr, nullptr, Uf, b1, 0, 512);
      gemm(AXh, AXl, 128, W1h, W1l, 128, s, NB, 128, 512); }
    agg5();
    { Seg4 s{}; setseg(s, 0, nullptr, nullptr, nullptr, nullptr, nullptr, nullptr, Uf, b2, 0, 512);
      gemm(T1h, T1l, 512, W2h, W2l, 512, s, NB, 512, 512); }
    agg5();
    { Seg4 s{}; setseg(s, 0, nullptr, nullptr, nullptr, nullptr, nullptr, nullptr, Uf, b3, 0, 512);
      gemm(T1h, T1l, 512, W3h, W3l, 512, s, NB, 512, 512); }
    agg5();
    { Seg4 s{}; setseg(s, 0, nullptr, nullptr, nullptr, nullptr, nullptr, nullptr, Uf, b4, 0, 512);
      gemm(T1h, T1l, 512, W4h, W4l, 512, s, NB, 512, 512); }
    agg5();
    { Seg4 s{}; setseg(s, 0, nullptr, nullptr, nullptr, nullptr, Hh, Hl, nullptr, b5, 0, 512);
      gemm(T1h, T1l, 512, W5h, W5l, 512, s, NB, 512, 512); }  // H planes

    // batched gate tops: Co=1536, segs -> Z|U|T plane buffers
    { Seg4 s{};
      setseg(s, 0, nullptr, nullptr, nullptr, nullptr, Zh, Zl, nullptr, gbias, 0, 512);
      setseg(s, 1, nullptr, nullptr, nullptr, nullptr, Uh, Ul, nullptr, gbias + 512, 0, 512);
      setseg(s, 2, nullptr, nullptr, nullptr, nullptr, Th, Tl, nullptr, gbias + 1024, 0, 512);
      gemm(AXh, AXl, 128, G3H, G3L, 128, s, NB, 128, 1536); }

    // batched Z/R bottoms: Co=1024; seg0 Z=sig(top+H@LzB), seg1 HR=H*sig(...)
    { Seg4 s{};
      setseg(s, 0, Zh, Zl, nullptr, nullptr, Zh, Zl, nullptr, nullptr, 1 | 2, 512);
      setseg(s, 1, Uh, Ul, Hh, Hl, Uh, Ul, nullptr, nullptr, 1 | 4, 512);
      gemm(Hh, Hl, 512, LZRh, LZRl, 512, s, NB, 512, 1024); }

    // candidate bottom: Ht_pre = top + HR@LhB
    { Seg4 s{}; setseg(s, 0, Th, Tl, nullptr, nullptr, Th, Tl, nullptr, nullptr, 1, 512);
      gemm(Uh, Ul, 512, LhBh, LhBl, 512, s, NB, 512, 512); }

    if (PB == 4)
      accum_fused_k<<<aggBlocks, 256, 0, stream>>>(Zh, Zl, Hh, Hl, Th, Tl, probs, Hacc, T1h, T1l, N);
    else if (PB == 2)
      accum_k<2><<<aggBlocks, 256, 0, stream>>>(Zh, Zl, Hh, Hl, Th, Tl, probs, Hacc, N, p0);
    else
      accum_k<1><<<aggBlocks, 256, 0, stream>>>(Zh, Zl, Hh, Hl, Th, Tl, probs, Hacc, N, p0);
  }

  if (PB != 4)
    reluconv_k<<<(NC / 4 + 255) / 256, 256, 0, stream>>>(Hacc, T1h, T1l, NC / 4);

  // final MLP: relu(Hacc) -> lin1(+relu) -> lin2 matvec
  { Seg4 s{}; setseg(s, 0, nullptr, nullptr, nullptr, nullptr, nullptr, nullptr, Uf, lin1b, 8, 256);
    gemm(T1h, T1l, 512, l1h, l1l, 512, s, N, 512, HID); }
  matvec_k<<<(N * 64 + 255) / 256, 256, 0, stream>>>(Uf, lin2w, lin2b, (float*)d_out, N, HID);
}

// Round 7
// 2243.484 us; speedup vs baseline: 1.8926x; 1.1698x over previous
//
#include <hip/hip_runtime.h>
#include <hip/hip_fp16.h>
#include <cstdint>
#include <cstddef>

// ---------------------------------------------------------------------------
// ConvStackedTemporalGCN — split-bf16 MFMA GEMM, gate folding, fp16 streams
// N=10000, F=128, P=4, E=160000, C=512, HID=256
//  * gcn(h,W,b) = (A h) W + b ; A.Xp shared across W1/gates.
//  * Gate fold: top = (AX)@(Wg@L_top) + folded bias ; bot = H@L_bot.
//  * Segmented GEMM: one dispatch = several 512-col segments w/ own epilogue.
//  * Conv-chain U and gate scalars in fp16 (halves agg/epilogue traffic);
//    GEMM A/B operands stay split hi+lo bf16 (3-product, ~1e-5 rel).
//  * agg512: one wave per (node,p) row, fp16 in, bf16-plane out.
//  R7 fix: W5 SegOne brace-init was field-shifted after ACq was added
//          (Cl=nullptr -> null deref crash). Corrected; no other changes.
// ---------------------------------------------------------------------------

typedef short bf16x8 __attribute__((ext_vector_type(8)));
typedef float f32x4 __attribute__((ext_vector_type(4)));

__device__ __forceinline__ uint16_t f2bf(float f) {
  uint32_t u = __float_as_uint(f);
  u += 0x7FFFu + ((u >> 16) & 1u);
  return (uint16_t)(u >> 16);
}
__device__ __forceinline__ float bf2f(uint16_t h) {
  return __uint_as_float((uint32_t)h << 16);
}
__device__ __forceinline__ void gl16(const void* g, void* l) {
  __builtin_amdgcn_global_load_lds((const __attribute__((address_space(1))) uint32_t*)g,
                                   (__attribute__((address_space(3))) uint32_t*)l, 16, 0, 0);
}

// ---------------- graph preprocessing ----------------
__global__ void init_k(float* deg, int* counts, int N) {
  int i = blockIdx.x * blockDim.x + threadIdx.x;
  if (i < N) { deg[i] = 1.0f; counts[i] = 0; }
}
__global__ void edge_k(const int* __restrict__ ei, const float* __restrict__ ea,
                       float* deg, int* counts, int E) {
  int e = blockIdx.x * blockDim.x + threadIdx.x;
  if (e < E) {
    int d = ei[E + e];
    atomicAdd(&deg[d], ea[e]);
    atomicAdd(&counts[d], 1);
  }
}
__global__ void dinv_k(const float* __restrict__ deg, float* dinv, float* dinv2, int N) {
  int i = blockIdx.x * blockDim.x + threadIdx.x;
  if (i < N) {
    float d = deg[i];
    float r = d > 0.0f ? rsqrtf(d) : 0.0f;
    dinv[i] = r;
    dinv2[i] = r * r;
  }
}
__global__ void scan_sm_k(int* __restrict__ counts, int* row_ptr, int n,
                          const float* __restrict__ attn, float* probs) {
  __shared__ int wtot[16];
  __shared__ int carry_s;
  int tid = threadIdx.x, lane = tid & 63, w = tid >> 6;
  if (tid == 0) carry_s = 0;
  __syncthreads();
  for (int base = 0; base < n; base += 1024) {
    int i = base + tid;
    int v = 0;
    if (i < n) { v = counts[i]; counts[i] = 0; }
    int s = v;
#pragma unroll
    for (int off = 1; off < 64; off <<= 1) {
      int t = __shfl_up(s, off);
      if (lane >= off) s += t;
    }
    if (lane == 63) wtot[w] = s;
    __syncthreads();
    if (w == 0) {
      int t16 = (lane < 16) ? wtot[lane] : 0;
#pragma unroll
      for (int off = 1; off < 16; off <<= 1) {
        int t = __shfl_up(t16, off);
        if (lane >= off) t16 += t;
      }
      if (lane < 16) wtot[lane] = t16;
    }
    __syncthreads();
    int carry = carry_s;
    int woff = (w > 0) ? wtot[w - 1] : 0;
    int incl = carry + woff + s;
    if (i < n) row_ptr[i] = incl - v;
    __syncthreads();
    if (tid == 1023) carry_s = incl;
    __syncthreads();
  }
  if (tid == 0) {
    row_ptr[n] = carry_s;
    float a0 = attn[0], a1 = attn[1], a2 = attn[2], a3 = attn[3];
    float m = fmaxf(fmaxf(a0, a1), fmaxf(a2, a3));
    float e0 = expf(a0 - m), e1 = expf(a1 - m), e2 = expf(a2 - m), e3 = expf(a3 - m);
    float s4 = e0 + e1 + e2 + e3;
    probs[0] = e0 / s4; probs[1] = e1 / s4; probs[2] = e2 / s4; probs[3] = e3 / s4;
  }
}
__global__ void fill_k(const int* __restrict__ ei, const float* __restrict__ ea,
                       const float* __restrict__ dinv, const int* __restrict__ row_ptr,
                       int* cursor, int2* __restrict__ csrE, int E) {
  int e = blockIdx.x * blockDim.x + threadIdx.x;
  if (e < E) {
    int s = ei[e], d = ei[E + e];
    float w = dinv[s] * ea[e] * dinv[d];
    int pos = atomicAdd(&cursor[d], 1);
    csrE[row_ptr[d] + pos] = make_int2(s, __float_as_int(w));
  }
}

// ---------------- all weight transposes+splits in one launch ---------------
struct WCdesc {
  const float* src[9];
  uint16_t* dh[9];
  uint16_t* dl[9];
  int K[9];
  int Co[9];
};
__global__ void wconv_all_k(WCdesc d) {
  int z = blockIdx.z;
  int K, Co;
  const float* W;
  uint16_t *Th, *Tl;
  switch (z) {
    case 0: W = d.src[0]; Th = d.dh[0]; Tl = d.dl[0]; K = d.K[0]; Co = d.Co[0]; break;
    case 1: W = d.src[1]; Th = d.dh[1]; Tl = d.dl[1]; K = d.K[1]; Co = d.Co[1]; break;
    case 2: W = d.src[2]; Th = d.dh[2]; Tl = d.dl[2]; K = d.K[2]; Co = d.Co[2]; break;
    case 3: W = d.src[3]; Th = d.dh[3]; Tl = d.dl[3]; K = d.K[3]; Co = d.Co[3]; break;
    case 4: W = d.src[4]; Th = d.dh[4]; Tl = d.dl[4]; K = d.K[4]; Co = d.Co[4]; break;
    case 5: W = d.src[5]; Th = d.dh[5]; Tl = d.dl[5]; K = d.K[5]; Co = d.Co[5]; break;
    case 6: W = d.src[6]; Th = d.dh[6]; Tl = d.dl[6]; K = d.K[6]; Co = d.Co[6]; break;
    case 7: W = d.src[7]; Th = d.dh[7]; Tl = d.dl[7]; K = d.K[7]; Co = d.Co[7]; break;
    default: W = d.src[8]; Th = d.dh[8]; Tl = d.dl[8]; K = d.K[8]; Co = d.Co[8]; break;
  }
  int bco = blockIdx.x * 32, bk = blockIdx.y * 32;
  if (bco >= Co || bk >= K) return;
  __shared__ float t[32][33];
  int tx = threadIdx.x & 31, ty = threadIdx.x >> 5;
  for (int r = ty; r < 32; r += 8) t[r][tx] = W[(size_t)(bk + r) * Co + bco + tx];
  __syncthreads();
  for (int r = ty; r < 32; r += 8) {
    float v = t[tx][r];
    uint16_t h = f2bf(v);
    size_t o = (size_t)(bco + r) * K + bk + tx;
    Th[o] = h;
    Tl[o] = f2bf(v - bf2f(h));
  }
}

// ---------------- 3 gate-weight folds in one launch ------------------------
struct WFdesc { const float* Wg[3]; const float* Lt[3]; };
__global__ void wfold3_k(WFdesc d, uint16_t* __restrict__ Oh, uint16_t* __restrict__ Ol) {
  int z = blockIdx.z;
  const float *Wg, *Lt;
  switch (z) {
    case 0: Wg = d.Wg[0]; Lt = d.Lt[0]; break;
    case 1: Wg = d.Wg[1]; Lt = d.Lt[1]; break;
    default: Wg = d.Wg[2]; Lt = d.Lt[2]; break;
  }
  __shared__ float a[32][33], b[32][33];
  int c0 = blockIdx.x * 32, f0 = blockIdx.y * 32;
  int tx = threadIdx.x & 31, ty = threadIdx.x >> 5;
  float acc[4] = {0.f, 0.f, 0.f, 0.f};
  for (int k0 = 0; k0 < 512; k0 += 32) {
    for (int r = ty; r < 32; r += 8) a[r][tx] = Wg[(size_t)(f0 + r) * 512 + k0 + tx];
    for (int r = ty; r < 32; r += 8) b[r][tx] = Lt[(size_t)(k0 + r) * 512 + c0 + tx];
    __syncthreads();
    for (int kk = 0; kk < 32; ++kk) {
      float bv = b[kk][tx];
#pragma unroll
      for (int q = 0; q < 4; ++q) acc[q] += a[ty * 4 + q][kk] * bv;
    }
    __syncthreads();
  }
  size_t base = (size_t)z * 512 * 128;
#pragma unroll
  for (int q = 0; q < 4; ++q) {
    int f = f0 + ty * 4 + q, c = c0 + tx;
    float v = acc[q];
    uint16_t h = f2bf(v);
    Oh[base + (size_t)c * 128 + f] = h;
    Ol[base + (size_t)c * 128 + f] = f2bf(v - bf2f(h));
  }
}
__global__ void gbias_k(const float* bz, const float* Lz, const float* Lzb,
                        const float* br, const float* Lr, const float* Lrb,
                        const float* bh, const float* Lh, const float* Lhb,
                        float* __restrict__ out) {
  int c = blockIdx.x * 256 + threadIdx.x;
  if (c >= 1536) return;
  int g = c >> 9, cc = c & 511;
  const float* bsrc = g == 0 ? bz : (g == 1 ? br : bh);
  const float* L    = g == 0 ? Lz : (g == 1 ? Lr : Lh);
  const float* lb   = g == 0 ? Lzb : (g == 1 ? Lrb : Lhb);
  float s = lb[cc];
  for (int k = 0; k < 512; ++k) s += bsrc[k] * L[(size_t)k * 512 + cc];
  out[c] = s;
}

// ---------------- aggregation, C=512, fp16 in: wave per (node,p) row -------
template <int PB, int SP>
__global__ __launch_bounds__(256) void agg512q_k(
    const __half* __restrict__ in, uint16_t* __restrict__ outh, uint16_t* __restrict__ outl,
    const int* __restrict__ rowp, const int2* __restrict__ csrE,
    const float* __restrict__ dinv2, int N) {
  const int RP = PB / SP;
  int gw = (blockIdx.x * 256 + threadIdx.x) >> 6;
  int l = threadIdx.x & 63;
  if (gw >= N * SP) return;
  int node = gw / SP;
  int rb = (gw - node * SP) * RP;
  float acc[RP][8];
  float w0 = dinv2[node];
  union U16x8 { uint4 u; __half2 h[4]; };
  const __half* sp = in + ((size_t)node * PB + rb) * 512 + l * 8;
#pragma unroll
  for (int p = 0; p < RP; ++p) {
    U16x8 v;
    v.u = *(const uint4*)(sp + (size_t)p * 512);
#pragma unroll
    for (int j = 0; j < 4; ++j) {
      float2 f = __half22float2(v.h[j]);
      acc[p][j * 2] = w0 * f.x;
      acc[p][j * 2 + 1] = w0 * f.y;
    }
  }
  int s = rowp[node], e = rowp[node + 1];
#pragma unroll 4
  for (int idx = s; idx < e; ++idx) {
    int2 pk = csrE[idx];
    int src = pk.x;
    float w = __int_as_float(pk.y);
    const __half* rp = in + ((size_t)src * PB + rb) * 512 + l * 8;
#pragma unroll
    for (int p = 0; p < RP; ++p) {
      U16x8 v;
      v.u = *(const uint4*)(rp + (size_t)p * 512);
#pragma unroll
      for (int j = 0; j < 4; ++j) {
        float2 f = __half22float2(v.h[j]);
        acc[p][j * 2] += w * f.x;
        acc[p][j * 2 + 1] += w * f.y;
      }
    }
  }
#pragma unroll
  for (int p = 0; p < RP; ++p) {
    size_t ro = ((size_t)node * PB + rb + p) * 512 + l * 8;
    uint16_t h8[8], l8[8];
#pragma unroll
    for (int j = 0; j < 8; ++j) {
      uint16_t h = f2bf(acc[p][j]);
      h8[j] = h;
      l8[j] = f2bf(acc[p][j] - bf2f(h));
    }
    *(bf16x8*)(outh + ro) = *(bf16x8*)h8;
    *(bf16x8*)(outl + ro) = *(bf16x8*)l8;
  }
}

// ---------------- first-hop aggregation from x [N][F=128][P=4] -------------
template <int PB>
__global__ __launch_bounds__(256) void agg128_k(
    const float* __restrict__ x, uint16_t* __restrict__ outh, uint16_t* __restrict__ outl,
    const int* __restrict__ rowp, const int2* __restrict__ csrE,
    const float* __restrict__ dinv2, int N, int p0) {
  int node = (blockIdx.x * 256 + threadIdx.x) >> 6;
  int l = threadIdx.x & 63;
  if (node >= N) return;
  float acc[8];
  float w0 = dinv2[node];
  const float* sp = x + (size_t)node * 512 + l * 8;
  {
    float4 v0 = *(const float4*)sp;
    float4 v1 = *(const float4*)(sp + 4);
    acc[0] = w0 * v0.x; acc[1] = w0 * v0.y; acc[2] = w0 * v0.z; acc[3] = w0 * v0.w;
    acc[4] = w0 * v1.x; acc[5] = w0 * v1.y; acc[6] = w0 * v1.z; acc[7] = w0 * v1.w;
  }
  int s = rowp[node], e = rowp[node + 1];
#pragma unroll 2
  for (int idx = s; idx < e; ++idx) {
    int2 pk = csrE[idx];
    int src = pk.x;
    float w = __int_as_float(pk.y);
    const float* rp = x + (size_t)src * 512 + l * 8;
    float4 v0 = *(const float4*)rp;
    float4 v1 = *(const float4*)(rp + 4);
    acc[0] += w * v0.x; acc[1] += w * v0.y; acc[2] += w * v0.z; acc[3] += w * v0.w;
    acc[4] += w * v1.x; acc[5] += w * v1.y; acc[6] += w * v1.z; acc[7] += w * v1.w;
  }
  // slot j: f = l*2 + (j>>2) ; p = j&3
#pragma unroll
  for (int pr = 0; pr < PB; ++pr) {
    int pa = p0 + pr;
    float v0 = acc[pa], v1 = acc[4 + pa];
    uint16_t h0 = f2bf(v0), h1 = f2bf(v1);
    uint16_t lo0 = f2bf(v0 - bf2f(h0)), lo1 = f2bf(v1 - bf2f(h1));
    size_t o = ((size_t)node * PB + pr) * 128 + l * 2;
    *(uint32_t*)(outh + o) = (uint32_t)h0 | ((uint32_t)h1 << 16);
    *(uint32_t*)(outl + o) = (uint32_t)lo0 | ((uint32_t)lo1 << 16);
  }
}

// ---------------- segmented split-bf16 GEMM --------------------------------
// flags: 1=ACC planes, 2=sigmoid, 4=HR(out=AUX*sigmoid), 8=relu,
//        16=fp16 out (Cq), 32=ACC fp16 (ACq)
struct SegOne {
  const uint16_t *ACh, *ACl;
  const __half* ACq;
  const uint16_t *AXh, *AXl;
  uint16_t *Ch, *Cl;
  __half* Cq;
  const float* bias;
  int flags, ldc;
};
struct Seg4 {
  const uint16_t* ACh[4]; const uint16_t* ACl[4];
  const __half* ACq[4];
  const uint16_t* AXh[4]; const uint16_t* AXl[4];
  uint16_t* Ch[4]; uint16_t* Cl[4];
  __half* Cq[4];
  const float* bias[4];
  int flags[4];
  int ldc[4];
};
__device__ __forceinline__ SegOne pickseg(const Seg4& s, int i) {
  SegOne o;
  switch (i) {
    case 0: o = {s.ACh[0], s.ACl[0], s.ACq[0], s.AXh[0], s.AXl[0], s.Ch[0], s.Cl[0], s.Cq[0], s.bias[0], s.flags[0], s.ldc[0]}; break;
    case 1: o = {s.ACh[1], s.ACl[1], s.ACq[1], s.AXh[1], s.AXl[1], s.Ch[1], s.Cl[1], s.Cq[1], s.bias[1], s.flags[1], s.ldc[1]}; break;
    case 2: o = {s.ACh[2], s.ACl[2], s.ACq[2], s.AXh[2], s.AXl[2], s.Ch[2], s.Cl[2], s.Cq[2], s.bias[2], s.flags[2], s.ldc[2]}; break;
    default: o = {s.ACh[3], s.ACl[3], s.ACq[3], s.AXh[3], s.AXl[3], s.Ch[3], s.Cl[3], s.Cq[3], s.bias[3], s.flags[3], s.ldc[3]}; break;
  }
  return o;
}
__global__ __launch_bounds__(256) void gemm_sp_k(
    const uint16_t* __restrict__ Ah, const uint16_t* __restrict__ Al, int lda,
    const uint16_t* __restrict__ Bh, const uint16_t* __restrict__ Bl, int ldb,
    Seg4 sg, int Nrows, int K, int Co) {
  __shared__ char lds[32768];
  const int tid = threadIdx.x;
  const int bm = blockIdx.x * 128, bn = blockIdx.y * 128;
  const int l = tid & 63, w = tid >> 6, wr = w >> 1, wc = w & 1;

  f32x4 acc[4][4];
#pragma unroll
  for (int i = 0; i < 4; ++i)
#pragma unroll
    for (int j = 0; j < 4; ++j) acc[i][j] = (f32x4){0.f, 0.f, 0.f, 0.f};

  const int r127 = tid & 127, ch = tid >> 7;
  const uint16_t* Ahp = Ah + (size_t)(bm + r127) * lda + ch * 8;
  const uint16_t* Alp = Al + (size_t)(bm + r127) * lda + ch * 8;
  const uint16_t* Bhp = Bh + (size_t)(bn + r127) * ldb + ch * 8;
  const uint16_t* Blp = Bl + (size_t)(bn + r127) * ldb + ch * 8;
  char* l0 = lds + (uint32_t)(tid & 192) * 16;

  for (int k0 = 0; k0 < K; k0 += 32) {
    __syncthreads();
    gl16(Ahp + k0, l0 + 0);
    gl16(Ahp + k0 + 16, l0 + 4096);
    gl16(Alp + k0, l0 + 8192);
    gl16(Alp + k0 + 16, l0 + 12288);
    gl16(Bhp + k0, l0 + 16384);
    gl16(Bhp + k0 + 16, l0 + 20480);
    gl16(Blp + k0, l0 + 24576);
    gl16(Blp + k0 + 16, l0 + 28672);
    __syncthreads();
    const uint32_t kc = (uint32_t)(l >> 4) * 2048;
    const uint32_t ar = kc + (uint32_t)(wr * 64 + (l & 15)) * 16;
    const uint32_t br = kc + (uint32_t)(wc * 64 + (l & 15)) * 16;
    bf16x8 ah[4], al[4], bh[4], bl[4];
#pragma unroll
    for (int i = 0; i < 4; ++i) {
      ah[i] = *(const bf16x8*)(lds + ar + i * 256);
      al[i] = *(const bf16x8*)(lds + 8192 + ar + i * 256);
      bh[i] = *(const bf16x8*)(lds + 16384 + br + i * 256);
      bl[i] = *(const bf16x8*)(lds + 24576 + br + i * 256);
    }
#pragma unroll
    for (int mi = 0; mi < 4; ++mi)
#pragma unroll
      for (int ni = 0; ni < 4; ++ni) {
        acc[mi][ni] = __builtin_amdgcn_mfma_f32_16x16x32_bf16(ah[mi], bh[ni], acc[mi][ni], 0, 0, 0);
        acc[mi][ni] = __builtin_amdgcn_mfma_f32_16x16x32_bf16(ah[mi], bl[ni], acc[mi][ni], 0, 0, 0);
        acc[mi][ni] = __builtin_amdgcn_mfma_f32_16x16x32_bf16(al[mi], bh[ni], acc[mi][ni], 0, 0, 0);
      }
  }

  const SegOne sgo = pickseg(sg, bn >> 9);
  const bool facc = sgo.flags & 1, fsig = sgo.flags & 2, fhr = sgo.flags & 4;
  const bool frelu = sgo.flags & 8, facq = sgo.flags & 32;
#pragma unroll
  for (int mi = 0; mi < 4; ++mi) {
#pragma unroll
    for (int q = 0; q < 4; ++q) {
      int row = bm + wr * 64 + mi * 16 + (l >> 4) * 4 + q;
      if (row >= Nrows) continue;
#pragma unroll
      for (int ni = 0; ni < 4; ++ni) {
        int col = bn + wc * 64 + ni * 16 + (l & 15);
        float v = acc[mi][ni][q];
        size_t off = (size_t)row * sgo.ldc + (col & 511);
        if (facc) v += bf2f(sgo.ACh[off]) + bf2f(sgo.ACl[off]);
        else if (facq) v += __half2float(sgo.ACq[off]);
        else if (sgo.bias) v += sgo.bias[col & 511];
        if (fsig) v = 1.0f / (1.0f + expf(-v));
        if (fhr) {
          float rr = 1.0f / (1.0f + expf(-v));
          v = (bf2f(sgo.AXh[off]) + bf2f(sgo.AXl[off])) * rr;
        }
        if (frelu) v = fmaxf(v, 0.f);
        if (sgo.Ch) {
          uint16_t h = f2bf(v);
          sgo.Ch[off] = h;
          sgo.Cl[off] = f2bf(v - bf2f(h));
        }
        if (sgo.Cq) sgo.Cq[off] = __float2half(v);
      }
    }
  }
}

// ---------------- GRU combine (PB=4): Hacc = sum_p probs*(...) + relu planes
__global__ __launch_bounds__(256) void accum_fused_k(
    const __half* __restrict__ Zq, const uint16_t* __restrict__ Hh,
    const uint16_t* __restrict__ Hl, const __half* __restrict__ Tq,
    const float* __restrict__ probs, float* __restrict__ hacc,
    uint16_t* __restrict__ Rh, uint16_t* __restrict__ Rl, int N) {
  int node = (blockIdx.x * 256 + threadIdx.x) >> 6;
  int l = threadIdx.x & 63;
  if (node >= N) return;
  float sum[8] = {};
  union U16x8 { uint4 u; __half2 h[4]; };
#pragma unroll
  for (int pr = 0; pr < 4; ++pr) {
    float pw = probs[pr];
    size_t ro = ((size_t)node * 4 + pr) * 512 + l * 8;
    U16x8 zq, tq;
    zq.u = *(const uint4*)(Zq + ro);
    tq.u = *(const uint4*)(Tq + ro);
    bf16x8 hh = *(const bf16x8*)(Hh + ro), hl = *(const bf16x8*)(Hl + ro);
#pragma unroll
    for (int j = 0; j < 4; ++j) {
      float2 z2 = __half22float2(zq.h[j]);
      float2 t2 = __half22float2(tq.h[j]);
      float h0 = bf2f((uint16_t)hh[j * 2]) + bf2f((uint16_t)hl[j * 2]);
      float h1 = bf2f((uint16_t)hh[j * 2 + 1]) + bf2f((uint16_t)hl[j * 2 + 1]);
      sum[j * 2] += pw * (z2.x * h0 + (1.0f - z2.x) * tanhf(t2.x));
      sum[j * 2 + 1] += pw * (z2.y * h1 + (1.0f - z2.y) * tanhf(t2.y));
    }
  }
  float* o = hacc + (size_t)node * 512 + l * 8;
  uint16_t h8[8], l8[8];
#pragma unroll
  for (int j = 0; j < 8; ++j) {
    o[j] = sum[j];
    float rv = fmaxf(sum[j], 0.f);
    uint16_t h = f2bf(rv);
    h8[j] = h;
    l8[j] = f2bf(rv - bf2f(h));
  }
  size_t po = (size_t)node * 512 + l * 8;
  *(bf16x8*)(Rh + po) = *(bf16x8*)h8;
  *(bf16x8*)(Rl + po) = *(bf16x8*)l8;
}

// fallback (PB<4): Hacc += sum
template <int PB>
__global__ __launch_bounds__(256) void accum_k(
    const __half* __restrict__ Zq, const uint16_t* __restrict__ Hh,
    const uint16_t* __restrict__ Hl, const __half* __restrict__ Tq,
    const float* __restrict__ probs, float* __restrict__ hacc, int N, int p0) {
  int node = (blockIdx.x * 256 + threadIdx.x) >> 6;
  int l = threadIdx.x & 63;
  if (node >= N) return;
  float sum[8] = {};
#pragma unroll
  for (int pr = 0; pr < PB; ++pr) {
    float pw = probs[p0 + pr];
    size_t ro = ((size_t)node * PB + pr) * 512 + l * 8;
#pragma unroll
    for (int j = 0; j < 8; ++j) {
      float z = __half2float(Zq[ro + j]);
      float h = bf2f(Hh[ro + j]) + bf2f(Hl[ro + j]);
      float t = tanhf(__half2float(Tq[ro + j]));
      sum[j] += pw * (z * h + (1.0f - z) * t);
    }
  }
  float* o = hacc + (size_t)node * 512 + l * 8;
#pragma unroll
  for (int j = 0; j < 8; ++j) o[j] += sum[j];
}

__global__ void reluconv_k(const float* __restrict__ in, uint16_t* __restrict__ oh,
                           uint16_t* __restrict__ ol, int n4) {
  int i = blockIdx.x * blockDim.x + threadIdx.x;
  if (i >= n4) return;
  float4 v = ((const float4*)in)[i];
  float a[4] = {fmaxf(v.x, 0.f), fmaxf(v.y, 0.f), fmaxf(v.z, 0.f), fmaxf(v.w, 0.f)};
  uint16_t h4[4], l4[4];
#pragma unroll
  for (int j = 0; j < 4; ++j) {
    h4[j] = f2bf(a[j]);
    l4[j] = f2bf(a[j] - bf2f(h4[j]));
  }
  ((uint2*)oh)[i] = *(uint2*)h4;
  ((uint2*)ol)[i] = *(uint2*)l4;
}

// out[i] = dot(A[i,:K] fp16, w) + b[0]
__global__ __launch_bounds__(256) void matvec_k(const __half* __restrict__ A,
                                                const float* __restrict__ w,
                                                const float* __restrict__ b,
                                                float* __restrict__ out, int N, int K) {
  int gw = (blockIdx.x * 256 + threadIdx.x) >> 6;
  int lane = threadIdx.x & 63;
  if (gw >= N) return;
  float s = 0.0f;
  for (int k = lane; k < K; k += 64) s += __half2float(A[(size_t)gw * K + k]) * w[k];
#pragma unroll
  for (int off = 32; off > 0; off >>= 1) s += __shfl_down(s, off);
  if (lane == 0) out[gw] = s + b[0];
}

extern "C" void kernel_launch(void* const* d_in, const int* in_sizes, int n_in,
                              void* d_out, int out_size, void* d_ws, size_t ws_size,
                              hipStream_t stream) {
  const int N = 10000, F = 128, P = 4, E = 160000;
  const int C = 512, HID = 256;
  const int NC = N * C;
  (void)F; (void)in_sizes; (void)n_in;

  const float* x     = (const float*)d_in[0];
  const int*   ei    = (const int*)d_in[1];
  const float* ea    = (const float*)d_in[2];
  const float* W1    = (const float*)d_in[3];
  const float* b1    = (const float*)d_in[4];
  const float* W2    = (const float*)d_in[5];
  const float* b2    = (const float*)d_in[6];
  const float* W3    = (const float*)d_in[7];
  const float* b3    = (const float*)d_in[8];
  const float* W4    = (const float*)d_in[9];
  const float* b4    = (const float*)d_in[10];
  const float* W5    = (const float*)d_in[11];
  const float* b5    = (const float*)d_in[12];
  const float* Wz    = (const float*)d_in[13];
  const float* bz    = (const float*)d_in[14];
  const float* Lz_w  = (const float*)d_in[15];
  const float* Lz_b  = (const float*)d_in[16];
  const float* Wr    = (const float*)d_in[17];
  const float* br    = (const float*)d_in[18];
  const float* Lr_w  = (const float*)d_in[19];
  const float* Lr_b  = (const float*)d_in[20];
  const float* Wh    = (const float*)d_in[21];
  const float* bh    = (const float*)d_in[22];
  const float* Lh_w  = (const float*)d_in[23];
  const float* Lh_b  = (const float*)d_in[24];
  const float* attn  = (const float*)d_in[25];
  const float* lin1w = (const float*)d_in[26];
  const float* lin1b = (const float*)d_in[27];
  const float* lin2w = (const float*)d_in[28];
  const float* lin2b = (const float*)d_in[29];

  // ---- pick PB (same bound as before -> stable choice) ----
  auto need = [&](int PBv) -> size_t {
    size_t NBpv = ((size_t)PBv * N + 127) / 128 * 128;
    return ((size_t)16 << 20) + NBpv * 128 * 4 + NBpv * 512 * 4 * 5;
  };
  int PB = 1;
  if (ws_size >= need(4)) PB = 4;
  else if (ws_size >= need(2)) PB = 2;
  const int NB = PB * N;
  const size_t NBp = ((size_t)NB + 127) / 128 * 128;

  // ---- workspace carve-out ----
  char* wsp = (char*)d_ws;
  auto alloc = [&](size_t bytes) -> char* {
    char* ret = wsp;
    wsp += (bytes + 255) & ~(size_t)255;
    return ret;
  };
  float* deg    = (float*)alloc((size_t)N * 4);
  float* dinv   = (float*)alloc((size_t)N * 4);
  float* dinv2  = (float*)alloc((size_t)N * 4);
  int*   counts = (int*)alloc((size_t)N * 4);
  int*   rowp   = (int*)alloc((size_t)(N + 1) * 4);
  int2*  csrE   = (int2*)alloc((size_t)E * 8);
  float* probs  = (float*)alloc(256);

  auto wplanes = [&](size_t n, uint16_t** h, uint16_t** lo) {
    *h = (uint16_t*)alloc(n * 2);
    *lo = (uint16_t*)alloc(n * 2);
  };
  uint16_t *W1h, *W1l, *W2h, *W2l, *W3h, *W3l, *W4h, *W4l, *W5h, *W5l;
  uint16_t *LZRh, *LZRl, *LhBh, *LhBl, *l1h, *l1l, *G3H, *G3L;
  wplanes((size_t)128 * 512, &W1h, &W1l);
  wplanes((size_t)512 * 512, &W2h, &W2l);
  wplanes((size_t)512 * 512, &W3h, &W3l);
  wplanes((size_t)512 * 512, &W4h, &W4l);
  wplanes((size_t)512 * 512, &W5h, &W5l);
  wplanes((size_t)1024 * 512, &LZRh, &LZRl);  // [LzB | LrB] as [1024][512]
  wplanes((size_t)512 * 512, &LhBh, &LhBl);
  wplanes((size_t)512 * 256, &l1h, &l1l);
  wplanes((size_t)1536 * 128, &G3H, &G3L);    // folded tops [1536][128]
  float* gbias = (float*)alloc(1536 * 4);

  uint16_t* AXh = (uint16_t*)alloc(NBp * 128 * 2);
  uint16_t* AXl = (uint16_t*)alloc(NBp * 128 * 2);
  uint16_t* T1h = (uint16_t*)alloc(NBp * 512 * 2);  // agg-out / HR / relu planes
  uint16_t* T1l = (uint16_t*)alloc(NBp * 512 * 2);
  __half*   U16 = (__half*)alloc(NBp * 512 * 2);    // conv-chain fp16 / R-top
  uint16_t* Hh  = (uint16_t*)alloc(NBp * 512 * 2);  // H planes
  uint16_t* Hl  = (uint16_t*)alloc(NBp * 512 * 2);
  __half*   Zq  = (__half*)alloc(NBp * 512 * 2);    // Z-top -> Z
  __half*   Tq  = (__half*)alloc(NBp * 512 * 2);    // h-top -> Ht_pre

  float* Hacc = (float*)d_out + 10000;

  // ---- preprocessing ----
  if (PB != 4) hipMemsetAsync(d_out, 0, (size_t)out_size * sizeof(float), stream);
  init_k<<<(N + 255) / 256, 256, 0, stream>>>(deg, counts, N);
  edge_k<<<(E + 255) / 256, 256, 0, stream>>>(ei, ea, deg, counts, E);
  dinv_k<<<(N + 255) / 256, 256, 0, stream>>>(deg, dinv, dinv2, N);
  scan_sm_k<<<1, 1024, 0, stream>>>(counts, rowp, N, attn, probs);
  fill_k<<<(E + 255) / 256, 256, 0, stream>>>(ei, ea, dinv, rowp, counts, csrE, E);

  {
    WCdesc d;
    const float* srcs[9] = {W1, W2, W3, W4, W5,
                            Lz_w + (size_t)512 * 512, Lr_w + (size_t)512 * 512,
                            Lh_w + (size_t)512 * 512, lin1w};
    uint16_t* dhs[9] = {W1h, W2h, W3h, W4h, W5h, LZRh, LZRh + (size_t)512 * 512, LhBh, l1h};
    uint16_t* dls[9] = {W1l, W2l, W3l, W4l, W5l, LZRl, LZRl + (size_t)512 * 512, LhBl, l1l};
    int Ks[9] = {128, 512, 512, 512, 512, 512, 512, 512, 512};
    int Cos[9] = {512, 512, 512, 512, 512, 512, 512, 512, 256};
    for (int i = 0; i < 9; ++i) {
      d.src[i] = srcs[i]; d.dh[i] = dhs[i]; d.dl[i] = dls[i];
      d.K[i] = Ks[i]; d.Co[i] = Cos[i];
    }
    wconv_all_k<<<dim3(16, 16, 9), 256, 0, stream>>>(d);
  }
  {
    WFdesc d;
    d.Wg[0] = Wz; d.Wg[1] = Wr; d.Wg[2] = Wh;
    d.Lt[0] = Lz_w; d.Lt[1] = Lr_w; d.Lt[2] = Lh_w;
    wfold3_k<<<dim3(16, 4, 3), 256, 0, stream>>>(d, G3H, G3L);
  }
  gbias_k<<<6, 256, 0, stream>>>(bz, Lz_w, Lz_b, br, Lr_w, Lr_b, bh, Lh_w, Lh_b, gbias);

  auto setseg = [](Seg4& s, int i, SegOne v) {
    s.ACh[i] = v.ACh; s.ACl[i] = v.ACl; s.ACq[i] = v.ACq;
    s.AXh[i] = v.AXh; s.AXl[i] = v.AXl;
    s.Ch[i] = v.Ch; s.Cl[i] = v.Cl; s.Cq[i] = v.Cq;
    s.bias[i] = v.bias; s.flags[i] = v.flags; s.ldc[i] = v.ldc;
  };
  auto gemm = [&](const uint16_t* Ah, const uint16_t* Al, int lda,
                  const uint16_t* Bh, const uint16_t* Bl, int ldb,
                  const Seg4& sg, int Nrows, int K, int Co) {
    dim3 g((Nrows + 127) / 128, Co / 128);
    gemm_sp_k<<<g, 256, 0, stream>>>(Ah, Al, lda, Bh, Bl, ldb, sg, Nrows, K, Co);
  };

  const int aggBlocks = (N * 64 + 255) / 256;
  auto agg5 = [&]() {
    if (PB == 4)
      agg512q_k<4, 4><<<(N * 4 * 64 + 255) / 256, 256, 0, stream>>>(U16, T1h, T1l, rowp, csrE, dinv2, N);
    else if (PB == 2)
      agg512q_k<2, 2><<<(N * 2 * 64 + 255) / 256, 256, 0, stream>>>(U16, T1h, T1l, rowp, csrE, dinv2, N);
    else
      agg512q_k<1, 1><<<aggBlocks, 256, 0, stream>>>(U16, T1h, T1l, rowp, csrE, dinv2, N);
  };

  for (int p0 = 0; p0 < P; p0 += PB) {
    if (PB == 4)      agg128_k<4><<<aggBlocks, 256, 0, stream>>>(x, AXh, AXl, rowp, csrE, dinv2, N, p0);
    else if (PB == 2) agg128_k<2><<<aggBlocks, 256, 0, stream>>>(x, AXh, AXl, rowp, csrE, dinv2, N, p0);
    else              agg128_k<1><<<aggBlocks, 256, 0, stream>>>(x, AXh, AXl, rowp, csrE, dinv2, N, p0);

    // conv stack: h_{i+1} = (A h_i) W + b  (U16 = fp16 inter-buffer)
    // SegOne field order: ACh, ACl, ACq, AXh, AXl, Ch, Cl, Cq, bias, flags, ldc
    { Seg4 s{}; setseg(s, 0, {nullptr, nullptr, nullptr, nullptr, nullptr, nullptr, nullptr, U16, b1, 16, 512});
      gemm(AXh, AXl, 128, W1h, W1l, 128, s, NB, 128, 512); }
    agg5();
    { Seg4 s{}; setseg(s, 0, {nullptr, nullptr, nullptr, nullptr, nullptr, nullptr, nullptr, U16, b2, 16, 512});
      gemm(T1h, T1l, 512, W2h, W2l, 512, s, NB, 512, 512); }
    agg5();
    { Seg4 s{}; setseg(s, 0, {nullptr, nullptr, nullptr, nullptr, nullptr, nullptr, nullptr, U16, b3, 16, 512});
      gemm(T1h, T1l, 512, W3h, W3l, 512, s, NB, 512, 512); }
    agg5();
    { Seg4 s{}; setseg(s, 0, {nullptr, nullptr, nullptr, nullptr, nullptr, nullptr, nullptr, U16, b4, 16, 512});
      gemm(T1h, T1l, 512, W4h, W4l, 512, s, NB, 512, 512); }
    agg5();
    // H planes out: Ch=Hh, Cl=Hl  (R7 fix: 5 nulls before Ch/Cl, not 4)
    { Seg4 s{}; setseg(s, 0, {nullptr, nullptr, nullptr, nullptr, nullptr, Hh, Hl, nullptr, b5, 0, 512});
      gemm(T1h, T1l, 512, W5h, W5l, 512, s, NB, 512, 512); }

    // batched gate tops: Co=1536 -> Zq | U16(R-top) | Tq  (all fp16)
    { Seg4 s{};
      setseg(s, 0, {nullptr, nullptr, nullptr, nullptr, nullptr, nullptr, nullptr, Zq, gbias, 16, 512});
      setseg(s, 1, {nullptr, nullptr, nullptr, nullptr, nullptr, nullptr, nullptr, U16, gbias + 512, 16, 512});
      setseg(s, 2, {nullptr, nullptr, nullptr, nullptr, nullptr, nullptr, nullptr, Tq, gbias + 1024, 16, 512});
      gemm(AXh, AXl, 128, G3H, G3L, 128, s, NB, 128, 1536); }

    // batched Z/R bottoms: Co=1024
    //  seg0: Z = sigmoid(Ztop + H@LzB) -> Zq (fp16, in-place ACC)
    //  seg1: HR = H * sigmoid(Rtop + H@LrB) -> T1 planes (GEMM-A of H-bot)
    { Seg4 s{};
      setseg(s, 0, {nullptr, nullptr, Zq, nullptr, nullptr, nullptr, nullptr, Zq, nullptr, 32 | 2 | 16, 512});
      setseg(s, 1, {nullptr, nullptr, U16, Hh, Hl, T1h, T1l, nullptr, nullptr, 32 | 4, 512});
      gemm(Hh, Hl, 512, LZRh, LZRl, 512, s, NB, 512, 1024); }

    // candidate bottom: Ht_pre = h-top + HR@LhB -> Tq (fp16)
    { Seg4 s{}; setseg(s, 0, {nullptr, nullptr, Tq, nullptr, nullptr, nullptr, nullptr, Tq, nullptr, 32 | 16, 512});
      gemm(T1h, T1l, 512, LhBh, LhBl, 512, s, NB, 512, 512); }

    if (PB == 4)
      accum_fused_k<<<aggBlocks, 256, 0, stream>>>(Zq, Hh, Hl, Tq, probs, Hacc, T1h, T1l, N);
    else if (PB == 2)
      accum_k<2><<<aggBlocks, 256, 0, stream>>>(Zq, Hh, Hl, Tq, probs, Hacc, N, p0);
    else
      accum_k<1><<<aggBlocks, 256, 0, stream>>>(Zq, Hh, Hl, Tq, probs, Hacc, N, p0);
  }

  if (PB != 4)
    reluconv_k<<<(NC / 4 + 255) / 256, 256, 0, stream>>>(Hacc, T1h, T1l, NC / 4);

  // final MLP: relu(Hacc) planes -> lin1(+relu, fp16 out) -> lin2 matvec
  { Seg4 s{}; setseg(s, 0, {nullptr, nullptr, nullptr, nullptr, nullptr, nullptr, nullptr, (__half*)Hh, lin1b, 8 | 16, 256});
    gemm(T1h, T1l, 512, l1h, l1l, 512, s, N, 512, HID); }
  matvec_k<<<(N * 64 + 255) / 256, 256, 0, stream>>>((__half*)Hh, lin2w, lin2b, (float*)d_out, N, HID);
}

// Round 9
// 1777.936 us; speedup vs baseline: 2.3881x; 1.2618x over previous
//
#include <hip/hip_runtime.h>
#include <hip/hip_fp16.h>
#include <cstdint>
#include <cstddef>

// ---------------------------------------------------------------------------
// ConvStackedTemporalGCN — R9: conv-stack factorization (R8 + compile fix)
// N=10000, F=128, P=4, E=160000, C=512, HID=256
//
//  * A (node op) and W (feature op) commute =>
//      H = A^5 X Wc + sum_i (A^{5-i} 1) (b_i^T P_i) + 1 b5^T,
//    Wc = W1..W5 [128,512], P_i = W_{i+1}..W5. The 4 agg512 + 4 K512 conv
//    GEMMs become 4 agg128(fp16) + 1 K128 GEMM with a rank-4 epilogue.
//  * Gate fold: top = (AX)@(Wg@L_top) + folded bias ; bot = H@L_bot.
//  * Segmented GEMM: one dispatch = several 512-col segments w/ own epilogue.
//  * GEMM A/B operands split hi+lo bf16 (3-product, ~1e-5 rel); activation
//    streams fp16.
//  R9 fix: svec_k calls now cast (float*)sv4 (was float4* type mismatch).
// ---------------------------------------------------------------------------

typedef short bf16x8 __attribute__((ext_vector_type(8)));
typedef float f32x4 __attribute__((ext_vector_type(4)));

__device__ __forceinline__ uint16_t f2bf(float f) {
  uint32_t u = __float_as_uint(f);
  u += 0x7FFFu + ((u >> 16) & 1u);
  return (uint16_t)(u >> 16);
}
__device__ __forceinline__ float bf2f(uint16_t h) {
  return __uint_as_float((uint32_t)h << 16);
}
__device__ __forceinline__ void gl16(const void* g, void* l) {
  __builtin_amdgcn_global_load_lds((const __attribute__((address_space(1))) uint32_t*)g,
                                   (__attribute__((address_space(3))) uint32_t*)l, 16, 0, 0);
}

// ---------------- graph preprocessing ----------------
__global__ void init_k(float* deg, int* counts, int N) {
  int i = blockIdx.x * blockDim.x + threadIdx.x;
  if (i < N) { deg[i] = 1.0f; counts[i] = 0; }
}
__global__ void edge_k(const int* __restrict__ ei, const float* __restrict__ ea,
                       float* deg, int* counts, int E) {
  int e = blockIdx.x * blockDim.x + threadIdx.x;
  if (e < E) {
    int d = ei[E + e];
    atomicAdd(&deg[d], ea[e]);
    atomicAdd(&counts[d], 1);
  }
}
__global__ void dinv_k(const float* __restrict__ deg, float* dinv, float* dinv2, int N) {
  int i = blockIdx.x * blockDim.x + threadIdx.x;
  if (i < N) {
    float d = deg[i];
    float r = d > 0.0f ? rsqrtf(d) : 0.0f;
    dinv[i] = r;
    dinv2[i] = r * r;
  }
}
__global__ void scan_sm_k(int* __restrict__ counts, int* row_ptr, int n,
                          const float* __restrict__ attn, float* probs) {
  __shared__ int wtot[16];
  __shared__ int carry_s;
  int tid = threadIdx.x, lane = tid & 63, w = tid >> 6;
  if (tid == 0) carry_s = 0;
  __syncthreads();
  for (int base = 0; base < n; base += 1024) {
    int i = base + tid;
    int v = 0;
    if (i < n) { v = counts[i]; counts[i] = 0; }
    int s = v;
#pragma unroll
    for (int off = 1; off < 64; off <<= 1) {
      int t = __shfl_up(s, off);
      if (lane >= off) s += t;
    }
    if (lane == 63) wtot[w] = s;
    __syncthreads();
    if (w == 0) {
      int t16 = (lane < 16) ? wtot[lane] : 0;
#pragma unroll
      for (int off = 1; off < 16; off <<= 1) {
        int t = __shfl_up(t16, off);
        if (lane >= off) t16 += t;
      }
      if (lane < 16) wtot[lane] = t16;
    }
    __syncthreads();
    int carry = carry_s;
    int woff = (w > 0) ? wtot[w - 1] : 0;
    int incl = carry + woff + s;
    if (i < n) row_ptr[i] = incl - v;
    __syncthreads();
    if (tid == 1023) carry_s = incl;
    __syncthreads();
  }
  if (tid == 0) {
    row_ptr[n] = carry_s;
    float a0 = attn[0], a1 = attn[1], a2 = attn[2], a3 = attn[3];
    float m = fmaxf(fmaxf(a0, a1), fmaxf(a2, a3));
    float e0 = expf(a0 - m), e1 = expf(a1 - m), e2 = expf(a2 - m), e3 = expf(a3 - m);
    float s4 = e0 + e1 + e2 + e3;
    probs[0] = e0 / s4; probs[1] = e1 / s4; probs[2] = e2 / s4; probs[3] = e3 / s4;
  }
}
__global__ void fill_k(const int* __restrict__ ei, const float* __restrict__ ea,
                       const float* __restrict__ dinv, const int* __restrict__ row_ptr,
                       int* cursor, int2* __restrict__ csrE, int E) {
  int e = blockIdx.x * blockDim.x + threadIdx.x;
  if (e < E) {
    int s = ei[e], d = ei[E + e];
    float w = dinv[s] * ea[e] * dinv[d];
    int pos = atomicAdd(&cursor[d], 1);
    csrE[row_ptr[d] + pos] = make_int2(s, __float_as_int(w));
  }
}

// ---------------- small fp32 GEMM: C[M,Cc] = A[M,512] @ B[512,Cc] ----------
__global__ void mm512_k(const float* __restrict__ A, const float* __restrict__ B,
                        float* __restrict__ C, int M, int Cc) {
  __shared__ float a[32][33], b[32][33];
  int c0 = blockIdx.x * 32, m0 = blockIdx.y * 32;
  int tx = threadIdx.x & 31, ty = threadIdx.x >> 5;
  float acc[4] = {0.f, 0.f, 0.f, 0.f};
  for (int k0 = 0; k0 < 512; k0 += 32) {
    for (int r = ty; r < 32; r += 8) a[r][tx] = A[(size_t)(m0 + r) * 512 + k0 + tx];
    for (int r = ty; r < 32; r += 8) b[r][tx] = B[(size_t)(k0 + r) * Cc + c0 + tx];
    __syncthreads();
    for (int kk = 0; kk < 32; ++kk) {
      float bv = b[kk][tx];
#pragma unroll
      for (int q = 0; q < 4; ++q) acc[q] += a[ty * 4 + q][kk] * bv;
    }
    __syncthreads();
  }
#pragma unroll
  for (int q = 0; q < 4; ++q) C[(size_t)(m0 + ty * 4 + q) * Cc + c0 + tx] = acc[q];
}

// ---------------- rank-1 bias helpers --------------------------------------
// c_i = P_i^T b_i ; cm4[col] = (c1,c2,c3,c4)
__global__ void cvec_k(const float* b1, const float* b2, const float* b3, const float* b4,
                       const float* P1, const float* P2, const float* P3, const float* P4,
                       float4* __restrict__ cm4) {
  int c = blockIdx.x * 256 + threadIdx.x;
  if (c >= 512) return;
  float s1 = 0.f, s2 = 0.f, s3 = 0.f, s4 = 0.f;
  for (int k = 0; k < 512; ++k) {
    s1 += b1[k] * P1[(size_t)k * 512 + c];
    s2 += b2[k] * P2[(size_t)k * 512 + c];
    s3 += b3[k] * P3[(size_t)k * 512 + c];
    s4 += b4[k] * P4[(size_t)k * 512 + c];
  }
  cm4[c] = make_float4(s1, s2, s3, s4);
}
// one power step: sv4[i*4+outc] = (A v)[i], v from sv4[.*4+inc] or ones
__global__ void svec_k(const int* __restrict__ rowp, const int2* __restrict__ csrE,
                       const float* __restrict__ dinv2, float* sv4,
                       int inc, int outc, int useOnes, int N) {
  int i = blockIdx.x * 256 + threadIdx.x;
  if (i >= N) return;
  float vi = useOnes ? 1.0f : sv4[i * 4 + inc];
  float s = dinv2[i] * vi;
  int a = rowp[i], b = rowp[i + 1];
  for (int idx = a; idx < b; ++idx) {
    int2 pk = csrE[idx];
    float w = __int_as_float(pk.y);
    float vs = useOnes ? 1.0f : sv4[pk.x * 4 + inc];
    s += w * vs;
  }
  sv4[i * 4 + outc] = s;
}

// ---------------- weight transposes+splits (one launch) --------------------
struct WCdesc {
  const float* src[9];
  uint16_t* dh[9];
  uint16_t* dl[9];
  int K[9];
  int Co[9];
};
__global__ void wconv_all_k(WCdesc d) {
  int z = blockIdx.z;
  int K, Co;
  const float* W;
  uint16_t *Th, *Tl;
  switch (z) {
    case 0: W = d.src[0]; Th = d.dh[0]; Tl = d.dl[0]; K = d.K[0]; Co = d.Co[0]; break;
    case 1: W = d.src[1]; Th = d.dh[1]; Tl = d.dl[1]; K = d.K[1]; Co = d.Co[1]; break;
    case 2: W = d.src[2]; Th = d.dh[2]; Tl = d.dl[2]; K = d.K[2]; Co = d.Co[2]; break;
    case 3: W = d.src[3]; Th = d.dh[3]; Tl = d.dl[3]; K = d.K[3]; Co = d.Co[3]; break;
    case 4: W = d.src[4]; Th = d.dh[4]; Tl = d.dl[4]; K = d.K[4]; Co = d.Co[4]; break;
    case 5: W = d.src[5]; Th = d.dh[5]; Tl = d.dl[5]; K = d.K[5]; Co = d.Co[5]; break;
    case 6: W = d.src[6]; Th = d.dh[6]; Tl = d.dl[6]; K = d.K[6]; Co = d.Co[6]; break;
    case 7: W = d.src[7]; Th = d.dh[7]; Tl = d.dl[7]; K = d.K[7]; Co = d.Co[7]; break;
    default: W = d.src[8]; Th = d.dh[8]; Tl = d.dl[8]; K = d.K[8]; Co = d.Co[8]; break;
  }
  int bco = blockIdx.x * 32, bk = blockIdx.y * 32;
  if (bco >= Co || bk >= K) return;
  __shared__ float t[32][33];
  int tx = threadIdx.x & 31, ty = threadIdx.x >> 5;
  for (int r = ty; r < 32; r += 8) t[r][tx] = W[(size_t)(bk + r) * Co + bco + tx];
  __syncthreads();
  for (int r = ty; r < 32; r += 8) {
    float v = t[tx][r];
    uint16_t h = f2bf(v);
    size_t o = (size_t)(bco + r) * K + bk + tx;
    Th[o] = h;
    Tl[o] = f2bf(v - bf2f(h));
  }
}

// ---------------- 3 gate-weight folds in one launch ------------------------
struct WFdesc { const float* Wg[3]; const float* Lt[3]; };
__global__ void wfold3_k(WFdesc d, uint16_t* __restrict__ Oh, uint16_t* __restrict__ Ol) {
  int z = blockIdx.z;
  const float *Wg, *Lt;
  switch (z) {
    case 0: Wg = d.Wg[0]; Lt = d.Lt[0]; break;
    case 1: Wg = d.Wg[1]; Lt = d.Lt[1]; break;
    default: Wg = d.Wg[2]; Lt = d.Lt[2]; break;
  }
  __shared__ float a[32][33], b[32][33];
  int c0 = blockIdx.x * 32, f0 = blockIdx.y * 32;
  int tx = threadIdx.x & 31, ty = threadIdx.x >> 5;
  float acc[4] = {0.f, 0.f, 0.f, 0.f};
  for (int k0 = 0; k0 < 512; k0 += 32) {
    for (int r = ty; r < 32; r += 8) a[r][tx] = Wg[(size_t)(f0 + r) * 512 + k0 + tx];
    for (int r = ty; r < 32; r += 8) b[r][tx] = Lt[(size_t)(k0 + r) * 512 + c0 + tx];
    __syncthreads();
    for (int kk = 0; kk < 32; ++kk) {
      float bv = b[kk][tx];
#pragma unroll
      for (int q = 0; q < 4; ++q) acc[q] += a[ty * 4 + q][kk] * bv;
    }
    __syncthreads();
  }
  size_t base = (size_t)z * 512 * 128;
#pragma unroll
  for (int q = 0; q < 4; ++q) {
    int f = f0 + ty * 4 + q, c = c0 + tx;
    float v = acc[q];
    uint16_t h = f2bf(v);
    Oh[base + (size_t)c * 128 + f] = h;
    Ol[base + (size_t)c * 128 + f] = f2bf(v - bf2f(h));
  }
}
__global__ void gbias_k(const float* bz, const float* Lz, const float* Lzb,
                        const float* br, const float* Lr, const float* Lrb,
                        const float* bh, const float* Lh, const float* Lhb,
                        float* __restrict__ out) {
  int c = blockIdx.x * 256 + threadIdx.x;
  if (c >= 1536) return;
  int g = c >> 9, cc = c & 511;
  const float* bsrc = g == 0 ? bz : (g == 1 ? br : bh);
  const float* L    = g == 0 ? Lz : (g == 1 ? Lr : Lh);
  const float* lb   = g == 0 ? Lzb : (g == 1 ? Lrb : Lhb);
  float s = lb[cc];
  for (int k = 0; k < 512; ++k) s += bsrc[k] * L[(size_t)k * 512 + cc];
  out[c] = s;
}

// ---------------- first-hop aggregation from x -> Y1 fp16 + AX planes ------
template <int PB>
__global__ __launch_bounds__(256) void agg128x_k(
    const float* __restrict__ x, __half* __restrict__ Y,
    uint16_t* __restrict__ outh, uint16_t* __restrict__ outl,
    const int* __restrict__ rowp, const int2* __restrict__ csrE,
    const float* __restrict__ dinv2, int N, int p0) {
  int node = (blockIdx.x * 256 + threadIdx.x) >> 6;
  int l = threadIdx.x & 63;
  if (node >= N) return;
  float acc[8];
  float w0 = dinv2[node];
  const float* sp = x + (size_t)node * 512 + l * 8;
  {
    float4 v0 = *(const float4*)sp;
    float4 v1 = *(const float4*)(sp + 4);
    acc[0] = w0 * v0.x; acc[1] = w0 * v0.y; acc[2] = w0 * v0.z; acc[3] = w0 * v0.w;
    acc[4] = w0 * v1.x; acc[5] = w0 * v1.y; acc[6] = w0 * v1.z; acc[7] = w0 * v1.w;
  }
  int s = rowp[node], e = rowp[node + 1];
#pragma unroll 2
  for (int idx = s; idx < e; ++idx) {
    int2 pk = csrE[idx];
    int src = pk.x;
    float w = __int_as_float(pk.y);
    const float* rp = x + (size_t)src * 512 + l * 8;
    float4 v0 = *(const float4*)rp;
    float4 v1 = *(const float4*)(rp + 4);
    acc[0] += w * v0.x; acc[1] += w * v0.y; acc[2] += w * v0.z; acc[3] += w * v0.w;
    acc[4] += w * v1.x; acc[5] += w * v1.y; acc[6] += w * v1.z; acc[7] += w * v1.w;
  }
  // slot j: f = l*2 + (j>>2) ; p = j&3   (x is [F][P] per node)
#pragma unroll
  for (int pr = 0; pr < PB; ++pr) {
    int pa = p0 + pr;
    float v0 = acc[pa], v1 = acc[4 + pa];
    size_t o = ((size_t)node * PB + pr) * 128 + l * 2;
    uint16_t h0 = f2bf(v0), h1 = f2bf(v1);
    uint16_t lo0 = f2bf(v0 - bf2f(h0)), lo1 = f2bf(v1 - bf2f(h1));
    *(uint32_t*)(outh + o) = (uint32_t)h0 | ((uint32_t)h1 << 16);
    *(uint32_t*)(outl + o) = (uint32_t)lo0 | ((uint32_t)lo1 << 16);
    __half2 yv = __floats2half2_rn(v0, v1);
    *(__half2*)(Y + o) = yv;
  }
}

// ---------------- fp16 aggregation over [NB][128] rows ---------------------
template <int PB>
__global__ __launch_bounds__(256) void agg128h_k(
    const __half* __restrict__ in, __half* __restrict__ out,
    uint16_t* __restrict__ outh, uint16_t* __restrict__ outl,
    const int* __restrict__ rowp, const int2* __restrict__ csrE,
    const float* __restrict__ dinv2, int N) {
  int node = (blockIdx.x * 256 + threadIdx.x) >> 6;
  int l = threadIdx.x & 63;
  if (node >= N) return;
  float w0 = dinv2[node];
  if constexpr (PB == 4) {
    union U { uint4 u; __half2 h[4]; };
    float acc[8];
    U v;
    v.u = *(const uint4*)(in + (size_t)node * 512 + l * 8);
#pragma unroll
    for (int j = 0; j < 4; ++j) {
      float2 f = __half22float2(v.h[j]);
      acc[j * 2] = w0 * f.x;
      acc[j * 2 + 1] = w0 * f.y;
    }
    int s = rowp[node], e = rowp[node + 1];
#pragma unroll 4
    for (int idx = s; idx < e; ++idx) {
      int2 pk = csrE[idx];
      float w = __int_as_float(pk.y);
      U r;
      r.u = *(const uint4*)(in + (size_t)pk.x * 512 + l * 8);
#pragma unroll
      for (int j = 0; j < 4; ++j) {
        float2 f = __half22float2(r.h[j]);
        acc[j * 2] += w * f.x;
        acc[j * 2 + 1] += w * f.y;
      }
    }
    U o;
#pragma unroll
    for (int j = 0; j < 4; ++j) o.h[j] = __floats2half2_rn(acc[j * 2], acc[j * 2 + 1]);
    *(uint4*)(out + (size_t)node * 512 + l * 8) = o.u;
    if (outh) {
      uint16_t h8[8], l8[8];
#pragma unroll
      for (int j = 0; j < 8; ++j) {
        uint16_t h = f2bf(acc[j]);
        h8[j] = h;
        l8[j] = f2bf(acc[j] - bf2f(h));
      }
      size_t ro = (size_t)node * 512 + l * 8;
      *(bf16x8*)(outh + ro) = *(bf16x8*)h8;
      *(bf16x8*)(outl + ro) = *(bf16x8*)l8;
    }
  } else {
    float accx[PB], accy[PB];
    const size_t nb = (size_t)node * PB * 128 + l * 2;
#pragma unroll
    for (int p = 0; p < PB; ++p) {
      float2 f = __half22float2(*(const __half2*)(in + nb + (size_t)p * 128));
      accx[p] = w0 * f.x;
      accy[p] = w0 * f.y;
    }
    int s = rowp[node], e = rowp[node + 1];
    for (int idx = s; idx < e; ++idx) {
      int2 pk = csrE[idx];
      float w = __int_as_float(pk.y);
      const size_t sb = (size_t)pk.x * PB * 128 + l * 2;
#pragma unroll
      for (int p = 0; p < PB; ++p) {
        float2 f = __half22float2(*(const __half2*)(in + sb + (size_t)p * 128));
        accx[p] += w * f.x;
        accy[p] += w * f.y;
      }
    }
#pragma unroll
    for (int p = 0; p < PB; ++p) {
      size_t o = nb + (size_t)p * 128;
      *(__half2*)(out + o) = __floats2half2_rn(accx[p], accy[p]);
      if (outh) {
        uint16_t h0 = f2bf(accx[p]), h1 = f2bf(accy[p]);
        uint16_t lo0 = f2bf(accx[p] - bf2f(h0)), lo1 = f2bf(accy[p] - bf2f(h1));
        *(uint32_t*)(outh + o) = (uint32_t)h0 | ((uint32_t)h1 << 16);
        *(uint32_t*)(outl + o) = (uint32_t)lo0 | ((uint32_t)lo1 << 16);
      }
    }
  }
}

// ---------------- segmented split-bf16 GEMM --------------------------------
// flags: 1=ACC planes, 2=sigmoid, 4=HR(out=AUX*sigmoid), 8=relu,
//        16=fp16 out (Cq), 32=ACC fp16 (ACq), 64=rank4 bias (sv4·cm4 + bias)
struct SegOne {
  const uint16_t* ACh = nullptr;
  const uint16_t* ACl = nullptr;
  const __half* ACq = nullptr;
  const uint16_t* AXh = nullptr;
  const uint16_t* AXl = nullptr;
  uint16_t* Ch = nullptr;
  uint16_t* Cl = nullptr;
  __half* Cq = nullptr;
  const float* bias = nullptr;
  int flags = 0;
  int ldc = 512;
};
struct Seg4 {
  const uint16_t* ACh[4]; const uint16_t* ACl[4];
  const __half* ACq[4];
  const uint16_t* AXh[4]; const uint16_t* AXl[4];
  uint16_t* Ch[4]; uint16_t* Cl[4];
  __half* Cq[4];
  const float* bias[4];
  int flags[4];
  int ldc[4];
};
__device__ __forceinline__ SegOne pickseg(const Seg4& s, int i) {
  SegOne o;
  switch (i) {
    case 0: o.ACh = s.ACh[0]; o.ACl = s.ACl[0]; o.ACq = s.ACq[0]; o.AXh = s.AXh[0]; o.AXl = s.AXl[0];
            o.Ch = s.Ch[0]; o.Cl = s.Cl[0]; o.Cq = s.Cq[0]; o.bias = s.bias[0]; o.flags = s.flags[0]; o.ldc = s.ldc[0]; break;
    case 1: o.ACh = s.ACh[1]; o.ACl = s.ACl[1]; o.ACq = s.ACq[1]; o.AXh = s.AXh[1]; o.AXl = s.AXl[1];
            o.Ch = s.Ch[1]; o.Cl = s.Cl[1]; o.Cq = s.Cq[1]; o.bias = s.bias[1]; o.flags = s.flags[1]; o.ldc = s.ldc[1]; break;
    case 2: o.ACh = s.ACh[2]; o.ACl = s.ACl[2]; o.ACq = s.ACq[2]; o.AXh = s.AXh[2]; o.AXl = s.AXl[2];
            o.Ch = s.Ch[2]; o.Cl = s.Cl[2]; o.Cq = s.Cq[2]; o.bias = s.bias[2]; o.flags = s.flags[2]; o.ldc = s.ldc[2]; break;
    default: o.ACh = s.ACh[3]; o.ACl = s.ACl[3]; o.ACq = s.ACq[3]; o.AXh = s.AXh[3]; o.AXl = s.AXl[3];
             o.Ch = s.Ch[3]; o.Cl = s.Cl[3]; o.Cq = s.Cq[3]; o.bias = s.bias[3]; o.flags = s.flags[3]; o.ldc = s.ldc[3]; break;
  }
  return o;
}
__global__ __launch_bounds__(256) void gemm_sp_k(
    const uint16_t* __restrict__ Ah, const uint16_t* __restrict__ Al, int lda,
    const uint16_t* __restrict__ Bh, const uint16_t* __restrict__ Bl, int ldb,
    Seg4 sg, const float4* __restrict__ sv4, const float4* __restrict__ cm4,
    int nodeShift, int Nrows, int K, int Co) {
  __shared__ char lds[32768];
  const int tid = threadIdx.x;
  const int bm = blockIdx.x * 128, bn = blockIdx.y * 128;
  const int l = tid & 63, w = tid >> 6, wr = w >> 1, wc = w & 1;

  f32x4 acc[4][4];
#pragma unroll
  for (int i = 0; i < 4; ++i)
#pragma unroll
    for (int j = 0; j < 4; ++j) acc[i][j] = (f32x4){0.f, 0.f, 0.f, 0.f};

  const int r127 = tid & 127, ch = tid >> 7;
  const uint16_t* Ahp = Ah + (size_t)(bm + r127) * lda + ch * 8;
  const uint16_t* Alp = Al + (size_t)(bm + r127) * lda + ch * 8;
  const uint16_t* Bhp = Bh + (size_t)(bn + r127) * ldb + ch * 8;
  const uint16_t* Blp = Bl + (size_t)(bn + r127) * ldb + ch * 8;
  char* l0 = lds + (uint32_t)(tid & 192) * 16;

  for (int k0 = 0; k0 < K; k0 += 32) {
    __syncthreads();
    gl16(Ahp + k0, l0 + 0);
    gl16(Ahp + k0 + 16, l0 + 4096);
    gl16(Alp + k0, l0 + 8192);
    gl16(Alp + k0 + 16, l0 + 12288);
    gl16(Bhp + k0, l0 + 16384);
    gl16(Bhp + k0 + 16, l0 + 20480);
    gl16(Blp + k0, l0 + 24576);
    gl16(Blp + k0 + 16, l0 + 28672);
    __syncthreads();
    const uint32_t kc = (uint32_t)(l >> 4) * 2048;
    const uint32_t ar = kc + (uint32_t)(wr * 64 + (l & 15)) * 16;
    const uint32_t br = kc + (uint32_t)(wc * 64 + (l & 15)) * 16;
    bf16x8 ah[4], al[4], bh[4], bl[4];
#pragma unroll
    for (int i = 0; i < 4; ++i) {
      ah[i] = *(const bf16x8*)(lds + ar + i * 256);
      al[i] = *(const bf16x8*)(lds + 8192 + ar + i * 256);
      bh[i] = *(const bf16x8*)(lds + 16384 + br + i * 256);
      bl[i] = *(const bf16x8*)(lds + 24576 + br + i * 256);
    }
#pragma unroll
    for (int mi = 0; mi < 4; ++mi)
#pragma unroll
      for (int ni = 0; ni < 4; ++ni) {
        acc[mi][ni] = __builtin_amdgcn_mfma_f32_16x16x32_bf16(ah[mi], bh[ni], acc[mi][ni], 0, 0, 0);
        acc[mi][ni] = __builtin_amdgcn_mfma_f32_16x16x32_bf16(ah[mi], bl[ni], acc[mi][ni], 0, 0, 0);
        acc[mi][ni] = __builtin_amdgcn_mfma_f32_16x16x32_bf16(al[mi], bh[ni], acc[mi][ni], 0, 0, 0);
      }
  }

  const SegOne sgo = pickseg(sg, bn >> 9);
  const bool facc = sgo.flags & 1, fsig = sgo.flags & 2, fhr = sgo.flags & 4;
  const bool frelu = sgo.flags & 8, facq = sgo.flags & 32, frank4 = sgo.flags & 64;
#pragma unroll
  for (int mi = 0; mi < 4; ++mi) {
#pragma unroll
    for (int q = 0; q < 4; ++q) {
      int row = bm + wr * 64 + mi * 16 + (l >> 4) * 4 + q;
      if (row >= Nrows) continue;
#pragma unroll
      for (int ni = 0; ni < 4; ++ni) {
        int col = bn + wc * 64 + ni * 16 + (l & 15);
        float v = acc[mi][ni][q];
        size_t off = (size_t)row * sgo.ldc + (col & 511);
        if (facc) v += bf2f(sgo.ACh[off]) + bf2f(sgo.ACl[off]);
        else if (facq) v += __half2float(sgo.ACq[off]);
        else if (frank4) {
          float4 sv = sv4[row >> nodeShift];
          float4 cv = cm4[col & 511];
          v += sv.x * cv.x + sv.y * cv.y + sv.z * cv.z + sv.w * cv.w + sgo.bias[col & 511];
        } else if (sgo.bias) v += sgo.bias[col & 511];
        if (fsig) v = 1.0f / (1.0f + expf(-v));
        if (fhr) {
          float rr = 1.0f / (1.0f + expf(-v));
          v = (bf2f(sgo.AXh[off]) + bf2f(sgo.AXl[off])) * rr;
        }
        if (frelu) v = fmaxf(v, 0.f);
        if (sgo.Ch) {
          uint16_t h = f2bf(v);
          sgo.Ch[off] = h;
          sgo.Cl[off] = f2bf(v - bf2f(h));
        }
        if (sgo.Cq) sgo.Cq[off] = __float2half(v);
      }
    }
  }
}

// ---------------- GRU combine (PB=4): Hacc = sum_p probs*(...) + relu planes
__global__ __launch_bounds__(256) void accum_fused_k(
    const __half* __restrict__ Zq, const uint16_t* __restrict__ Hh,
    const uint16_t* __restrict__ Hl, const __half* __restrict__ Tq,
    const float* __restrict__ probs, float* __restrict__ hacc,
    uint16_t* __restrict__ Rh, uint16_t* __restrict__ Rl, int N) {
  int node = (blockIdx.x * 256 + threadIdx.x) >> 6;
  int l = threadIdx.x & 63;
  if (node >= N) return;
  float sum[8] = {};
  union U16x8 { uint4 u; __half2 h[4]; };
#pragma unroll
  for (int pr = 0; pr < 4; ++pr) {
    float pw = probs[pr];
    size_t ro = ((size_t)node * 4 + pr) * 512 + l * 8;
    U16x8 zq, tq;
    zq.u = *(const uint4*)(Zq + ro);
    tq.u = *(const uint4*)(Tq + ro);
    bf16x8 hh = *(const bf16x8*)(Hh + ro), hl = *(const bf16x8*)(Hl + ro);
#pragma unroll
    for (int j = 0; j < 4; ++j) {
      float2 z2 = __half22float2(zq.h[j]);
      float2 t2 = __half22float2(tq.h[j]);
      float h0 = bf2f((uint16_t)hh[j * 2]) + bf2f((uint16_t)hl[j * 2]);
      float h1 = bf2f((uint16_t)hh[j * 2 + 1]) + bf2f((uint16_t)hl[j * 2 + 1]);
      sum[j * 2] += pw * (z2.x * h0 + (1.0f - z2.x) * tanhf(t2.x));
      sum[j * 2 + 1] += pw * (z2.y * h1 + (1.0f - z2.y) * tanhf(t2.y));
    }
  }
  float* o = hacc + (size_t)node * 512 + l * 8;
  uint16_t h8[8], l8[8];
#pragma unroll
  for (int j = 0; j < 8; ++j) {
    o[j] = sum[j];
    float rv = fmaxf(sum[j], 0.f);
    uint16_t h = f2bf(rv);
    h8[j] = h;
    l8[j] = f2bf(rv - bf2f(h));
  }
  size_t po = (size_t)node * 512 + l * 8;
  *(bf16x8*)(Rh + po) = *(bf16x8*)h8;
  *(bf16x8*)(Rl + po) = *(bf16x8*)l8;
}

// fallback (PB<4)
template <int PB>
__global__ __launch_bounds__(256) void accum_k(
    const __half* __restrict__ Zq, const uint16_t* __restrict__ Hh,
    const uint16_t* __restrict__ Hl, const __half* __restrict__ Tq,
    const float* __restrict__ probs, float* __restrict__ hacc, int N, int p0) {
  int node = (blockIdx.x * 256 + threadIdx.x) >> 6;
  int l = threadIdx.x & 63;
  if (node >= N) return;
  float sum[8] = {};
#pragma unroll
  for (int pr = 0; pr < PB; ++pr) {
    float pw = probs[p0 + pr];
    size_t ro = ((size_t)node * PB + pr) * 512 + l * 8;
#pragma unroll
    for (int j = 0; j < 8; ++j) {
      float z = __half2float(Zq[ro + j]);
      float h = bf2f(Hh[ro + j]) + bf2f(Hl[ro + j]);
      float t = tanhf(__half2float(Tq[ro + j]));
      sum[j] += pw * (z * h + (1.0f - z) * t);
    }
  }
  float* o = hacc + (size_t)node * 512 + l * 8;
#pragma unroll
  for (int j = 0; j < 8; ++j) o[j] += sum[j];
}

__global__ void reluconv_k(const float* __restrict__ in, uint16_t* __restrict__ oh,
                           uint16_t* __restrict__ ol, int n4) {
  int i = blockIdx.x * blockDim.x + threadIdx.x;
  if (i >= n4) return;
  float4 v = ((const float4*)in)[i];
  float a[4] = {fmaxf(v.x, 0.f), fmaxf(v.y, 0.f), fmaxf(v.z, 0.f), fmaxf(v.w, 0.f)};
  uint16_t h4[4], l4[4];
#pragma unroll
  for (int j = 0; j < 4; ++j) {
    h4[j] = f2bf(a[j]);
    l4[j] = f2bf(a[j] - bf2f(h4[j]));
  }
  ((uint2*)oh)[i] = *(uint2*)h4;
  ((uint2*)ol)[i] = *(uint2*)l4;
}

__global__ __launch_bounds__(256) void matvec_k(const __half* __restrict__ A,
                                                const float* __restrict__ w,
                                                const float* __restrict__ b,
                                                float* __restrict__ out, int N, int K) {
  int gw = (blockIdx.x * 256 + threadIdx.x) >> 6;
  int lane = threadIdx.x & 63;
  if (gw >= N) return;
  float s = 0.0f;
  for (int k = lane; k < K; k += 64) s += __half2float(A[(size_t)gw * K + k]) * w[k];
#pragma unroll
  for (int off = 32; off > 0; off >>= 1) s += __shfl_down(s, off);
  if (lane == 0) out[gw] = s + b[0];
}

extern "C" void kernel_launch(void* const* d_in, const int* in_sizes, int n_in,
                              void* d_out, int out_size, void* d_ws, size_t ws_size,
                              hipStream_t stream) {
  const int N = 10000, F = 128, P = 4, E = 160000;
  const int C = 512, HID = 256;
  const int NC = N * C;
  (void)F; (void)in_sizes; (void)n_in;

  const float* x     = (const float*)d_in[0];
  const int*   ei    = (const int*)d_in[1];
  const float* ea    = (const float*)d_in[2];
  const float* W1    = (const float*)d_in[3];
  const float* b1    = (const float*)d_in[4];
  const float* W2    = (const float*)d_in[5];
  const float* b2    = (const float*)d_in[6];
  const float* W3    = (const float*)d_in[7];
  const float* b3    = (const float*)d_in[8];
  const float* W4    = (const float*)d_in[9];
  const float* b4    = (const float*)d_in[10];
  const float* W5    = (const float*)d_in[11];
  const float* b5    = (const float*)d_in[12];
  const float* Wz    = (const float*)d_in[13];
  const float* bz    = (const float*)d_in[14];
  const float* Lz_w  = (const float*)d_in[15];
  const float* Lz_b  = (const float*)d_in[16];
  const float* Wr    = (const float*)d_in[17];
  const float* br    = (const float*)d_in[18];
  const float* Lr_w  = (const float*)d_in[19];
  const float* Lr_b  = (const float*)d_in[20];
  const float* Wh    = (const float*)d_in[21];
  const float* bh    = (const float*)d_in[22];
  const float* Lh_w  = (const float*)d_in[23];
  const float* Lh_b  = (const float*)d_in[24];
  const float* attn  = (const float*)d_in[25];
  const float* lin1w = (const float*)d_in[26];
  const float* lin1b = (const float*)d_in[27];
  const float* lin2w = (const float*)d_in[28];
  const float* lin2b = (const float*)d_in[29];

  // ---- pick PB (same conservative bound -> stable choice) ----
  auto need = [&](int PBv) -> size_t {
    size_t NBpv = ((size_t)PBv * N + 127) / 128 * 128;
    return ((size_t)16 << 20) + NBpv * 128 * 4 + NBpv * 512 * 4 * 5;
  };
  int PB = 1;
  if (ws_size >= need(4)) PB = 4;
  else if (ws_size >= need(2)) PB = 2;
  const int NB = PB * N;
  const size_t NBp = ((size_t)NB + 127) / 128 * 128;
  const int nodeShift = (PB == 4) ? 2 : (PB == 2 ? 1 : 0);

  // ---- workspace carve-out ----
  char* wsp = (char*)d_ws;
  auto alloc = [&](size_t bytes) -> char* {
    char* ret = wsp;
    wsp += (bytes + 255) & ~(size_t)255;
    return ret;
  };
  float* deg    = (float*)alloc((size_t)N * 4);
  float* dinv   = (float*)alloc((size_t)N * 4);
  float* dinv2  = (float*)alloc((size_t)N * 4);
  int*   counts = (int*)alloc((size_t)N * 4);
  int*   rowp   = (int*)alloc((size_t)(N + 1) * 4);
  int2*  csrE   = (int2*)alloc((size_t)E * 8);
  float* probs  = (float*)alloc(256);

  auto wplanes = [&](size_t n, uint16_t** h, uint16_t** lo) {
    *h = (uint16_t*)alloc(n * 2);
    *lo = (uint16_t*)alloc(n * 2);
  };
  uint16_t *LZRh, *LZRl, *LhBh, *LhBl, *l1h, *l1l, *G3H, *G3L, *WcH, *WcL;
  wplanes((size_t)1024 * 512, &LZRh, &LZRl);  // [LzB | LrB] as [1024][512]
  wplanes((size_t)512 * 512, &LhBh, &LhBl);
  wplanes((size_t)512 * 256, &l1h, &l1l);
  wplanes((size_t)1536 * 128, &G3H, &G3L);    // folded gate tops [1536][128]
  wplanes((size_t)512 * 128, &WcH, &WcL);     // Wc planes [512][128]
  float* gbias = (float*)alloc(1536 * 4);
  float* P3f   = (float*)alloc((size_t)512 * 512 * 4);  // W4@W5
  float* P2f   = (float*)alloc((size_t)512 * 512 * 4);  // W3@P3
  float* P1f   = (float*)alloc((size_t)512 * 512 * 4);  // W2@P2
  float* Wcf   = (float*)alloc((size_t)128 * 512 * 4);  // W1@P1
  float4* cm4  = (float4*)alloc(512 * 16);
  float4* sv4  = (float4*)alloc((size_t)N * 16);

  uint16_t* AXh = (uint16_t*)alloc(NBp * 128 * 2);
  uint16_t* AXl = (uint16_t*)alloc(NBp * 128 * 2);
  __half*   Ya  = (__half*)alloc(NBp * 128 * 2);    // Y ping
  __half*   Yb  = (__half*)alloc(NBp * 128 * 2);    // Y pong
  uint16_t* Y5h = (uint16_t*)alloc(NBp * 128 * 2);  // Y5 planes (H-GEMM A)
  uint16_t* Y5l = (uint16_t*)alloc(NBp * 128 * 2);
  uint16_t* T1h = (uint16_t*)alloc(NBp * 512 * 2);  // HR / relu planes
  uint16_t* T1l = (uint16_t*)alloc(NBp * 512 * 2);
  __half*   U16 = (__half*)alloc(NBp * 512 * 2);    // R-top fp16
  uint16_t* Hh  = (uint16_t*)alloc(NBp * 512 * 2);  // H planes
  uint16_t* Hl  = (uint16_t*)alloc(NBp * 512 * 2);
  __half*   Zq  = (__half*)alloc(NBp * 512 * 2);    // Z-top -> Z
  __half*   Tq  = (__half*)alloc(NBp * 512 * 2);    // h-top -> Ht_pre

  float* Hacc = (float*)d_out + 10000;

  // ---- preprocessing ----
  if (PB != 4) hipMemsetAsync(d_out, 0, (size_t)out_size * sizeof(float), stream);
  init_k<<<(N + 255) / 256, 256, 0, stream>>>(deg, counts, N);
  edge_k<<<(E + 255) / 256, 256, 0, stream>>>(ei, ea, deg, counts, E);
  dinv_k<<<(N + 255) / 256, 256, 0, stream>>>(deg, dinv, dinv2, N);
  scan_sm_k<<<1, 1024, 0, stream>>>(counts, rowp, N, attn, probs);
  fill_k<<<(E + 255) / 256, 256, 0, stream>>>(ei, ea, dinv, rowp, counts, csrE, E);

  // weight-product chain: P3 = W4@W5, P2 = W3@P3, P1 = W2@P2, Wc = W1@P1
  mm512_k<<<dim3(16, 16), 256, 0, stream>>>(W4, W5, P3f, 512, 512);
  mm512_k<<<dim3(16, 16), 256, 0, stream>>>(W3, P3f, P2f, 512, 512);
  mm512_k<<<dim3(16, 16), 256, 0, stream>>>(W2, P2f, P1f, 512, 512);
  mm512_k<<<dim3(16, 4), 256, 0, stream>>>(W1, P1f, Wcf, 128, 512);
  // rank-1 bias terms: cm4[col] = (P1'b1, P2'b2, P3'b3, W5'b4)[col]
  cvec_k<<<2, 256, 0, stream>>>(b1, b2, b3, b4, P1f, P2f, P3f, W5, cm4);
  // s-vectors: sv4[node] = (A^4·1, A^3·1, A^2·1, A·1)
  svec_k<<<(N + 255) / 256, 256, 0, stream>>>(rowp, csrE, dinv2, (float*)sv4, 0, 3, 1, N);
  svec_k<<<(N + 255) / 256, 256, 0, stream>>>(rowp, csrE, dinv2, (float*)sv4, 3, 2, 0, N);
  svec_k<<<(N + 255) / 256, 256, 0, stream>>>(rowp, csrE, dinv2, (float*)sv4, 2, 1, 0, N);
  svec_k<<<(N + 255) / 256, 256, 0, stream>>>(rowp, csrE, dinv2, (float*)sv4, 1, 0, 0, N);

  {
    WCdesc d{};
    const float* srcs[5] = {Lz_w + (size_t)512 * 512, Lr_w + (size_t)512 * 512,
                            Lh_w + (size_t)512 * 512, lin1w, Wcf};
    uint16_t* dhs[5] = {LZRh, LZRh + (size_t)512 * 512, LhBh, l1h, WcH};
    uint16_t* dls[5] = {LZRl, LZRl + (size_t)512 * 512, LhBl, l1l, WcL};
    int Ks[5] = {512, 512, 512, 512, 128};
    int Cos[5] = {512, 512, 512, 256, 512};
    for (int i = 0; i < 5; ++i) {
      d.src[i] = srcs[i]; d.dh[i] = dhs[i]; d.dl[i] = dls[i];
      d.K[i] = Ks[i]; d.Co[i] = Cos[i];
    }
    wconv_all_k<<<dim3(16, 16, 5), 256, 0, stream>>>(d);
  }
  {
    WFdesc d;
    d.Wg[0] = Wz; d.Wg[1] = Wr; d.Wg[2] = Wh;
    d.Lt[0] = Lz_w; d.Lt[1] = Lr_w; d.Lt[2] = Lh_w;
    wfold3_k<<<dim3(16, 4, 3), 256, 0, stream>>>(d, G3H, G3L);
  }
  gbias_k<<<6, 256, 0, stream>>>(bz, Lz_w, Lz_b, br, Lr_w, Lr_b, bh, Lh_w, Lh_b, gbias);

  auto setseg = [](Seg4& s, int i, const SegOne& v) {
    s.ACh[i] = v.ACh; s.ACl[i] = v.ACl; s.ACq[i] = v.ACq;
    s.AXh[i] = v.AXh; s.AXl[i] = v.AXl;
    s.Ch[i] = v.Ch; s.Cl[i] = v.Cl; s.Cq[i] = v.Cq;
    s.bias[i] = v.bias; s.flags[i] = v.flags; s.ldc[i] = v.ldc;
  };
  auto gemm = [&](const uint16_t* Ah, const uint16_t* Al, int lda,
                  const uint16_t* Bh, const uint16_t* Bl, int ldb,
                  const Seg4& sg, int Nrows, int K, int Co) {
    dim3 g((Nrows + 127) / 128, Co / 128);
    gemm_sp_k<<<g, 256, 0, stream>>>(Ah, Al, lda, Bh, Bl, ldb, sg,
                                     sv4, cm4, nodeShift, Nrows, K, Co);
  };

  const int aggBlocks = (N * 64 + 255) / 256;
  auto aggx = [&](int p0) {
    if (PB == 4)      agg128x_k<4><<<aggBlocks, 256, 0, stream>>>(x, Ya, AXh, AXl, rowp, csrE, dinv2, N, p0);
    else if (PB == 2) agg128x_k<2><<<aggBlocks, 256, 0, stream>>>(x, Ya, AXh, AXl, rowp, csrE, dinv2, N, p0);
    else              agg128x_k<1><<<aggBlocks, 256, 0, stream>>>(x, Ya, AXh, AXl, rowp, csrE, dinv2, N, p0);
  };
  auto aggh = [&](const __half* in, __half* out, uint16_t* oh, uint16_t* ol) {
    if (PB == 4)      agg128h_k<4><<<aggBlocks, 256, 0, stream>>>(in, out, oh, ol, rowp, csrE, dinv2, N);
    else if (PB == 2) agg128h_k<2><<<aggBlocks, 256, 0, stream>>>(in, out, oh, ol, rowp, csrE, dinv2, N);
    else              agg128h_k<1><<<aggBlocks, 256, 0, stream>>>(in, out, oh, ol, rowp, csrE, dinv2, N);
  };

  for (int p0 = 0; p0 < P; p0 += PB) {
    // Y1 = A X(p-batch) (fp16) + AX planes for gate GEMMs
    aggx(p0);
    // Y2..Y5 = A^k X; Y5 also emits bf16 planes
    aggh(Ya, Yb, nullptr, nullptr);
    aggh(Yb, Ya, nullptr, nullptr);
    aggh(Ya, Yb, nullptr, nullptr);
    aggh(Yb, Ya, Y5h, Y5l);

    // H = Y5 @ Wc + rank4(sv,cm) + b5 -> H planes
    { Seg4 s{}; SegOne v;
      v.Ch = Hh; v.Cl = Hl; v.bias = b5; v.flags = 64; v.ldc = 512;
      setseg(s, 0, v);
      gemm(Y5h, Y5l, 128, WcH, WcL, 128, s, NB, 128, 512); }

    // batched gate tops: Co=1536 -> Zq | U16(R-top) | Tq (fp16)
    { Seg4 s{}; SegOne v0, v1, v2;
      v0.Cq = Zq;  v0.bias = gbias;        v0.flags = 16; v0.ldc = 512;
      v1.Cq = U16; v1.bias = gbias + 512;  v1.flags = 16; v1.ldc = 512;
      v2.Cq = Tq;  v2.bias = gbias + 1024; v2.flags = 16; v2.ldc = 512;
      setseg(s, 0, v0); setseg(s, 1, v1); setseg(s, 2, v2);
      gemm(AXh, AXl, 128, G3H, G3L, 128, s, NB, 128, 1536); }

    // batched Z/R bottoms: Co=1024
    { Seg4 s{}; SegOne v0, v1;
      v0.ACq = Zq; v0.Cq = Zq; v0.flags = 32 | 2 | 16; v0.ldc = 512;  // Z=sig
      v1.ACq = U16; v1.AXh = Hh; v1.AXl = Hl; v1.Ch = T1h; v1.Cl = T1l;
      v1.flags = 32 | 4; v1.ldc = 512;                                // HR
      setseg(s, 0, v0); setseg(s, 1, v1);
      gemm(Hh, Hl, 512, LZRh, LZRl, 512, s, NB, 512, 1024); }

    // candidate bottom: Ht_pre = h-top + HR@LhB -> Tq
    { Seg4 s{}; SegOne v;
      v.ACq = Tq; v.Cq = Tq; v.flags = 32 | 16; v.ldc = 512;
      setseg(s, 0, v);
      gemm(T1h, T1l, 512, LhBh, LhBl, 512, s, NB, 512, 512); }

    if (PB == 4)
      accum_fused_k<<<aggBlocks, 256, 0, stream>>>(Zq, Hh, Hl, Tq, probs, Hacc, T1h, T1l, N);
    else if (PB == 2)
      accum_k<2><<<aggBlocks, 256, 0, stream>>>(Zq, Hh, Hl, Tq, probs, Hacc, N, p0);
    else
      accum_k<1><<<aggBlocks, 256, 0, stream>>>(Zq, Hh, Hl, Tq, probs, Hacc, N, p0);
  }

  if (PB != 4)
    reluconv_k<<<(NC / 4 + 255) / 256, 256, 0, stream>>>(Hacc, T1h, T1l, NC / 4);

  // final MLP: relu(Hacc) planes -> lin1(+relu, fp16 out) -> lin2 matvec
  { Seg4 s{}; SegOne v;
    v.Cq = (__half*)Hh; v.bias = lin1b; v.flags = 8 | 16; v.ldc = 256;
    setseg(s, 0, v);
    gemm(T1h, T1l, 512, l1h, l1l, 512, s, N, 512, HID); }
  matvec_k<<<(N * 64 + 255) / 256, 256, 0, stream>>>((__half*)Hh, lin2w, lin2b, (float*)d_out, N, HID);
}